// Round 8
// baseline (881.328 us; speedup 1.0000x reference)
//
#include <hip/hip_runtime.h>

typedef unsigned short u16;
typedef __attribute__((ext_vector_type(8))) short short8;
typedef __attribute__((ext_vector_type(4))) float floatx4;
typedef _Float16 half8 __attribute__((ext_vector_type(8)));
typedef _Float16 half2v __attribute__((ext_vector_type(2)));
typedef unsigned uint4v __attribute__((ext_vector_type(4)));

#define AGENT __HIP_MEMORY_SCOPE_AGENT
#define SENT 0x7FFF7FFFu   // f16 NaN pair — unreachable: h = sigm*tanh in (-1,1)

// ---------- helpers ----------
__device__ __forceinline__ float bf2f(u16 v) { return __uint_as_float(((unsigned)v) << 16); }
__device__ __forceinline__ u16 f2bf(float f) {
    unsigned u = __float_as_uint(f);
    unsigned r = (u + 0x7FFFu + ((u >> 16) & 1u)) >> 16;
    return (u16)r;
}
// fast transcendentals: native v_exp + raw v_rcp (no precise-div sequence)
__device__ __forceinline__ float sigm_(float x) {
    return __builtin_amdgcn_rcpf(1.f + __expf(-x));
}
__device__ __forceinline__ float tanh_(float x) {
    x = fminf(fmaxf(x, -15.f), 15.f);
    float e = __expf(2.f * x);
    return (e - 1.f) * __builtin_amdgcn_rcpf(e + 1.f);
}

// async global->LDS, 16B per lane; LDS dest is wave-uniform base + lane*16
typedef __attribute__((address_space(1))) void gvoid_t;
typedef __attribute__((address_space(3))) void lvoid_t;
__device__ __forceinline__ void gl_lds16(const void* g, void* l) {
    __builtin_amdgcn_global_load_lds((gvoid_t*)g, (lvoid_t*)l, 16, 0, 0);
}

// B=32, C=512, H=6, W=40, NC=97, L=26, T=27
#define HEX_WORDS (134 * 32 * 256)

// ---------- init: sentinel-fill hEx + dtype sniff (one launch) ----------
__global__ void init_k(const void* __restrict__ feat_raw, int* __restrict__ flag,
                       unsigned* __restrict__ hEx) {
    int idx = blockIdx.x * 256 + threadIdx.x;
    hEx[idx] = SENT;
    if (idx == 0) {
        const u16* p = (const u16*)feat_raw;
        int insane = 0;
        #pragma unroll
        for (int i = 0; i < 32; i += 2) {
            float x = bf2f(p[i]);
            float a = fabsf(x);
            if (!(a <= 1000.f)) insane = 1;
            if (x != 0.f && a < 1e-8f) insane = 1;
        }
        *flag = insane;
    }
}

// ---------- one-shot canonicalization ----------
struct SrcPtrs {
    const void* e0Wih; const void* e1Wih; const void* d0Wih; const void* d1Wih;
    const void* b0; const void* b1; const void* b2; const void* b3;
    const void* b4; const void* b5; const void* b6; const void* b7;
    const void* encW; const void* qW; const void* predW; const void* emb;
    const void* encb; const void* qb; const void* kb; const void* sW;
    const void* sb; const void* predb;
};
#define OFF_W0      0
#define OFF_W1      1048576
#define OFF_W2      2097152
#define OFF_W3      3145728
#define OFF_B       4194304
#define OFF_ENCW    4210688
#define OFF_QW      4472832
#define OFF_PREDW   4734976
#define OFF_EMB     4883968
#define OFF_ENCB    4933632
#define OFF_QB      4934144
#define OFF_KB      4934656
#define OFF_SW      4935168
#define OFF_SB      4935680
#define OFF_PREDB   4935681
#define CANON_TOTAL 4935778

__global__ __launch_bounds__(256) void canon_all(SrcPtrs S, u16* __restrict__ dst,
                                                 const int* __restrict__ flag) {
    int idx = blockIdx.x * 256 + threadIdx.x;
    if (idx >= CANON_TOTAL) return;
    const void* s; int loc;
    if (idx < OFF_B) {
        int k = idx >> 20; loc = idx & 1048575;
        s = (k == 0) ? S.e0Wih : (k == 1) ? S.e1Wih : (k == 2) ? S.d0Wih : S.d1Wih;
    } else if (idx < OFF_ENCW) {
        int r = idx - OFF_B; int k = r >> 11; loc = r & 2047;
        s = (k == 0) ? S.b0 : (k == 1) ? S.b1 : (k == 2) ? S.b2 : (k == 3) ? S.b3
          : (k == 4) ? S.b4 : (k == 5) ? S.b5 : (k == 6) ? S.b6 : S.b7;
    } else if (idx < OFF_QW)    { s = S.encW;  loc = idx - OFF_ENCW; }
    else if (idx < OFF_PREDW)   { s = S.qW;    loc = idx - OFF_QW; }
    else if (idx < OFF_EMB)     { s = S.predW; loc = idx - OFF_PREDW; }
    else if (idx < OFF_ENCB)    { s = S.emb;   loc = idx - OFF_EMB; }
    else if (idx < OFF_QB)      { s = S.encb;  loc = idx - OFF_ENCB; }
    else if (idx < OFF_KB)      { s = S.qb;    loc = idx - OFF_QB; }
    else if (idx < OFF_SW)      { s = S.kb;    loc = idx - OFF_KB; }
    else if (idx < OFF_SB)      { s = S.sW;    loc = idx - OFF_SW; }
    else if (idx < OFF_PREDB)   { s = S.sb;    loc = idx - OFF_SB; }
    else                        { s = S.predb; loc = idx - OFF_PREDB; }
    dst[idx] = (*flag) ? f2bf(((const float*)s)[loc]) : ((const u16*)s)[loc];
}

__global__ __launch_bounds__(64) void canonf_k(const void* __restrict__ src, float* __restrict__ dst,
                                               int n, const int* __restrict__ flag) {
    int i = blockIdx.x * 64 + threadIdx.x;
    if (i >= n) return;
    dst[i] = (*flag) ? ((const float*)src)[i] : bf2f(((const u16*)src)[i]);
}

// ---------- prep kernels ----------
__device__ __forceinline__ float rdf(const void* p, long i, int fl) {
    return fl ? ((const float*)p)[i] : bf2f(((const u16*)p)[i]);
}

__global__ __launch_bounds__(256) void featv_k(const void* __restrict__ feat, u16* __restrict__ featv,
                                               const int* __restrict__ flag) {
    const int fl = *flag;
    int idx = blockIdx.x * 256 + threadIdx.x;
    int c = idx & 511;
    int r = idx >> 9;
    int w = r % 40, b = r / 40;
    float mx = -1e30f;
    long base = ((long)(b * 512 + c) * 6) * 40 + w;
    #pragma unroll
    for (int h = 0; h < 6; h++) mx = fmaxf(mx, rdf(feat, base + h * 40, fl));
    featv[idx] = f2bf(mx);
}

__global__ __launch_bounds__(256) void padfeat_k(const void* __restrict__ feat, u16* __restrict__ featP,
                                                 const int* __restrict__ flag) {
    const int fl = *flag;
    int idx = blockIdx.x * 256 + threadIdx.x;
    int c = idx & 511;
    int r = idx >> 9;
    int wp = r % 42; int r2 = r / 42;
    int hp = r2 & 7; int b = r2 >> 3;
    u16 v = 0;
    if (hp >= 1 && hp <= 6 && wp >= 1 && wp <= 40) {
        long si = ((long)(b * 512 + c) * 6 + (hp - 1)) * 40 + (wp - 1);
        v = fl ? f2bf(((const float*)feat)[si]) : ((const u16*)feat)[si];
    }
    featP[idx] = v;
}

__global__ __launch_bounds__(256) void w2_k(const void* __restrict__ kW, u16* __restrict__ W2,
                                            const int* __restrict__ flag) {
    int idx = blockIdx.x * 256 + threadIdx.x;
    int co = idx / 4608;
    int r = idx % 4608;
    int kh = r / 1536;
    int r2 = r % 1536;
    int kw = r2 / 512;
    int ci = r2 & 511;
    long si = ((long)(co * 512 + ci) * 3 + kh) * 3 + kw;
    W2[idx] = (*flag) ? f2bf(((const float*)kW)[si]) : ((const u16*)kW)[si];
}

__global__ __launch_bounds__(256) void wq3_all(
    const void* __restrict__ s0, const void* __restrict__ s1,
    const void* __restrict__ s2, const void* __restrict__ s3,
    _Float16* __restrict__ d0, _Float16* __restrict__ d1,
    _Float16* __restrict__ d2, _Float16* __restrict__ d3,
    const int* __restrict__ flag)
{
    int gb = blockIdx.x;
    int id = gb >> 9;
    const void* W = (id == 0) ? s0 : (id == 1) ? s1 : (id == 2) ? s2 : s3;
    _Float16* D = (id == 0) ? d0 : (id == 1) ? d1 : (id == 2) ? d2 : d3;
    int o = (gb & 511) * 256 + threadIdx.x;
    int t = o & 511;
    int c = (o >> 9) & 31;
    int j = o >> 14;
    int rid = t >> 1, hf = t & 1;
    int n = (rid >> 6) * 512 + j * 64 + (rid & 63);
    int k = hf * 256 + c * 8;
    int fl = *flag;
    _Float16* dst = D + (long)o * 8;
    #pragma unroll
    for (int jj = 0; jj < 8; jj++) {
        long si = (long)n * 512 + k + jj;
        float v = fl ? ((const float*)W)[si] : bf2f(((const u16*)W)[si]);
        dst[jj] = (_Float16)v;
    }
}

// ---------- NT GEMM ----------
__global__ __launch_bounds__(256) void gemm_nt_f32(
    const u16* __restrict__ A, int lda,
    const u16* __restrict__ Bw,
    const u16* __restrict__ bias0, const u16* __restrict__ bias1,
    float* __restrict__ C, int M, int N, int K, int ldc)
{
    __shared__ __align__(16) u16 As[64][40];
    __shared__ __align__(16) u16 Bs[64][40];
    const int tid = threadIdx.x;
    const int bn = blockIdx.x, bm = blockIdx.y;
    const int l = tid & 63, wid = tid >> 6;
    const int wm = wid >> 1, wn = wid & 1;
    const int lr = tid >> 2, lc = (tid & 3) * 8;
    const int l15 = l & 15, lq = l >> 4;

    floatx4 acc00 = (floatx4)(0.f), acc01 = (floatx4)(0.f), acc10 = (floatx4)(0.f), acc11 = (floatx4)(0.f);

    int am = bm * 64 + lr; if (am > M - 1) am = M - 1;
    const u16* Ap = A + (long)am * lda + lc;
    const u16* Bp = Bw + (long)(bn * 64 + lr) * K + lc;

    for (int k0 = 0; k0 < K; k0 += 32) {
        *(short8*)&As[lr][lc] = *(const short8*)(Ap + k0);
        *(short8*)&Bs[lr][lc] = *(const short8*)(Bp + k0);
        __syncthreads();
        short8 af0 = *(const short8*)&As[wm * 32 + l15][lq * 8];
        short8 af1 = *(const short8*)&As[wm * 32 + 16 + l15][lq * 8];
        short8 bf0 = *(const short8*)&Bs[wn * 32 + l15][lq * 8];
        short8 bf1 = *(const short8*)&Bs[wn * 32 + 16 + l15][lq * 8];
        acc00 = __builtin_amdgcn_mfma_f32_16x16x32_bf16(af0, bf0, acc00, 0, 0, 0);
        acc01 = __builtin_amdgcn_mfma_f32_16x16x32_bf16(af0, bf1, acc01, 0, 0, 0);
        acc10 = __builtin_amdgcn_mfma_f32_16x16x32_bf16(af1, bf0, acc10, 0, 0, 0);
        acc11 = __builtin_amdgcn_mfma_f32_16x16x32_bf16(af1, bf1, acc11, 0, 0, 0);
        __syncthreads();
    }
    floatx4 accs[2][2] = {{acc00, acc01}, {acc10, acc11}};
    #pragma unroll
    for (int i = 0; i < 2; i++)
        #pragma unroll
        for (int j = 0; j < 2; j++)
            #pragma unroll
            for (int r = 0; r < 4; r++) {
                int gm = bm * 64 + wm * 32 + i * 16 + lq * 4 + r;
                int gn = bn * 64 + wn * 32 + j * 16 + l15;
                if (gm < M) {
                    float v = accs[i][j][r];
                    if (bias0) v += bf2f(bias0[gn]);
                    if (bias1) v += bf2f(bias1[gn]);
                    C[(long)gm * ldc + gn] = v;
                }
            }
}

// ---------- conv3x3 v4 (proven): 8-wave (512thr) 128x128 tile, depth-3 counted-vmcnt, chunk-XOR swizzle ----------
__global__ __launch_bounds__(512) void conv_gemm(
    const u16* __restrict__ featP, const u16* __restrict__ W2,
    const u16* __restrict__ kb, u16* __restrict__ kmap)
{
    __shared__ __align__(16) u16 As[4][128][32];
    __shared__ __align__(16) u16 Bs[4][128][32];
    const int tid = threadIdx.x;
    int bm = blockIdx.x * 8 + (blockIdx.y & 7);
    int bn = blockIdx.y >> 3;
    if (bm >= 60) return;
    const int wv = tid >> 6, l = tid & 63;
    const int wm = wv >> 2, wn = wv & 3;     // 2 (M) x 4 (N) wave grid
    const int l15 = l & 15, lq = l >> 4;
    const int ch = ((l & 3) ^ ((l >> 3) & 3)) * 8;

    int ar = bm * 128 + wv * 16 + (l >> 2);
    int ab = ar / 240, ahw = ar % 240;
    const u16* ga = featP + ((long)(ab * 8 + ahw / 40) * 42 + (ahw % 40)) * 512 + ch;
    const u16* gb = W2 + (long)(bn * 128 + wv * 16 + (l >> 2)) * 4608 + ch;

    floatx4 acc[4][2];
    #pragma unroll
    for (int i = 0; i < 4; i++)
        #pragma unroll
        for (int j = 0; j < 2; j++) acc[i][j] = (floatx4)(0.f);

    auto stage = [&](int k0, int pb) {
        int kh = k0 / 1536;
        int rem = k0 - kh * 1536;
        int aoff = (kh * 42 + (rem >> 9)) * 512 + (rem & 511);
        gl_lds16(ga + aoff, &As[pb][wv * 16][0]);
        gl_lds16(gb + k0, &Bs[pb][wv * 16][0]);
    };

    const int rs = (lq ^ ((l15 >> 1) & 3)) * 8;

    auto compute = [&](int cur) {
        short8 af[4], bf[2];
        #pragma unroll
        for (int i = 0; i < 4; i++) af[i] = *(const short8*)&As[cur][wm * 64 + i * 16 + l15][rs];
        #pragma unroll
        for (int j = 0; j < 2; j++) bf[j] = *(const short8*)&Bs[cur][wn * 32 + j * 16 + l15][rs];
        #pragma unroll
        for (int i = 0; i < 4; i++)
            #pragma unroll
            for (int j = 0; j < 2; j++)
                acc[i][j] = __builtin_amdgcn_mfma_f32_16x16x32_bf16(af[i], bf[j], acc[i][j], 0, 0, 0);
    };

    stage(0, 0); stage(32, 1); stage(64, 2);
    for (int k = 0; k < 142; k++) {
        asm volatile("s_waitcnt vmcnt(4)" ::: "memory");
        __builtin_amdgcn_s_barrier();
        asm volatile("" ::: "memory");
        if (k < 141) stage((k + 3) * 32, (k + 3) & 3);
        compute(k & 3);
    }
    asm volatile("s_waitcnt vmcnt(2)" ::: "memory");
    __builtin_amdgcn_s_barrier();
    asm volatile("" ::: "memory");
    compute(2);
    asm volatile("s_waitcnt vmcnt(0)" ::: "memory");
    __builtin_amdgcn_s_barrier();
    asm volatile("" ::: "memory");
    compute(3);

    #pragma unroll
    for (int i = 0; i < 4; i++)
        #pragma unroll
        for (int j = 0; j < 2; j++)
            #pragma unroll
            for (int r = 0; r < 4; r++) {
                int row = bm * 128 + wm * 64 + i * 16 + lq * 4 + r;
                int col = bn * 128 + wn * 32 + j * 16 + l15;
                kmap[(long)row * 512 + col] = f2bf(acc[i][j][r] + bf2f(kb[col]));
            }
}

// ---------- LSTM recurrence v10: v4 protocol + parallel gate tail ----------
// v9 post-mortem: co-launch refuted (3 attribute variants all produced VGPR=64 +
// spill; even ignoring spill, enc1_conv 211 µs > 142 serial). Reverted to Round-2.
// v10 tweak, contained to the step tail (same math, same exchange protocol):
//  (a) gate transcendentals parallelized 4x: lanes tid<256 each compute ONE gate
//      (g=tid>>6; i/f/o->sigm, g->tanh) into gS[256]; tid<64 combine is ~2 fma +
//      1 tanh instead of a ~12-transcendental serial chain. The publisher's store
//      lands earlier -> shortens the inter-block arrival chain, 134 steps/fwd.
//  (b) xpre loads spread across tid<256 (1 float/lane).
//  (c) poll moved to wave1 so next-step poll issue overlaps wave0's publish tail.
// Hazards: part_t writes ordered after sync#1_t which follows sync#3_{t-1} (all
// readers done); gS write->sync#3->read; hS2 poll-write at t+1 is after sync#2_t
// which follows all dots_t reads. Same ordering argument as the proven v4.
#define WL(F) F(0) F(1) F(2) F(3) F(4) F(5) F(6) F(7) F(8) F(9) F(10) F(11) F(12) F(13) F(14) F(15) \
              F(16) F(17) F(18) F(19) F(20) F(21) F(22) F(23) F(24) F(25) F(26) F(27) F(28) F(29) F(30) F(31)
#define WLA(F) F(0,0) F(1,1) F(2,2) F(3,3) F(4,0) F(5,1) F(6,2) F(7,3) \
               F(8,0) F(9,1) F(10,2) F(11,3) F(12,0) F(13,1) F(14,2) F(15,3) \
               F(16,0) F(17,1) F(18,2) F(19,3) F(20,0) F(21,1) F(22,2) F(23,3) \
               F(24,0) F(25,1) F(26,2) F(27,3) F(28,0) F(29,1) F(30,2) F(31,3)
#define WDECL(i) half8 w##i = wp8[(long)(j * 32 + i) * 512 + tid];
#define WPIN(i)  asm volatile("" : "+v"(w##i));
#define DOTC(i,k) { \
    half8 hv = *(const half8*)&hS2[(hf * 2 + (i / 16)) * 136 + (i % 16) * 8]; \
    a##k = __builtin_amdgcn_fdot2(__builtin_shufflevector(hv, hv, 0, 1), __builtin_shufflevector(w##i, w##i, 0, 1), a##k, false); \
    a##k = __builtin_amdgcn_fdot2(__builtin_shufflevector(hv, hv, 2, 3), __builtin_shufflevector(w##i, w##i, 2, 3), a##k, false); \
    a##k = __builtin_amdgcn_fdot2(__builtin_shufflevector(hv, hv, 4, 5), __builtin_shufflevector(w##i, w##i, 4, 5), a##k, false); \
    a##k = __builtin_amdgcn_fdot2(__builtin_shufflevector(hv, hv, 6, 7), __builtin_shufflevector(w##i, w##i, 6, 7), a##k, false); }

__global__ __launch_bounds__(512) __attribute__((amdgpu_waves_per_eu(2, 2))) void lstm_sync(
    const float* __restrict__ xpre, const _Float16* __restrict__ Wq3,
    u16* __restrict__ seq_out, float* __restrict__ f32_out,
    unsigned* __restrict__ hExT, int T, int f32_ld)
{
    const int i_ = blockIdx.x;
    const int slot = i_ >> 3;
    const int b = (i_ & 7) * 4 + (slot & 3);
    const int j = slot >> 2;
    const int tid = threadIdx.x;
    const int hf = tid & 1;

    __shared__ __align__(16) _Float16 hS2[4 * 136];
    __shared__ float part[512];
    __shared__ float gS[256];

    const half8* wp8 = (const half8*)Wq3;
    WL(WDECL)
    WL(WPIN)
    float cst = 0.f;

    for (int t = 0; t < T; t++) {
        float xv = 0.f;
        if (tid < 256) {
            // gate g = tid>>6, h-index ln = tid&63 -> xpre[.. + g*512 + j*64 + ln]
            xv = xpre[((long)b * T + t) * 2048 + (tid >> 6) * 512 + j * 64 + (tid & 63)];
        }
        float a0 = 0.f, a1 = 0.f, a2 = 0.f, a3 = 0.f;
        if (t > 0) {
            if (tid >= 64 && tid < 128) {   // wave1 polls (overlaps wave0's tail of t-1)
                const int ln = tid - 64;
                const unsigned* src = &hExT[((long)(t - 1) * 32 + b) * 256 + ln * 4];
                unsigned v0, v1, v2, v3;
                do {
                    v0 = __hip_atomic_load(src + 0, __ATOMIC_RELAXED, AGENT);
                    v1 = __hip_atomic_load(src + 1, __ATOMIC_RELAXED, AGENT);
                    v2 = __hip_atomic_load(src + 2, __ATOMIC_RELAXED, AGENT);
                    v3 = __hip_atomic_load(src + 3, __ATOMIC_RELAXED, AGENT);
                } while (v0 == SENT || v1 == SENT || v2 == SENT || v3 == SENT);
                uint4v v; v.x = v0; v.y = v1; v.z = v2; v.w = v3;
                *(uint4v*)&hS2[(ln >> 4) * 136 + (ln & 15) * 8] = v;
            }
            __syncthreads();
            WLA(DOTC)
        }
        part[tid] = (a0 + a1) + (a2 + a3);
        __syncthreads();
        // parallel gate stage: gate row = tid (0..255); i/f/o -> sigm, g -> tanh
        if (tid < 256) {
            float raw = xv + part[tid * 2] + part[tid * 2 + 1];
            gS[tid] = ((tid >> 6) == 2) ? tanh_(raw) : sigm_(raw);
        }
        __syncthreads();
        if (tid < 64) {
            cst = gS[64 + tid] * cst + gS[tid] * gS[128 + tid];
            float h = gS[192 + tid] * tanh_(cst);
            float hlo = __shfl(h, tid * 2);
            float hhi = __shfl(h, tid * 2 + 1);
            if (t + 1 < T && tid < 32) {
                half2v hp; hp[0] = (_Float16)hlo; hp[1] = (_Float16)hhi;
                __hip_atomic_store(&hExT[((long)t * 32 + b) * 256 + j * 32 + tid],
                                   *(unsigned*)&hp, __ATOMIC_RELAXED, AGENT);
            }
            asm volatile("" ::: "memory");
            long so = ((long)b * T + t) * 512 + j * 64 + tid;
            seq_out[so] = f2bf(h);
            if (f32_out) f32_out[((long)b * T + t) * f32_ld + j * 64 + tid] = h;
        }
    }
}

// ---------- token build ----------
__global__ __launch_bounds__(256) void tok_k(
    const float* __restrict__ holf, const u16* __restrict__ cemb,
    const int* __restrict__ label, u16* __restrict__ tok)
{
    int idx = blockIdx.x * 256 + threadIdx.x;
    int c = idx & 511;
    int m = idx >> 9;
    int b = m / 27, t = m % 27;
    float v;
    if (t == 0) v = holf[(long)b * 512 + c];
    else v = bf2f(cemb[(long)label[b * 26 + (t - 1)] * 512 + c]);
    tok[idx] = f2bf(v);
}

// ---------- fused score v2 (r9-verified) ----------
__global__ __launch_bounds__(256) void score_k(
    const float* __restrict__ q, const u16* __restrict__ kmap,
    const u16* __restrict__ sW, const u16* __restrict__ sb,
    const float* __restrict__ vr, float* __restrict__ aw)
{
    int blk = blockIdx.x;
    int xcd = blk & 7, rest = blk >> 3;
    int bq = rest & 3, t = rest >> 2;
    int b = xcd * 4 + bq;
    int bt = b * 27 + t;
    int tid = threadIdx.x, wv = tid >> 6, ln = tid & 63;

    __shared__ float sc[240];
    __shared__ float red[256];

    float qr[8], sr[8];
    const float* qp = q + (long)bt * 512 + ln * 8;
    #pragma unroll
    for (int i = 0; i < 8; i++) qr[i] = qp[i];
    #pragma unroll
    for (int i = 0; i < 8; i++) sr[i] = bf2f(sW[ln * 8 + i]);

    const u16* kb_ = kmap + (long)b * 240 * 512;
    for (int r = wv * 60; r < wv * 60 + 60; r++) {
        short8 kv = *(const short8*)(kb_ + (long)r * 512 + ln * 8);
        float acc = 0.f;
        #pragma unroll
        for (int i = 0; i < 8; i++) {
            float x = bf2f((u16)kv[i]) + qr[i];
            acc = fmaf(sr[i], tanh_(x), acc);
        }
        #pragma unroll
        for (int m = 32; m > 0; m >>= 1) acc += __shfl_xor(acc, m);
        if (ln == 0) sc[r] = acc;
    }
    __syncthreads();

    float scv = -INFINITY, ex = 0.f;
    if (tid < 240) {
        float rr = vr[b];
        int vw = (int)ceilf(40.f * rr);
        if (vw > 40) vw = 40;
        int wcol = tid % 40;
        scv = (wcol >= vw) ? -INFINITY : (sc[tid] + bf2f(sb[0]));
    }
    red[tid] = scv;
    __syncthreads();
    for (int s = 128; s > 0; s >>= 1) {
        if (tid < s) red[tid] = fmaxf(red[tid], red[tid + s]);
        __syncthreads();
    }
    float mx = red[0];
    __syncthreads();
    if (tid < 240) ex = (scv == -INFINITY) ? 0.f : __expf(scv - mx);
    red[tid] = ex;
    __syncthreads();
    for (int s = 128; s > 0; s >>= 1) {
        if (tid < s) red[tid] += red[tid + s];
        __syncthreads();
    }
    float inv = __builtin_amdgcn_rcpf(red[0]);
    if (tid < 240) aw[(long)bt * 240 + tid] = ex * inv;
}

// ---------- attn_feat -> concat cols [512,1024) ----------
__global__ __launch_bounds__(256) void attn_k(
    const void* __restrict__ feat, const float* __restrict__ aw,
    float* __restrict__ concat, const int* __restrict__ flag)
{
    const int fl = *flag;
    int b = blockIdx.x >> 3;
    int cc = (blockIdx.x & 7) * 64;
    int tid = threadIdx.x;
    __shared__ float awS[27 * 240];
    __shared__ u16 fS[64 * 240];
    for (int i = tid; i < 27 * 240; i += 256) awS[i] = aw[(long)b * 27 * 240 + i];
    long fbase = ((long)b * 512 + cc) * 240;
    for (int i = tid; i < 64 * 240; i += 256)
        fS[i] = fl ? f2bf(((const float*)feat)[fbase + i]) : ((const u16*)feat)[fbase + i];
    __syncthreads();
    for (int item = tid; item < 64 * 27; item += 256) {
        int c = item / 27, t = item % 27;
        const u16* fp = &fS[c * 240];
        const float* ap = &awS[t * 240];
        float acc = 0.f;
        for (int hw = 0; hw < 240; hw++) acc = fmaf(bf2f(fp[hw]), ap[hw], acc);
        concat[((long)(b * 27 + t)) * 1536 + 512 + cc + c] = acc;
    }
}

// ---------- prediction + slice ----------
__global__ __launch_bounds__(256) void pred_k(
    const float* __restrict__ concat, const float* __restrict__ holf,
    const u16* __restrict__ pW, const u16* __restrict__ pb,
    void* __restrict__ out, const int* __restrict__ flag)
{
    int m0 = blockIdx.x * 4;
    int tid = threadIdx.x;
    const int fl = *flag;
    __shared__ float aS[4][1024];
    __shared__ float hS[4][512];
    for (int i = tid; i < 4 * 1024; i += 256)
        aS[i / 1024][i % 1024] = concat[(long)(m0 + i / 1024) * 1536 + (i % 1024)];
    for (int i = tid; i < 4 * 512; i += 256) {
        int m = m0 + i / 512;
        hS[i / 512][i % 512] = holf[(long)(m / 27) * 512 + (i % 512)];
    }
    __syncthreads();
    int r = tid >> 6;
    int nb = tid & 63;
    int m = m0 + r;
    int b = m / 27, t = m % 27;
    for (int n = nb; n < 97; n += 64) {
        const u16* wp = pW + (long)n * 1536;
        float acc = 0.f;
        for (int k = 0; k < 1024; k++) acc = fmaf(aS[r][k], bf2f(wp[k]), acc);
        for (int k = 0; k < 512; k++) acc = fmaf(hS[r][k], bf2f(wp[1024 + k]), acc);
        acc += bf2f(pb[n]);
        if (t > 0) {
            long o = ((long)(b * 26 + (t - 1))) * 97 + n;
            if (fl) ((float*)out)[o] = acc;
            else    ((u16*)out)[o] = f2bf(acc);
        }
    }
}

// ---------- launch ----------
extern "C" void kernel_launch(void* const* d_in, const int* in_sizes, int n_in,
                              void* d_out, int out_size, void* d_ws, size_t ws_size,
                              hipStream_t stream) {
    (void)in_sizes; (void)n_in; (void)out_size; (void)ws_size;
    const void* feat_r = d_in[0];
    const int*  label  = (const int*)d_in[1];
    const void* vr_r   = d_in[2];

    char* w = (char*)d_ws;
    size_t off = 0;
    auto alloc = [&](size_t bytes) -> void* {
        void* p = w + off;
        off = (off + bytes + 63) & ~(size_t)63;
        return p;
    };
    int*   flag    = (int*)  alloc(4);
    unsigned* hEx  = (unsigned*)alloc((size_t)HEX_WORDS * 4);
    u16*   canon   = (u16*)  alloc((size_t)CANON_TOTAL * 2);
    float* cvr     = (float*)alloc(32ull * 4);
    u16*   featv   = (u16*)  alloc(655360ull * 2);
    float* xpre    = (float*)alloc(2621440ull * 4);   // kmap aliases after LSTMs
    u16*   seq0    = (u16*)  alloc(655360ull * 2);
    u16*   seq1    = (u16*)  alloc(655360ull * 2);
    u16*   tok     = (u16*)  alloc(442368ull * 2);
    u16*   seqd0   = (u16*)  alloc(442368ull * 2);
    u16*   Hid     = (u16*)  alloc(442368ull * 2);
    float* holf    = (float*)alloc(16384ull * 4);
    float* qf      = (float*)alloc(442368ull * 4);
    u16*   featP   = (u16*)  alloc(5505024ull * 2);
    u16*   W2      = (u16*)  alloc(2359296ull * 2);
    float* aw      = (float*)alloc(207360ull * 4);
    float* concat  = (float*)alloc(1327104ull * 4);
    _Float16* Wq[4];
    for (int i = 0; i < 4; i++) Wq[i] = (_Float16*)alloc(1048576ull * 2);
    u16*   kmap    = (u16*)xpre;

    unsigned* hEx0 = hEx;
    unsigned* hEx1 = hEx + 40ull * 8192;
    unsigned* hEx2 = hEx + 80ull * 8192;
    unsigned* hEx3 = hEx + 107ull * 8192;

    u16* cW0    = canon + OFF_W0;
    u16* cW1    = canon + OFF_W1;
    u16* cW2    = canon + OFF_W2;
    u16* cW3    = canon + OFF_W3;
    u16* cb0    = canon + OFF_B;
    u16* cencW  = canon + OFF_ENCW;
    u16* cqW    = canon + OFF_QW;
    u16* cpredW = canon + OFF_PREDW;
    u16* cemb   = canon + OFF_EMB;
    u16* cencb  = canon + OFF_ENCB;
    u16* cqb    = canon + OFF_QB;
    u16* ckb    = canon + OFF_KB;
    u16* csW    = canon + OFF_SW;
    u16* csb    = canon + OFF_SB;
    u16* cpredb = canon + OFF_PREDB;

    // ---- init (sentinel fill + sniff) + canonicalize ----
    init_k<<<dim3(HEX_WORDS / 256), 256, 0, stream>>>(feat_r, flag, hEx);
    SrcPtrs S;
    S.e0Wih = d_in[3];  S.e1Wih = d_in[7];  S.d0Wih = d_in[20]; S.d1Wih = d_in[24];
    S.b0 = d_in[5];  S.b1 = d_in[6];  S.b2 = d_in[9];  S.b3 = d_in[10];
    S.b4 = d_in[22]; S.b5 = d_in[23]; S.b6 = d_in[26]; S.b7 = d_in[27];
    S.encW = d_in[11]; S.qW = d_in[13]; S.predW = d_in[28]; S.emb = d_in[19];
    S.encb = d_in[12]; S.qb = d_in[14]; S.kb = d_in[16]; S.sW = d_in[17];
    S.sb = d_in[18]; S.predb = d_in[29];
    canon_all<<<dim3((CANON_TOTAL + 255) / 256), 256, 0, stream>>>(S, canon, flag);
    canonf_k<<<dim3(1), 64, 0, stream>>>(vr_r, cvr, 32, flag);
    w2_k<<<dim3(9216), 256, 0, stream>>>(d_in[15], W2, flag);
    wq3_all<<<dim3(2048), 256, 0, stream>>>(d_in[4], d_in[8], d_in[21], d_in[25],
                                            Wq[0], Wq[1], Wq[2], Wq[3], flag);

    // ---- prep ----
    featv_k  <<<dim3(2560), 256, 0, stream>>>(feat_r, featv, flag);
    padfeat_k<<<dim3(21504), 256, 0, stream>>>(feat_r, featP, flag);

    // ---- encoder ----
    gemm_nt_f32<<<dim3(32, 20), 256, 0, stream>>>(featv, 512, cW0, cb0 + 0 * 2048, cb0 + 1 * 2048, xpre, 1280, 2048, 512, 2048);
    lstm_sync<<<dim3(256), 512, 0, stream>>>(xpre, Wq[0], seq0, nullptr, hEx0, 40, 0);
    gemm_nt_f32<<<dim3(32, 20), 256, 0, stream>>>(seq0, 512, cW1, cb0 + 2 * 2048, cb0 + 3 * 2048, xpre, 1280, 2048, 512, 2048);
    lstm_sync<<<dim3(256), 512, 0, stream>>>(xpre, Wq[1], seq1, nullptr, hEx1, 40, 0);
    gemm_nt_f32<<<dim3(8, 1), 256, 0, stream>>>(seq1 + 39 * 512, 40 * 512, cencW, cencb, nullptr, holf, 32, 512, 512, 512);

    // ---- decoder ----
    tok_k<<<dim3(1728), 256, 0, stream>>>(holf, cemb, label, tok);
    gemm_nt_f32<<<dim3(32, 14), 256, 0, stream>>>(tok, 512, cW2, cb0 + 4 * 2048, cb0 + 5 * 2048, xpre, 864, 2048, 512, 2048);
    lstm_sync<<<dim3(256), 512, 0, stream>>>(xpre, Wq[2], seqd0, nullptr, hEx2, 27, 0);
    gemm_nt_f32<<<dim3(32, 14), 256, 0, stream>>>(seqd0, 512, cW3, cb0 + 6 * 2048, cb0 + 7 * 2048, xpre, 864, 2048, 512, 2048);
    lstm_sync<<<dim3(256), 512, 0, stream>>>(xpre, Wq[3], Hid, concat, hEx3, 27, 1536);

    // ---- attention (xpre dead; kmap aliases it) ----
    gemm_nt_f32<<<dim3(8, 14), 256, 0, stream>>>(Hid, 512, cqW, cqb, nullptr, qf, 864, 512, 512, 512);
    conv_gemm<<<dim3(8, 32), 512, 0, stream>>>(featP, W2, ckb, kmap);
    score_k<<<dim3(864), 256, 0, stream>>>(qf, kmap, csW, csb, cvr, aw);
    attn_k<<<dim3(256), 256, 0, stream>>>(feat_r, aw, concat, flag);

    // ---- prediction ----
    pred_k<<<dim3(216), 256, 0, stream>>>(concat, holf, cpredW, cpredb, d_out, flag);
}

// Round 9
// 819.656 us; speedup vs baseline: 1.0752x; 1.0752x over previous
//
#include <hip/hip_runtime.h>

typedef unsigned short u16;
typedef __attribute__((ext_vector_type(8))) short short8;
typedef __attribute__((ext_vector_type(4))) float floatx4;
typedef _Float16 half8 __attribute__((ext_vector_type(8)));
typedef _Float16 half2v __attribute__((ext_vector_type(2)));
typedef unsigned uint4v __attribute__((ext_vector_type(4)));

#define AGENT __HIP_MEMORY_SCOPE_AGENT
#define SENT 0x7FFF7FFFu   // f16 NaN pair — unreachable: h = sigm*tanh in (-1,1)

// ---------- helpers ----------
__device__ __forceinline__ float bf2f(u16 v) { return __uint_as_float(((unsigned)v) << 16); }
__device__ __forceinline__ u16 f2bf(float f) {
    unsigned u = __float_as_uint(f);
    unsigned r = (u + 0x7FFFu + ((u >> 16) & 1u)) >> 16;
    return (u16)r;
}
// fast transcendentals: native v_exp + raw v_rcp (no precise-div sequence)
__device__ __forceinline__ float sigm_(float x) {
    return __builtin_amdgcn_rcpf(1.f + __expf(-x));
}
__device__ __forceinline__ float tanh_(float x) {
    x = fminf(fmaxf(x, -15.f), 15.f);
    float e = __expf(2.f * x);
    return (e - 1.f) * __builtin_amdgcn_rcpf(e + 1.f);
}

// async global->LDS, 16B per lane; LDS dest is wave-uniform base + lane*16
typedef __attribute__((address_space(1))) void gvoid_t;
typedef __attribute__((address_space(3))) void lvoid_t;
__device__ __forceinline__ void gl_lds16(const void* g, void* l) {
    __builtin_amdgcn_global_load_lds((gvoid_t*)g, (lvoid_t*)l, 16, 0, 0);
}

// B=32, C=512, H=6, W=40, NC=97, L=26, T=27
#define HEX_WORDS (134 * 32 * 256)

// ---------- init: sentinel-fill hEx + dtype sniff (one launch) ----------
__global__ void init_k(const void* __restrict__ feat_raw, int* __restrict__ flag,
                       unsigned* __restrict__ hEx) {
    int idx = blockIdx.x * 256 + threadIdx.x;
    hEx[idx] = SENT;
    if (idx == 0) {
        const u16* p = (const u16*)feat_raw;
        int insane = 0;
        #pragma unroll
        for (int i = 0; i < 32; i += 2) {
            float x = bf2f(p[i]);
            float a = fabsf(x);
            if (!(a <= 1000.f)) insane = 1;
            if (x != 0.f && a < 1e-8f) insane = 1;
        }
        *flag = insane;
    }
}

// ---------- one-shot canonicalization ----------
struct SrcPtrs {
    const void* e0Wih; const void* e1Wih; const void* d0Wih; const void* d1Wih;
    const void* b0; const void* b1; const void* b2; const void* b3;
    const void* b4; const void* b5; const void* b6; const void* b7;
    const void* encW; const void* qW; const void* predW; const void* emb;
    const void* encb; const void* qb; const void* kb; const void* sW;
    const void* sb; const void* predb;
};
#define OFF_W0      0
#define OFF_W1      1048576
#define OFF_W2      2097152
#define OFF_W3      3145728
#define OFF_B       4194304
#define OFF_ENCW    4210688
#define OFF_QW      4472832
#define OFF_PREDW   4734976
#define OFF_EMB     4883968
#define OFF_ENCB    4933632
#define OFF_QB      4934144
#define OFF_KB      4934656
#define OFF_SW      4935168
#define OFF_SB      4935680
#define OFF_PREDB   4935681
#define CANON_TOTAL 4935778

__global__ __launch_bounds__(256) void canon_all(SrcPtrs S, u16* __restrict__ dst,
                                                 const int* __restrict__ flag) {
    int idx = blockIdx.x * 256 + threadIdx.x;
    if (idx >= CANON_TOTAL) return;
    const void* s; int loc;
    if (idx < OFF_B) {
        int k = idx >> 20; loc = idx & 1048575;
        s = (k == 0) ? S.e0Wih : (k == 1) ? S.e1Wih : (k == 2) ? S.d0Wih : S.d1Wih;
    } else if (idx < OFF_ENCW) {
        int r = idx - OFF_B; int k = r >> 11; loc = r & 2047;
        s = (k == 0) ? S.b0 : (k == 1) ? S.b1 : (k == 2) ? S.b2 : (k == 3) ? S.b3
          : (k == 4) ? S.b4 : (k == 5) ? S.b5 : (k == 6) ? S.b6 : S.b7;
    } else if (idx < OFF_QW)    { s = S.encW;  loc = idx - OFF_ENCW; }
    else if (idx < OFF_PREDW)   { s = S.qW;    loc = idx - OFF_QW; }
    else if (idx < OFF_EMB)     { s = S.predW; loc = idx - OFF_PREDW; }
    else if (idx < OFF_ENCB)    { s = S.emb;   loc = idx - OFF_EMB; }
    else if (idx < OFF_QB)      { s = S.encb;  loc = idx - OFF_ENCB; }
    else if (idx < OFF_KB)      { s = S.qb;    loc = idx - OFF_QB; }
    else if (idx < OFF_SW)      { s = S.kb;    loc = idx - OFF_KB; }
    else if (idx < OFF_SB)      { s = S.sW;    loc = idx - OFF_SW; }
    else if (idx < OFF_PREDB)   { s = S.sb;    loc = idx - OFF_SB; }
    else                        { s = S.predb; loc = idx - OFF_PREDB; }
    dst[idx] = (*flag) ? f2bf(((const float*)s)[loc]) : ((const u16*)s)[loc];
}

__global__ __launch_bounds__(64) void canonf_k(const void* __restrict__ src, float* __restrict__ dst,
                                               int n, const int* __restrict__ flag) {
    int i = blockIdx.x * 64 + threadIdx.x;
    if (i >= n) return;
    dst[i] = (*flag) ? ((const float*)src)[i] : bf2f(((const u16*)src)[i]);
}

// ---------- prep kernels ----------
__device__ __forceinline__ float rdf(const void* p, long i, int fl) {
    return fl ? ((const float*)p)[i] : bf2f(((const u16*)p)[i]);
}

__global__ __launch_bounds__(256) void featv_k(const void* __restrict__ feat, u16* __restrict__ featv,
                                               const int* __restrict__ flag) {
    const int fl = *flag;
    int idx = blockIdx.x * 256 + threadIdx.x;
    int c = idx & 511;
    int r = idx >> 9;
    int w = r % 40, b = r / 40;
    float mx = -1e30f;
    long base = ((long)(b * 512 + c) * 6) * 40 + w;
    #pragma unroll
    for (int h = 0; h < 6; h++) mx = fmaxf(mx, rdf(feat, base + h * 40, fl));
    featv[idx] = f2bf(mx);
}

__global__ __launch_bounds__(256) void padfeat_k(const void* __restrict__ feat, u16* __restrict__ featP,
                                                 const int* __restrict__ flag) {
    const int fl = *flag;
    int idx = blockIdx.x * 256 + threadIdx.x;
    int c = idx & 511;
    int r = idx >> 9;
    int wp = r % 42; int r2 = r / 42;
    int hp = r2 & 7; int b = r2 >> 3;
    u16 v = 0;
    if (hp >= 1 && hp <= 6 && wp >= 1 && wp <= 40) {
        long si = ((long)(b * 512 + c) * 6 + (hp - 1)) * 40 + (wp - 1);
        v = fl ? f2bf(((const float*)feat)[si]) : ((const u16*)feat)[si];
    }
    featP[idx] = v;
}

__global__ __launch_bounds__(256) void w2_k(const void* __restrict__ kW, u16* __restrict__ W2,
                                            const int* __restrict__ flag) {
    int idx = blockIdx.x * 256 + threadIdx.x;
    int co = idx / 4608;
    int r = idx % 4608;
    int kh = r / 1536;
    int r2 = r % 1536;
    int kw = r2 / 512;
    int ci = r2 & 511;
    long si = ((long)(co * 512 + ci) * 3 + kh) * 3 + kw;
    W2[idx] = (*flag) ? f2bf(((const float*)kW)[si]) : ((const u16*)kW)[si];
}

__global__ __launch_bounds__(256) void wq3_all(
    const void* __restrict__ s0, const void* __restrict__ s1,
    const void* __restrict__ s2, const void* __restrict__ s3,
    _Float16* __restrict__ d0, _Float16* __restrict__ d1,
    _Float16* __restrict__ d2, _Float16* __restrict__ d3,
    const int* __restrict__ flag)
{
    int gb = blockIdx.x;
    int id = gb >> 9;
    const void* W = (id == 0) ? s0 : (id == 1) ? s1 : (id == 2) ? s2 : s3;
    _Float16* D = (id == 0) ? d0 : (id == 1) ? d1 : (id == 2) ? d2 : d3;
    int o = (gb & 511) * 256 + threadIdx.x;
    int t = o & 511;
    int c = (o >> 9) & 31;
    int j = o >> 14;
    int rid = t >> 1, hf = t & 1;
    int n = (rid >> 6) * 512 + j * 64 + (rid & 63);
    int k = hf * 256 + c * 8;
    int fl = *flag;
    _Float16* dst = D + (long)o * 8;
    #pragma unroll
    for (int jj = 0; jj < 8; jj++) {
        long si = (long)n * 512 + k + jj;
        float v = fl ? ((const float*)W)[si] : bf2f(((const u16*)W)[si]);
        dst[jj] = (_Float16)v;
    }
}

// ---------- NT GEMM (64-tile; kept for tiny M=32 encW GEMM) ----------
__global__ __launch_bounds__(256) void gemm_nt_f32(
    const u16* __restrict__ A, int lda,
    const u16* __restrict__ Bw,
    const u16* __restrict__ bias0, const u16* __restrict__ bias1,
    float* __restrict__ C, int M, int N, int K, int ldc)
{
    __shared__ __align__(16) u16 As[64][40];
    __shared__ __align__(16) u16 Bs[64][40];
    const int tid = threadIdx.x;
    const int bn = blockIdx.x, bm = blockIdx.y;
    const int l = tid & 63, wid = tid >> 6;
    const int wm = wid >> 1, wn = wid & 1;
    const int lr = tid >> 2, lc = (tid & 3) * 8;
    const int l15 = l & 15, lq = l >> 4;

    floatx4 acc00 = (floatx4)(0.f), acc01 = (floatx4)(0.f), acc10 = (floatx4)(0.f), acc11 = (floatx4)(0.f);

    int am = bm * 64 + lr; if (am > M - 1) am = M - 1;
    const u16* Ap = A + (long)am * lda + lc;
    const u16* Bp = Bw + (long)(bn * 64 + lr) * K + lc;

    for (int k0 = 0; k0 < K; k0 += 32) {
        *(short8*)&As[lr][lc] = *(const short8*)(Ap + k0);
        *(short8*)&Bs[lr][lc] = *(const short8*)(Bp + k0);
        __syncthreads();
        short8 af0 = *(const short8*)&As[wm * 32 + l15][lq * 8];
        short8 af1 = *(const short8*)&As[wm * 32 + 16 + l15][lq * 8];
        short8 bf0 = *(const short8*)&Bs[wn * 32 + l15][lq * 8];
        short8 bf1 = *(const short8*)&Bs[wn * 32 + 16 + l15][lq * 8];
        acc00 = __builtin_amdgcn_mfma_f32_16x16x32_bf16(af0, bf0, acc00, 0, 0, 0);
        acc01 = __builtin_amdgcn_mfma_f32_16x16x32_bf16(af0, bf1, acc01, 0, 0, 0);
        acc10 = __builtin_amdgcn_mfma_f32_16x16x32_bf16(af1, bf0, acc10, 0, 0, 0);
        acc11 = __builtin_amdgcn_mfma_f32_16x16x32_bf16(af1, bf1, acc11, 0, 0, 0);
        __syncthreads();
    }
    floatx4 accs[2][2] = {{acc00, acc01}, {acc10, acc11}};
    #pragma unroll
    for (int i = 0; i < 2; i++)
        #pragma unroll
        for (int j = 0; j < 2; j++)
            #pragma unroll
            for (int r = 0; r < 4; r++) {
                int gm = bm * 64 + wm * 32 + i * 16 + lq * 4 + r;
                int gn = bn * 64 + wn * 32 + j * 16 + l15;
                if (gm < M) {
                    float v = accs[i][j][r];
                    if (bias0) v += bf2f(bias0[gn]);
                    if (bias1) v += bf2f(bias1[gn]);
                    C[(long)gm * ldc + gn] = v;
                }
            }
}

// ---------- v11: 128x128 NT GEMM with the conv-v4 proven structure ----------
// K fixed at 512 (16 K-steps). 8 waves (2Mx4N), depth-3 counted-vmcnt pipeline,
// chunk-XOR swizzle (source chunk (l&3)^((l>>3)&3), read chunk lq^((l15>>1)&3)).
// A,B both row-major [*][512] bf16 (NT); A rows clamped to M-1 (duplicate loads,
// stores guarded). f32 output + up to 2 bf16 biases. Same buffer-reuse argument
// as conv_gemm (stage k+3 overwrites buf (k-1)&3 after barrier k).
__global__ __launch_bounds__(512) void gemm_nt_128(
    const u16* __restrict__ A, const u16* __restrict__ Bw,
    const u16* __restrict__ bias0, const u16* __restrict__ bias1,
    float* __restrict__ C, int M, int ldc)
{
    __shared__ __align__(16) u16 As[4][128][32];
    __shared__ __align__(16) u16 Bs[4][128][32];
    const int tid = threadIdx.x;
    const int bn = blockIdx.x, bm = blockIdx.y;
    const int wv = tid >> 6, l = tid & 63;
    const int wm = wv >> 2, wn = wv & 3;     // 2 (M) x 4 (N) wave grid
    const int l15 = l & 15, lq = l >> 4;
    const int ch = ((l & 3) ^ ((l >> 3) & 3)) * 8;

    int ar = bm * 128 + wv * 16 + (l >> 2);
    if (ar > M - 1) ar = M - 1;
    const u16* ga = A + (long)ar * 512 + ch;
    const u16* gb = Bw + (long)(bn * 128 + wv * 16 + (l >> 2)) * 512 + ch;

    floatx4 acc[4][2];
    #pragma unroll
    for (int i = 0; i < 4; i++)
        #pragma unroll
        for (int j = 0; j < 2; j++) acc[i][j] = (floatx4)(0.f);

    auto stage = [&](int k0, int pb) {
        gl_lds16(ga + k0, &As[pb][wv * 16][0]);
        gl_lds16(gb + k0, &Bs[pb][wv * 16][0]);
    };

    const int rs = (lq ^ ((l15 >> 1) & 3)) * 8;

    auto compute = [&](int cur) {
        short8 af[4], bf[2];
        #pragma unroll
        for (int i = 0; i < 4; i++) af[i] = *(const short8*)&As[cur][wm * 64 + i * 16 + l15][rs];
        #pragma unroll
        for (int j = 0; j < 2; j++) bf[j] = *(const short8*)&Bs[cur][wn * 32 + j * 16 + l15][rs];
        #pragma unroll
        for (int i = 0; i < 4; i++)
            #pragma unroll
            for (int j = 0; j < 2; j++)
                acc[i][j] = __builtin_amdgcn_mfma_f32_16x16x32_bf16(af[i], bf[j], acc[i][j], 0, 0, 0);
    };

    // 16 K-steps: prologue 3, main loop computes 0..13, tail 14,15
    stage(0, 0); stage(32, 1); stage(64, 2);
    for (int k = 0; k < 14; k++) {
        asm volatile("s_waitcnt vmcnt(4)" ::: "memory");
        __builtin_amdgcn_s_barrier();
        asm volatile("" ::: "memory");
        if (k < 13) stage((k + 3) * 32, (k + 3) & 3);
        compute(k & 3);
    }
    asm volatile("s_waitcnt vmcnt(2)" ::: "memory");
    __builtin_amdgcn_s_barrier();
    asm volatile("" ::: "memory");
    compute(2);   // 14 & 3
    asm volatile("s_waitcnt vmcnt(0)" ::: "memory");
    __builtin_amdgcn_s_barrier();
    asm volatile("" ::: "memory");
    compute(3);   // 15 & 3

    #pragma unroll
    for (int i = 0; i < 4; i++)
        #pragma unroll
        for (int j = 0; j < 2; j++)
            #pragma unroll
            for (int r = 0; r < 4; r++) {
                int gm = bm * 128 + wm * 64 + i * 16 + lq * 4 + r;
                int gn = bn * 128 + wn * 32 + j * 16 + l15;
                if (gm < M) {
                    float v = acc[i][j][r];
                    if (bias0) v += bf2f(bias0[gn]);
                    if (bias1) v += bf2f(bias1[gn]);
                    C[(long)gm * ldc + gn] = v;
                }
            }
}

// ---------- conv3x3 v4 (proven): 8-wave (512thr) 128x128 tile, depth-3 counted-vmcnt, chunk-XOR swizzle ----------
__global__ __launch_bounds__(512) void conv_gemm(
    const u16* __restrict__ featP, const u16* __restrict__ W2,
    const u16* __restrict__ kb, u16* __restrict__ kmap)
{
    __shared__ __align__(16) u16 As[4][128][32];
    __shared__ __align__(16) u16 Bs[4][128][32];
    const int tid = threadIdx.x;
    int bm = blockIdx.x * 8 + (blockIdx.y & 7);
    int bn = blockIdx.y >> 3;
    if (bm >= 60) return;
    const int wv = tid >> 6, l = tid & 63;
    const int wm = wv >> 2, wn = wv & 3;     // 2 (M) x 4 (N) wave grid
    const int l15 = l & 15, lq = l >> 4;
    const int ch = ((l & 3) ^ ((l >> 3) & 3)) * 8;

    int ar = bm * 128 + wv * 16 + (l >> 2);
    int ab = ar / 240, ahw = ar % 240;
    const u16* ga = featP + ((long)(ab * 8 + ahw / 40) * 42 + (ahw % 40)) * 512 + ch;
    const u16* gb = W2 + (long)(bn * 128 + wv * 16 + (l >> 2)) * 4608 + ch;

    floatx4 acc[4][2];
    #pragma unroll
    for (int i = 0; i < 4; i++)
        #pragma unroll
        for (int j = 0; j < 2; j++) acc[i][j] = (floatx4)(0.f);

    auto stage = [&](int k0, int pb) {
        int kh = k0 / 1536;
        int rem = k0 - kh * 1536;
        int aoff = (kh * 42 + (rem >> 9)) * 512 + (rem & 511);
        gl_lds16(ga + aoff, &As[pb][wv * 16][0]);
        gl_lds16(gb + k0, &Bs[pb][wv * 16][0]);
    };

    const int rs = (lq ^ ((l15 >> 1) & 3)) * 8;

    auto compute = [&](int cur) {
        short8 af[4], bf[2];
        #pragma unroll
        for (int i = 0; i < 4; i++) af[i] = *(const short8*)&As[cur][wm * 64 + i * 16 + l15][rs];
        #pragma unroll
        for (int j = 0; j < 2; j++) bf[j] = *(const short8*)&Bs[cur][wn * 32 + j * 16 + l15][rs];
        #pragma unroll
        for (int i = 0; i < 4; i++)
            #pragma unroll
            for (int j = 0; j < 2; j++)
                acc[i][j] = __builtin_amdgcn_mfma_f32_16x16x32_bf16(af[i], bf[j], acc[i][j], 0, 0, 0);
    };

    stage(0, 0); stage(32, 1); stage(64, 2);
    for (int k = 0; k < 142; k++) {
        asm volatile("s_waitcnt vmcnt(4)" ::: "memory");
        __builtin_amdgcn_s_barrier();
        asm volatile("" ::: "memory");
        if (k < 141) stage((k + 3) * 32, (k + 3) & 3);
        compute(k & 3);
    }
    asm volatile("s_waitcnt vmcnt(2)" ::: "memory");
    __builtin_amdgcn_s_barrier();
    asm volatile("" ::: "memory");
    compute(2);
    asm volatile("s_waitcnt vmcnt(0)" ::: "memory");
    __builtin_amdgcn_s_barrier();
    asm volatile("" ::: "memory");
    compute(3);

    #pragma unroll
    for (int i = 0; i < 4; i++)
        #pragma unroll
        for (int j = 0; j < 2; j++)
            #pragma unroll
            for (int r = 0; r < 4; r++) {
                int row = bm * 128 + wm * 64 + i * 16 + lq * 4 + r;
                int col = bn * 128 + wn * 32 + j * 16 + l15;
                kmap[(long)row * 512 + col] = f2bf(acc[i][j][r] + bf2f(kb[col]));
            }
}

// ---------- LSTM recurrence v4 (proven, reverted): sentinel self-announcing exchange ----------
// v10 post-mortem: parallel-gate tail REGRESSED 82->104 µs. The 4 gate transcendentals
// are independent (ILP-hidden); the real serial tail is ~2 transcendentals (~60cy).
// v10 added a 3rd barrier/step + wave1-poll handoff = pure overhead. The ~4300cy/step
// gap is exchange ARRIVAL latency (IF visibility + slowest-of-8 skew) — structural.
// All five LSTM attack attempts (v5 latency, v6 fusion, v7-9 co-launch, v10 tail)
// are refuted; this kernel is at its floor. DO NOT TOUCH.
#define WL(F) F(0) F(1) F(2) F(3) F(4) F(5) F(6) F(7) F(8) F(9) F(10) F(11) F(12) F(13) F(14) F(15) \
              F(16) F(17) F(18) F(19) F(20) F(21) F(22) F(23) F(24) F(25) F(26) F(27) F(28) F(29) F(30) F(31)
#define WLA(F) F(0,0) F(1,1) F(2,2) F(3,3) F(4,0) F(5,1) F(6,2) F(7,3) \
               F(8,0) F(9,1) F(10,2) F(11,3) F(12,0) F(13,1) F(14,2) F(15,3) \
               F(16,0) F(17,1) F(18,2) F(19,3) F(20,0) F(21,1) F(22,2) F(23,3) \
               F(24,0) F(25,1) F(26,2) F(27,3) F(28,0) F(29,1) F(30,2) F(31,3)
#define WDECL(i) half8 w##i = wp8[(long)(j * 32 + i) * 512 + tid];
#define WPIN(i)  asm volatile("" : "+v"(w##i));
#define DOTC(i,k) { \
    half8 hv = *(const half8*)&hS2[(hf * 2 + (i / 16)) * 136 + (i % 16) * 8]; \
    a##k = __builtin_amdgcn_fdot2(__builtin_shufflevector(hv, hv, 0, 1), __builtin_shufflevector(w##i, w##i, 0, 1), a##k, false); \
    a##k = __builtin_amdgcn_fdot2(__builtin_shufflevector(hv, hv, 2, 3), __builtin_shufflevector(w##i, w##i, 2, 3), a##k, false); \
    a##k = __builtin_amdgcn_fdot2(__builtin_shufflevector(hv, hv, 4, 5), __builtin_shufflevector(w##i, w##i, 4, 5), a##k, false); \
    a##k = __builtin_amdgcn_fdot2(__builtin_shufflevector(hv, hv, 6, 7), __builtin_shufflevector(w##i, w##i, 6, 7), a##k, false); }

__global__ __launch_bounds__(512) __attribute__((amdgpu_waves_per_eu(2, 2))) void lstm_sync(
    const float* __restrict__ xpre, const _Float16* __restrict__ Wq3,
    u16* __restrict__ seq_out, float* __restrict__ f32_out,
    unsigned* __restrict__ hExT, int T, int f32_ld)
{
    const int i_ = blockIdx.x;
    const int slot = i_ >> 3;
    const int b = (i_ & 7) * 4 + (slot & 3);
    const int j = slot >> 2;
    const int tid = threadIdx.x;
    const int hf = tid & 1;

    __shared__ __align__(16) _Float16 hS2[4 * 136];
    __shared__ float part[512];

    const half8* wp8 = (const half8*)Wq3;
    WL(WDECL)
    WL(WPIN)
    float cst = 0.f;

    for (int t = 0; t < T; t++) {
        float xi = 0.f, xf = 0.f, xg = 0.f, xo = 0.f;
        if (tid < 64) {
            const float* xp = xpre + ((long)b * T + t) * 2048 + j * 64 + tid;
            xi = xp[0]; xf = xp[512]; xg = xp[1024]; xo = xp[1536];
        }
        float a0 = 0.f, a1 = 0.f, a2 = 0.f, a3 = 0.f;
        if (t > 0) {
            if (tid < 64) {
                const unsigned* src = &hExT[((long)(t - 1) * 32 + b) * 256 + tid * 4];
                unsigned v0, v1, v2, v3;
                do {
                    v0 = __hip_atomic_load(src + 0, __ATOMIC_RELAXED, AGENT);
                    v1 = __hip_atomic_load(src + 1, __ATOMIC_RELAXED, AGENT);
                    v2 = __hip_atomic_load(src + 2, __ATOMIC_RELAXED, AGENT);
                    v3 = __hip_atomic_load(src + 3, __ATOMIC_RELAXED, AGENT);
                } while (v0 == SENT || v1 == SENT || v2 == SENT || v3 == SENT);
                uint4v v; v.x = v0; v.y = v1; v.z = v2; v.w = v3;
                *(uint4v*)&hS2[(tid >> 4) * 136 + (tid & 15) * 8] = v;
            }
            __syncthreads();
            WLA(DOTC)
        }
        part[tid] = (a0 + a1) + (a2 + a3);
        __syncthreads();
        if (tid < 64) {
            float gi = xi + part[(0   + tid) * 2] + part[(0   + tid) * 2 + 1];
            float gf = xf + part[(64  + tid) * 2] + part[(64  + tid) * 2 + 1];
            float gg = xg + part[(128 + tid) * 2] + part[(128 + tid) * 2 + 1];
            float go = xo + part[(192 + tid) * 2] + part[(192 + tid) * 2 + 1];
            cst = sigm_(gf) * cst + sigm_(gi) * tanh_(gg);
            float h = sigm_(go) * tanh_(cst);
            float hlo = __shfl(h, tid * 2);
            float hhi = __shfl(h, tid * 2 + 1);
            if (t + 1 < T && tid < 32) {
                half2v hp; hp[0] = (_Float16)hlo; hp[1] = (_Float16)hhi;
                __hip_atomic_store(&hExT[((long)t * 32 + b) * 256 + j * 32 + tid],
                                   *(unsigned*)&hp, __ATOMIC_RELAXED, AGENT);
            }
            asm volatile("" ::: "memory");
            long so = ((long)b * T + t) * 512 + j * 64 + tid;
            seq_out[so] = f2bf(h);
            if (f32_out) f32_out[((long)b * T + t) * f32_ld + j * 64 + tid] = h;
        }
    }
}

// ---------- token build ----------
__global__ __launch_bounds__(256) void tok_k(
    const float* __restrict__ holf, const u16* __restrict__ cemb,
    const int* __restrict__ label, u16* __restrict__ tok)
{
    int idx = blockIdx.x * 256 + threadIdx.x;
    int c = idx & 511;
    int m = idx >> 9;
    int b = m / 27, t = m % 27;
    float v;
    if (t == 0) v = holf[(long)b * 512 + c];
    else v = bf2f(cemb[(long)label[b * 26 + (t - 1)] * 512 + c]);
    tok[idx] = f2bf(v);
}

// ---------- fused score v2 (r9-verified) ----------
__global__ __launch_bounds__(256) void score_k(
    const float* __restrict__ q, const u16* __restrict__ kmap,
    const u16* __restrict__ sW, const u16* __restrict__ sb,
    const float* __restrict__ vr, float* __restrict__ aw)
{
    int blk = blockIdx.x;
    int xcd = blk & 7, rest = blk >> 3;
    int bq = rest & 3, t = rest >> 2;
    int b = xcd * 4 + bq;
    int bt = b * 27 + t;
    int tid = threadIdx.x, wv = tid >> 6, ln = tid & 63;

    __shared__ float sc[240];
    __shared__ float red[256];

    float qr[8], sr[8];
    const float* qp = q + (long)bt * 512 + ln * 8;
    #pragma unroll
    for (int i = 0; i < 8; i++) qr[i] = qp[i];
    #pragma unroll
    for (int i = 0; i < 8; i++) sr[i] = bf2f(sW[ln * 8 + i]);

    const u16* kb_ = kmap + (long)b * 240 * 512;
    for (int r = wv * 60; r < wv * 60 + 60; r++) {
        short8 kv = *(const short8*)(kb_ + (long)r * 512 + ln * 8);
        float acc = 0.f;
        #pragma unroll
        for (int i = 0; i < 8; i++) {
            float x = bf2f((u16)kv[i]) + qr[i];
            acc = fmaf(sr[i], tanh_(x), acc);
        }
        #pragma unroll
        for (int m = 32; m > 0; m >>= 1) acc += __shfl_xor(acc, m);
        if (ln == 0) sc[r] = acc;
    }
    __syncthreads();

    float scv = -INFINITY, ex = 0.f;
    if (tid < 240) {
        float rr = vr[b];
        int vw = (int)ceilf(40.f * rr);
        if (vw > 40) vw = 40;
        int wcol = tid % 40;
        scv = (wcol >= vw) ? -INFINITY : (sc[tid] + bf2f(sb[0]));
    }
    red[tid] = scv;
    __syncthreads();
    for (int s = 128; s > 0; s >>= 1) {
        if (tid < s) red[tid] = fmaxf(red[tid], red[tid + s]);
        __syncthreads();
    }
    float mx = red[0];
    __syncthreads();
    if (tid < 240) ex = (scv == -INFINITY) ? 0.f : __expf(scv - mx);
    red[tid] = ex;
    __syncthreads();
    for (int s = 128; s > 0; s >>= 1) {
        if (tid < s) red[tid] += red[tid + s];
        __syncthreads();
    }
    float inv = __builtin_amdgcn_rcpf(red[0]);
    if (tid < 240) aw[(long)bt * 240 + tid] = ex * inv;
}

// ---------- attn_feat -> concat cols [512,1024) ----------
__global__ __launch_bounds__(256) void attn_k(
    const void* __restrict__ feat, const float* __restrict__ aw,
    float* __restrict__ concat, const int* __restrict__ flag)
{
    const int fl = *flag;
    int b = blockIdx.x >> 3;
    int cc = (blockIdx.x & 7) * 64;
    int tid = threadIdx.x;
    __shared__ float awS[27 * 240];
    __shared__ u16 fS[64 * 240];
    for (int i = tid; i < 27 * 240; i += 256) awS[i] = aw[(long)b * 27 * 240 + i];
    long fbase = ((long)b * 512 + cc) * 240;
    for (int i = tid; i < 64 * 240; i += 256)
        fS[i] = fl ? f2bf(((const float*)feat)[fbase + i]) : ((const u16*)feat)[fbase + i];
    __syncthreads();
    for (int item = tid; item < 64 * 27; item += 256) {
        int c = item / 27, t = item % 27;
        const u16* fp = &fS[c * 240];
        const float* ap = &awS[t * 240];
        float acc = 0.f;
        for (int hw = 0; hw < 240; hw++) acc = fmaf(bf2f(fp[hw]), ap[hw], acc);
        concat[((long)(b * 27 + t)) * 1536 + 512 + cc + c] = acc;
    }
}

// ---------- prediction + slice ----------
__global__ __launch_bounds__(256) void pred_k(
    const float* __restrict__ concat, const float* __restrict__ holf,
    const u16* __restrict__ pW, const u16* __restrict__ pb,
    void* __restrict__ out, const int* __restrict__ flag)
{
    int m0 = blockIdx.x * 4;
    int tid = threadIdx.x;
    const int fl = *flag;
    __shared__ float aS[4][1024];
    __shared__ float hS[4][512];
    for (int i = tid; i < 4 * 1024; i += 256)
        aS[i / 1024][i % 1024] = concat[(long)(m0 + i / 1024) * 1536 + (i % 1024)];
    for (int i = tid; i < 4 * 512; i += 256) {
        int m = m0 + i / 512;
        hS[i / 512][i % 512] = holf[(long)(m / 27) * 512 + (i % 512)];
    }
    __syncthreads();
    int r = tid >> 6;
    int nb = tid & 63;
    int m = m0 + r;
    int b = m / 27, t = m % 27;
    for (int n = nb; n < 97; n += 64) {
        const u16* wp = pW + (long)n * 1536;
        float acc = 0.f;
        for (int k = 0; k < 1024; k++) acc = fmaf(aS[r][k], bf2f(wp[k]), acc);
        for (int k = 0; k < 512; k++) acc = fmaf(hS[r][k], bf2f(wp[1024 + k]), acc);
        acc += bf2f(pb[n]);
        if (t > 0) {
            long o = ((long)(b * 26 + (t - 1))) * 97 + n;
            if (fl) ((float*)out)[o] = acc;
            else    ((u16*)out)[o] = f2bf(acc);
        }
    }
}

// ---------- launch ----------
extern "C" void kernel_launch(void* const* d_in, const int* in_sizes, int n_in,
                              void* d_out, int out_size, void* d_ws, size_t ws_size,
                              hipStream_t stream) {
    (void)in_sizes; (void)n_in; (void)out_size; (void)ws_size;
    const void* feat_r = d_in[0];
    const int*  label  = (const int*)d_in[1];
    const void* vr_r   = d_in[2];

    char* w = (char*)d_ws;
    size_t off = 0;
    auto alloc = [&](size_t bytes) -> void* {
        void* p = w + off;
        off = (off + bytes + 63) & ~(size_t)63;
        return p;
    };
    int*   flag    = (int*)  alloc(4);
    unsigned* hEx  = (unsigned*)alloc((size_t)HEX_WORDS * 4);
    u16*   canon   = (u16*)  alloc((size_t)CANON_TOTAL * 2);
    float* cvr     = (float*)alloc(32ull * 4);
    u16*   featv   = (u16*)  alloc(655360ull * 2);
    float* xpre    = (float*)alloc(2621440ull * 4);   // kmap aliases after LSTMs
    u16*   seq0    = (u16*)  alloc(655360ull * 2);
    u16*   seq1    = (u16*)  alloc(655360ull * 2);
    u16*   tok     = (u16*)  alloc(442368ull * 2);
    u16*   seqd0   = (u16*)  alloc(442368ull * 2);
    u16*   Hid     = (u16*)  alloc(442368ull * 2);
    float* holf    = (float*)alloc(16384ull * 4);
    float* qf      = (float*)alloc(442368ull * 4);
    u16*   featP   = (u16*)  alloc(5505024ull * 2);
    u16*   W2      = (u16*)  alloc(2359296ull * 2);
    float* aw      = (float*)alloc(207360ull * 4);
    float* concat  = (float*)alloc(1327104ull * 4);
    _Float16* Wq[4];
    for (int i = 0; i < 4; i++) Wq[i] = (_Float16*)alloc(1048576ull * 2);
    u16*   kmap    = (u16*)xpre;

    unsigned* hEx0 = hEx;
    unsigned* hEx1 = hEx + 40ull * 8192;
    unsigned* hEx2 = hEx + 80ull * 8192;
    unsigned* hEx3 = hEx + 107ull * 8192;

    u16* cW0    = canon + OFF_W0;
    u16* cW1    = canon + OFF_W1;
    u16* cW2    = canon + OFF_W2;
    u16* cW3    = canon + OFF_W3;
    u16* cb0    = canon + OFF_B;
    u16* cencW  = canon + OFF_ENCW;
    u16* cqW    = canon + OFF_QW;
    u16* cpredW = canon + OFF_PREDW;
    u16* cemb   = canon + OFF_EMB;
    u16* cencb  = canon + OFF_ENCB;
    u16* cqb    = canon + OFF_QB;
    u16* ckb    = canon + OFF_KB;
    u16* csW    = canon + OFF_SW;
    u16* csb    = canon + OFF_SB;
    u16* cpredb = canon + OFF_PREDB;

    // ---- init (sentinel fill + sniff) + canonicalize ----
    init_k<<<dim3(HEX_WORDS / 256), 256, 0, stream>>>(feat_r, flag, hEx);
    SrcPtrs S;
    S.e0Wih = d_in[3];  S.e1Wih = d_in[7];  S.d0Wih = d_in[20]; S.d1Wih = d_in[24];
    S.b0 = d_in[5];  S.b1 = d_in[6];  S.b2 = d_in[9];  S.b3 = d_in[10];
    S.b4 = d_in[22]; S.b5 = d_in[23]; S.b6 = d_in[26]; S.b7 = d_in[27];
    S.encW = d_in[11]; S.qW = d_in[13]; S.predW = d_in[28]; S.emb = d_in[19];
    S.encb = d_in[12]; S.qb = d_in[14]; S.kb = d_in[16]; S.sW = d_in[17];
    S.sb = d_in[18]; S.predb = d_in[29];
    canon_all<<<dim3((CANON_TOTAL + 255) / 256), 256, 0, stream>>>(S, canon, flag);
    canonf_k<<<dim3(1), 64, 0, stream>>>(vr_r, cvr, 32, flag);
    w2_k<<<dim3(9216), 256, 0, stream>>>(d_in[15], W2, flag);
    wq3_all<<<dim3(2048), 256, 0, stream>>>(d_in[4], d_in[8], d_in[21], d_in[25],
                                            Wq[0], Wq[1], Wq[2], Wq[3], flag);

    // ---- prep ----
    featv_k  <<<dim3(2560), 256, 0, stream>>>(feat_r, featv, flag);
    padfeat_k<<<dim3(21504), 256, 0, stream>>>(feat_r, featP, flag);

    // ---- encoder (x-GEMMs on the 128-tile pipelined kernel) ----
    gemm_nt_128<<<dim3(16, 10), 512, 0, stream>>>(featv, cW0, cb0 + 0 * 2048, cb0 + 1 * 2048, xpre, 1280, 2048);
    lstm_sync<<<dim3(256), 512, 0, stream>>>(xpre, Wq[0], seq0, nullptr, hEx0, 40, 0);
    gemm_nt_128<<<dim3(16, 10), 512, 0, stream>>>(seq0, cW1, cb0 + 2 * 2048, cb0 + 3 * 2048, xpre, 1280, 2048);
    lstm_sync<<<dim3(256), 512, 0, stream>>>(xpre, Wq[1], seq1, nullptr, hEx1, 40, 0);
    gemm_nt_f32<<<dim3(8, 1), 256, 0, stream>>>(seq1 + 39 * 512, 40 * 512, cencW, cencb, nullptr, holf, 32, 512, 512, 512);

    // ---- decoder ----
    tok_k<<<dim3(1728), 256, 0, stream>>>(holf, cemb, label, tok);
    gemm_nt_128<<<dim3(16, 7), 512, 0, stream>>>(tok, cW2, cb0 + 4 * 2048, cb0 + 5 * 2048, xpre, 864, 2048);
    lstm_sync<<<dim3(256), 512, 0, stream>>>(xpre, Wq[2], seqd0, nullptr, hEx2, 27, 0);
    gemm_nt_128<<<dim3(16, 7), 512, 0, stream>>>(seqd0, cW3, cb0 + 6 * 2048, cb0 + 7 * 2048, xpre, 864, 2048);
    lstm_sync<<<dim3(256), 512, 0, stream>>>(xpre, Wq[3], Hid, concat, hEx3, 27, 1536);

    // ---- attention (xpre dead; kmap aliases it) ----
    gemm_nt_128<<<dim3(4, 7), 512, 0, stream>>>(Hid, cqW, cqb, nullptr, qf, 864, 512);
    conv_gemm<<<dim3(8, 32), 512, 0, stream>>>(featP, W2, ckb, kmap);
    score_k<<<dim3(864), 256, 0, stream>>>(qf, kmap, csW, csb, cvr, aw);
    attn_k<<<dim3(256), 256, 0, stream>>>(feat_r, aw, concat, flag);

    // ---- prediction ----
    pred_k<<<dim3(216), 256, 0, stream>>>(concat, holf, cpredW, cpredb, d_out, flag);
}

// Round 10
// 803.087 us; speedup vs baseline: 1.0974x; 1.0206x over previous
//
#include <hip/hip_runtime.h>

typedef unsigned short u16;
typedef __attribute__((ext_vector_type(8))) short short8;
typedef __attribute__((ext_vector_type(4))) float floatx4;
typedef _Float16 half8 __attribute__((ext_vector_type(8)));
typedef _Float16 half2v __attribute__((ext_vector_type(2)));
typedef unsigned uint4v __attribute__((ext_vector_type(4)));

#define AGENT __HIP_MEMORY_SCOPE_AGENT
#define SENT 0x7FFF7FFFu   // f16 NaN pair — unreachable: h = sigm*tanh in (-1,1)

// ---------- helpers ----------
__device__ __forceinline__ float bf2f(u16 v) { return __uint_as_float(((unsigned)v) << 16); }
__device__ __forceinline__ u16 f2bf(float f) {
    unsigned u = __float_as_uint(f);
    unsigned r = (u + 0x7FFFu + ((u >> 16) & 1u)) >> 16;
    return (u16)r;
}
// fast transcendentals: native v_exp + raw v_rcp (no precise-div sequence)
__device__ __forceinline__ float sigm_(float x) {
    return __builtin_amdgcn_rcpf(1.f + __expf(-x));
}
__device__ __forceinline__ float tanh_(float x) {
    x = fminf(fmaxf(x, -15.f), 15.f);
    float e = __expf(2.f * x);
    return (e - 1.f) * __builtin_amdgcn_rcpf(e + 1.f);
}

// async global->LDS, 16B per lane; LDS dest is wave-uniform base + lane*16
typedef __attribute__((address_space(1))) void gvoid_t;
typedef __attribute__((address_space(3))) void lvoid_t;
__device__ __forceinline__ void gl_lds16(const void* g, void* l) {
    __builtin_amdgcn_global_load_lds((gvoid_t*)g, (lvoid_t*)l, 16, 0, 0);
}

// B=32, C=512, H=6, W=40, NC=97, L=26, T=27
#define HEX_WORDS (134 * 32 * 256)

// ---------- offsets ----------
struct SrcPtrs {
    const void* e0Wih; const void* e1Wih; const void* d0Wih; const void* d1Wih;
    const void* b0; const void* b1; const void* b2; const void* b3;
    const void* b4; const void* b5; const void* b6; const void* b7;
    const void* encW; const void* qW; const void* predW; const void* emb;
    const void* encb; const void* qb; const void* kb; const void* sW;
    const void* sb; const void* predb;
};
#define OFF_W0      0
#define OFF_W1      1048576
#define OFF_W2      2097152
#define OFF_W3      3145728
#define OFF_B       4194304
#define OFF_ENCW    4210688
#define OFF_QW      4472832
#define OFF_PREDW   4734976
#define OFF_EMB     4883968
#define OFF_ENCB    4933632
#define OFF_QB      4934144
#define OFF_KB      4934656
#define OFF_SW      4935168
#define OFF_SB      4935680
#define OFF_PREDB   4935681
#define CANON_TOTAL 4935778

// ---------- v12: fused prep — 7 kernels in ONE dispatch ----------
// v11 budget audit: sum of per-kernel estimates ≈ 510 µs vs 819 measured; ~300 µs
// sits in ~22 serialized dispatch boundaries (~13 µs each — the documented ~10 µs
// launch-overhead plateau). The 7 prep kernels (init/canon/canonf/w2/wq3/featv/
// padfeat) are independent elementwise ops; the only cross-dependency was the dtype
// flag, whose sniff is 32 loads of ONE 64B line -> every block computes it locally
// (L2 broadcast). Block-range dispatch, each branch's indexing byte-identical to
// its predecessor kernel. flag still written (block 0) for attn_k/pred_k.
__device__ __forceinline__ int sniff_(const void* feat_raw) {
    const u16* p = (const u16*)feat_raw;
    int insane = 0;
    #pragma unroll
    for (int i = 0; i < 32; i += 2) {
        float x = bf2f(p[i]);
        float a = fabsf(x);
        if (!(a <= 1000.f)) insane = 1;
        if (x != 0.f && a < 1e-8f) insane = 1;
    }
    return insane;
}

struct PrepArgs {
    SrcPtrs S;
    const void* feat_raw;
    const void* vr_src;
    const void* kW_src;
    const void* wq_s0; const void* wq_s1; const void* wq_s2; const void* wq_s3;
    int* flag;
    unsigned* hEx;
    u16* canon;
    float* cvr;
    u16* featv;
    u16* featP;
    u16* W2;
    _Float16* wq_d0; _Float16* wq_d1; _Float16* wq_d2; _Float16* wq_d3;
};

// block ranges
#define PB_INIT    0        // 4288 blocks  : hEx sentinel fill (+flag from idx 0)
#define PB_CANON   4288     // 19281 blocks : canon_all
#define PB_CANONF  23569    // 1 block      : cvr (32 floats)
#define PB_W2      23570    // 9216 blocks  : conv weight reshuffle
#define PB_WQ3     32786    // 2048 blocks  : 4x Whh -> f16 dot layout
#define PB_FEATV   34834    // 2560 blocks  : height max-pool
#define PB_PAD     37394    // 21504 blocks : padded feat transpose
#define PB_TOTAL   58898

__global__ __launch_bounds__(256) void prep_all(PrepArgs P)
{
    const int blk = blockIdx.x;
    const int tid = threadIdx.x;

    if (blk < PB_CANON) {                       // ---- init: sentinel fill ----
        int idx = blk * 256 + tid;
        P.hEx[idx] = SENT;
        if (idx == 0) *P.flag = sniff_(P.feat_raw);
        return;
    }
    const int fl = sniff_(P.feat_raw);          // per-block local dtype flag

    if (blk < PB_CANONF) {                      // ---- canon_all ----
        int idx = (blk - PB_CANON) * 256 + tid;
        if (idx >= CANON_TOTAL) return;
        const SrcPtrs& S = P.S;
        const void* s; int loc;
        if (idx < OFF_B) {
            int k = idx >> 20; loc = idx & 1048575;
            s = (k == 0) ? S.e0Wih : (k == 1) ? S.e1Wih : (k == 2) ? S.d0Wih : S.d1Wih;
        } else if (idx < OFF_ENCW) {
            int r = idx - OFF_B; int k = r >> 11; loc = r & 2047;
            s = (k == 0) ? S.b0 : (k == 1) ? S.b1 : (k == 2) ? S.b2 : (k == 3) ? S.b3
              : (k == 4) ? S.b4 : (k == 5) ? S.b5 : (k == 6) ? S.b6 : S.b7;
        } else if (idx < OFF_QW)    { s = S.encW;  loc = idx - OFF_ENCW; }
        else if (idx < OFF_PREDW)   { s = S.qW;    loc = idx - OFF_QW; }
        else if (idx < OFF_EMB)     { s = S.predW; loc = idx - OFF_PREDW; }
        else if (idx < OFF_ENCB)    { s = S.emb;   loc = idx - OFF_EMB; }
        else if (idx < OFF_QB)      { s = S.encb;  loc = idx - OFF_ENCB; }
        else if (idx < OFF_KB)      { s = S.qb;    loc = idx - OFF_QB; }
        else if (idx < OFF_SW)      { s = S.kb;    loc = idx - OFF_KB; }
        else if (idx < OFF_SB)      { s = S.sW;    loc = idx - OFF_SW; }
        else if (idx < OFF_PREDB)   { s = S.sb;    loc = idx - OFF_SB; }
        else                        { s = S.predb; loc = idx - OFF_PREDB; }
        P.canon[idx] = fl ? f2bf(((const float*)s)[loc]) : ((const u16*)s)[loc];
    } else if (blk == PB_CANONF) {              // ---- canonf (valid_ratios) ----
        if (tid < 32)
            P.cvr[tid] = fl ? ((const float*)P.vr_src)[tid] : bf2f(((const u16*)P.vr_src)[tid]);
    } else if (blk < PB_WQ3) {                  // ---- w2 ----
        int idx = (blk - PB_W2) * 256 + tid;
        int co = idx / 4608;
        int r = idx % 4608;
        int kh = r / 1536;
        int r2 = r % 1536;
        int kw = r2 / 512;
        int ci = r2 & 511;
        long si = ((long)(co * 512 + ci) * 3 + kh) * 3 + kw;
        P.W2[idx] = fl ? f2bf(((const float*)P.kW_src)[si]) : ((const u16*)P.kW_src)[si];
    } else if (blk < PB_FEATV) {                // ---- wq3_all ----
        int gb = blk - PB_WQ3;
        int id = gb >> 9;
        const void* W = (id == 0) ? P.wq_s0 : (id == 1) ? P.wq_s1 : (id == 2) ? P.wq_s2 : P.wq_s3;
        _Float16* D = (id == 0) ? P.wq_d0 : (id == 1) ? P.wq_d1 : (id == 2) ? P.wq_d2 : P.wq_d3;
        int o = (gb & 511) * 256 + tid;
        int t = o & 511;
        int c = (o >> 9) & 31;
        int j = o >> 14;
        int rid = t >> 1, hf = t & 1;
        int n = (rid >> 6) * 512 + j * 64 + (rid & 63);
        int k = hf * 256 + c * 8;
        _Float16* dst = D + (long)o * 8;
        #pragma unroll
        for (int jj = 0; jj < 8; jj++) {
            long si = (long)n * 512 + k + jj;
            float v = fl ? ((const float*)W)[si] : bf2f(((const u16*)W)[si]);
            dst[jj] = (_Float16)v;
        }
    } else if (blk < PB_PAD) {                  // ---- featv (height max-pool) ----
        int idx = (blk - PB_FEATV) * 256 + tid;
        int c = idx & 511;
        int r = idx >> 9;
        int w = r % 40, b = r / 40;
        float mx = -1e30f;
        long base = ((long)(b * 512 + c) * 6) * 40 + w;
        #pragma unroll
        for (int h = 0; h < 6; h++) {
            float x = fl ? ((const float*)P.feat_raw)[base + h * 40]
                         : bf2f(((const u16*)P.feat_raw)[base + h * 40]);
            mx = fmaxf(mx, x);
        }
        P.featv[idx] = f2bf(mx);
    } else {                                    // ---- padfeat ----
        int idx = (blk - PB_PAD) * 256 + tid;
        int c = idx & 511;
        int r = idx >> 9;
        int wp = r % 42; int r2 = r / 42;
        int hp = r2 & 7; int b = r2 >> 3;
        u16 v = 0;
        if (hp >= 1 && hp <= 6 && wp >= 1 && wp <= 40) {
            long si = ((long)(b * 512 + c) * 6 + (hp - 1)) * 40 + (wp - 1);
            v = fl ? f2bf(((const float*)P.feat_raw)[si]) : ((const u16*)P.feat_raw)[si];
        }
        P.featP[idx] = v;
    }
}

// ---------- NT GEMM (64-tile; kept for tiny M=32 encW GEMM) ----------
__global__ __launch_bounds__(256) void gemm_nt_f32(
    const u16* __restrict__ A, int lda,
    const u16* __restrict__ Bw,
    const u16* __restrict__ bias0, const u16* __restrict__ bias1,
    float* __restrict__ C, int M, int N, int K, int ldc)
{
    __shared__ __align__(16) u16 As[64][40];
    __shared__ __align__(16) u16 Bs[64][40];
    const int tid = threadIdx.x;
    const int bn = blockIdx.x, bm = blockIdx.y;
    const int l = tid & 63, wid = tid >> 6;
    const int wm = wid >> 1, wn = wid & 1;
    const int lr = tid >> 2, lc = (tid & 3) * 8;
    const int l15 = l & 15, lq = l >> 4;

    floatx4 acc00 = (floatx4)(0.f), acc01 = (floatx4)(0.f), acc10 = (floatx4)(0.f), acc11 = (floatx4)(0.f);

    int am = bm * 64 + lr; if (am > M - 1) am = M - 1;
    const u16* Ap = A + (long)am * lda + lc;
    const u16* Bp = Bw + (long)(bn * 64 + lr) * K + lc;

    for (int k0 = 0; k0 < K; k0 += 32) {
        *(short8*)&As[lr][lc] = *(const short8*)(Ap + k0);
        *(short8*)&Bs[lr][lc] = *(const short8*)(Bp + k0);
        __syncthreads();
        short8 af0 = *(const short8*)&As[wm * 32 + l15][lq * 8];
        short8 af1 = *(const short8*)&As[wm * 32 + 16 + l15][lq * 8];
        short8 bf0 = *(const short8*)&Bs[wn * 32 + l15][lq * 8];
        short8 bf1 = *(const short8*)&Bs[wn * 32 + 16 + l15][lq * 8];
        acc00 = __builtin_amdgcn_mfma_f32_16x16x32_bf16(af0, bf0, acc00, 0, 0, 0);
        acc01 = __builtin_amdgcn_mfma_f32_16x16x32_bf16(af0, bf1, acc01, 0, 0, 0);
        acc10 = __builtin_amdgcn_mfma_f32_16x16x32_bf16(af1, bf0, acc10, 0, 0, 0);
        acc11 = __builtin_amdgcn_mfma_f32_16x16x32_bf16(af1, bf1, acc11, 0, 0, 0);
        __syncthreads();
    }
    floatx4 accs[2][2] = {{acc00, acc01}, {acc10, acc11}};
    #pragma unroll
    for (int i = 0; i < 2; i++)
        #pragma unroll
        for (int j = 0; j < 2; j++)
            #pragma unroll
            for (int r = 0; r < 4; r++) {
                int gm = bm * 64 + wm * 32 + i * 16 + lq * 4 + r;
                int gn = bn * 64 + wn * 32 + j * 16 + l15;
                if (gm < M) {
                    float v = accs[i][j][r];
                    if (bias0) v += bf2f(bias0[gn]);
                    if (bias1) v += bf2f(bias1[gn]);
                    C[(long)gm * ldc + gn] = v;
                }
            }
}

// ---------- v11: 128x128 NT GEMM with the conv-v4 proven structure ----------
__global__ __launch_bounds__(512) void gemm_nt_128(
    const u16* __restrict__ A, const u16* __restrict__ Bw,
    const u16* __restrict__ bias0, const u16* __restrict__ bias1,
    float* __restrict__ C, int M, int ldc)
{
    __shared__ __align__(16) u16 As[4][128][32];
    __shared__ __align__(16) u16 Bs[4][128][32];
    const int tid = threadIdx.x;
    const int bn = blockIdx.x, bm = blockIdx.y;
    const int wv = tid >> 6, l = tid & 63;
    const int wm = wv >> 2, wn = wv & 3;     // 2 (M) x 4 (N) wave grid
    const int l15 = l & 15, lq = l >> 4;
    const int ch = ((l & 3) ^ ((l >> 3) & 3)) * 8;

    int ar = bm * 128 + wv * 16 + (l >> 2);
    if (ar > M - 1) ar = M - 1;
    const u16* ga = A + (long)ar * 512 + ch;
    const u16* gb = Bw + (long)(bn * 128 + wv * 16 + (l >> 2)) * 512 + ch;

    floatx4 acc[4][2];
    #pragma unroll
    for (int i = 0; i < 4; i++)
        #pragma unroll
        for (int j = 0; j < 2; j++) acc[i][j] = (floatx4)(0.f);

    auto stage = [&](int k0, int pb) {
        gl_lds16(ga + k0, &As[pb][wv * 16][0]);
        gl_lds16(gb + k0, &Bs[pb][wv * 16][0]);
    };

    const int rs = (lq ^ ((l15 >> 1) & 3)) * 8;

    auto compute = [&](int cur) {
        short8 af[4], bf[2];
        #pragma unroll
        for (int i = 0; i < 4; i++) af[i] = *(const short8*)&As[cur][wm * 64 + i * 16 + l15][rs];
        #pragma unroll
        for (int j = 0; j < 2; j++) bf[j] = *(const short8*)&Bs[cur][wn * 32 + j * 16 + l15][rs];
        #pragma unroll
        for (int i = 0; i < 4; i++)
            #pragma unroll
            for (int j = 0; j < 2; j++)
                acc[i][j] = __builtin_amdgcn_mfma_f32_16x16x32_bf16(af[i], bf[j], acc[i][j], 0, 0, 0);
    };

    stage(0, 0); stage(32, 1); stage(64, 2);
    for (int k = 0; k < 14; k++) {
        asm volatile("s_waitcnt vmcnt(4)" ::: "memory");
        __builtin_amdgcn_s_barrier();
        asm volatile("" ::: "memory");
        if (k < 13) stage((k + 3) * 32, (k + 3) & 3);
        compute(k & 3);
    }
    asm volatile("s_waitcnt vmcnt(2)" ::: "memory");
    __builtin_amdgcn_s_barrier();
    asm volatile("" ::: "memory");
    compute(2);
    asm volatile("s_waitcnt vmcnt(0)" ::: "memory");
    __builtin_amdgcn_s_barrier();
    asm volatile("" ::: "memory");
    compute(3);

    #pragma unroll
    for (int i = 0; i < 4; i++)
        #pragma unroll
        for (int j = 0; j < 2; j++)
            #pragma unroll
            for (int r = 0; r < 4; r++) {
                int gm = bm * 128 + wm * 64 + i * 16 + lq * 4 + r;
                int gn = bn * 128 + wn * 32 + j * 16 + l15;
                if (gm < M) {
                    float v = acc[i][j][r];
                    if (bias0) v += bf2f(bias0[gn]);
                    if (bias1) v += bf2f(bias1[gn]);
                    C[(long)gm * ldc + gn] = v;
                }
            }
}

// ---------- conv3x3 v4 (proven): 8-wave (512thr) 128x128 tile, depth-3 counted-vmcnt, chunk-XOR swizzle ----------
__global__ __launch_bounds__(512) void conv_gemm(
    const u16* __restrict__ featP, const u16* __restrict__ W2,
    const u16* __restrict__ kb, u16* __restrict__ kmap)
{
    __shared__ __align__(16) u16 As[4][128][32];
    __shared__ __align__(16) u16 Bs[4][128][32];
    const int tid = threadIdx.x;
    int bm = blockIdx.x * 8 + (blockIdx.y & 7);
    int bn = blockIdx.y >> 3;
    if (bm >= 60) return;
    const int wv = tid >> 6, l = tid & 63;
    const int wm = wv >> 2, wn = wv & 3;     // 2 (M) x 4 (N) wave grid
    const int l15 = l & 15, lq = l >> 4;
    const int ch = ((l & 3) ^ ((l >> 3) & 3)) * 8;

    int ar = bm * 128 + wv * 16 + (l >> 2);
    int ab = ar / 240, ahw = ar % 240;
    const u16* ga = featP + ((long)(ab * 8 + ahw / 40) * 42 + (ahw % 40)) * 512 + ch;
    const u16* gb = W2 + (long)(bn * 128 + wv * 16 + (l >> 2)) * 4608 + ch;

    floatx4 acc[4][2];
    #pragma unroll
    for (int i = 0; i < 4; i++)
        #pragma unroll
        for (int j = 0; j < 2; j++) acc[i][j] = (floatx4)(0.f);

    auto stage = [&](int k0, int pb) {
        int kh = k0 / 1536;
        int rem = k0 - kh * 1536;
        int aoff = (kh * 42 + (rem >> 9)) * 512 + (rem & 511);
        gl_lds16(ga + aoff, &As[pb][wv * 16][0]);
        gl_lds16(gb + k0, &Bs[pb][wv * 16][0]);
    };

    const int rs = (lq ^ ((l15 >> 1) & 3)) * 8;

    auto compute = [&](int cur) {
        short8 af[4], bf[2];
        #pragma unroll
        for (int i = 0; i < 4; i++) af[i] = *(const short8*)&As[cur][wm * 64 + i * 16 + l15][rs];
        #pragma unroll
        for (int j = 0; j < 2; j++) bf[j] = *(const short8*)&Bs[cur][wn * 32 + j * 16 + l15][rs];
        #pragma unroll
        for (int i = 0; i < 4; i++)
            #pragma unroll
            for (int j = 0; j < 2; j++)
                acc[i][j] = __builtin_amdgcn_mfma_f32_16x16x32_bf16(af[i], bf[j], acc[i][j], 0, 0, 0);
    };

    stage(0, 0); stage(32, 1); stage(64, 2);
    for (int k = 0; k < 142; k++) {
        asm volatile("s_waitcnt vmcnt(4)" ::: "memory");
        __builtin_amdgcn_s_barrier();
        asm volatile("" ::: "memory");
        if (k < 141) stage((k + 3) * 32, (k + 3) & 3);
        compute(k & 3);
    }
    asm volatile("s_waitcnt vmcnt(2)" ::: "memory");
    __builtin_amdgcn_s_barrier();
    asm volatile("" ::: "memory");
    compute(2);
    asm volatile("s_waitcnt vmcnt(0)" ::: "memory");
    __builtin_amdgcn_s_barrier();
    asm volatile("" ::: "memory");
    compute(3);

    #pragma unroll
    for (int i = 0; i < 4; i++)
        #pragma unroll
        for (int j = 0; j < 2; j++)
            #pragma unroll
            for (int r = 0; r < 4; r++) {
                int row = bm * 128 + wm * 64 + i * 16 + lq * 4 + r;
                int col = bn * 128 + wn * 32 + j * 16 + l15;
                kmap[(long)row * 512 + col] = f2bf(acc[i][j][r] + bf2f(kb[col]));
            }
}

// ---------- LSTM recurrence v4 (proven): sentinel self-announcing exchange. DO NOT TOUCH. ----------
#define WL(F) F(0) F(1) F(2) F(3) F(4) F(5) F(6) F(7) F(8) F(9) F(10) F(11) F(12) F(13) F(14) F(15) \
              F(16) F(17) F(18) F(19) F(20) F(21) F(22) F(23) F(24) F(25) F(26) F(27) F(28) F(29) F(30) F(31)
#define WLA(F) F(0,0) F(1,1) F(2,2) F(3,3) F(4,0) F(5,1) F(6,2) F(7,3) \
               F(8,0) F(9,1) F(10,2) F(11,3) F(12,0) F(13,1) F(14,2) F(15,3) \
               F(16,0) F(17,1) F(18,2) F(19,3) F(20,0) F(21,1) F(22,2) F(23,3) \
               F(24,0) F(25,1) F(26,2) F(27,3) F(28,0) F(29,1) F(30,2) F(31,3)
#define WDECL(i) half8 w##i = wp8[(long)(j * 32 + i) * 512 + tid];
#define WPIN(i)  asm volatile("" : "+v"(w##i));
#define DOTC(i,k) { \
    half8 hv = *(const half8*)&hS2[(hf * 2 + (i / 16)) * 136 + (i % 16) * 8]; \
    a##k = __builtin_amdgcn_fdot2(__builtin_shufflevector(hv, hv, 0, 1), __builtin_shufflevector(w##i, w##i, 0, 1), a##k, false); \
    a##k = __builtin_amdgcn_fdot2(__builtin_shufflevector(hv, hv, 2, 3), __builtin_shufflevector(w##i, w##i, 2, 3), a##k, false); \
    a##k = __builtin_amdgcn_fdot2(__builtin_shufflevector(hv, hv, 4, 5), __builtin_shufflevector(w##i, w##i, 4, 5), a##k, false); \
    a##k = __builtin_amdgcn_fdot2(__builtin_shufflevector(hv, hv, 6, 7), __builtin_shufflevector(w##i, w##i, 6, 7), a##k, false); }

__global__ __launch_bounds__(512) __attribute__((amdgpu_waves_per_eu(2, 2))) void lstm_sync(
    const float* __restrict__ xpre, const _Float16* __restrict__ Wq3,
    u16* __restrict__ seq_out, float* __restrict__ f32_out,
    unsigned* __restrict__ hExT, int T, int f32_ld)
{
    const int i_ = blockIdx.x;
    const int slot = i_ >> 3;
    const int b = (i_ & 7) * 4 + (slot & 3);
    const int j = slot >> 2;
    const int tid = threadIdx.x;
    const int hf = tid & 1;

    __shared__ __align__(16) _Float16 hS2[4 * 136];
    __shared__ float part[512];

    const half8* wp8 = (const half8*)Wq3;
    WL(WDECL)
    WL(WPIN)
    float cst = 0.f;

    for (int t = 0; t < T; t++) {
        float xi = 0.f, xf = 0.f, xg = 0.f, xo = 0.f;
        if (tid < 64) {
            const float* xp = xpre + ((long)b * T + t) * 2048 + j * 64 + tid;
            xi = xp[0]; xf = xp[512]; xg = xp[1024]; xo = xp[1536];
        }
        float a0 = 0.f, a1 = 0.f, a2 = 0.f, a3 = 0.f;
        if (t > 0) {
            if (tid < 64) {
                const unsigned* src = &hExT[((long)(t - 1) * 32 + b) * 256 + tid * 4];
                unsigned v0, v1, v2, v3;
                do {
                    v0 = __hip_atomic_load(src + 0, __ATOMIC_RELAXED, AGENT);
                    v1 = __hip_atomic_load(src + 1, __ATOMIC_RELAXED, AGENT);
                    v2 = __hip_atomic_load(src + 2, __ATOMIC_RELAXED, AGENT);
                    v3 = __hip_atomic_load(src + 3, __ATOMIC_RELAXED, AGENT);
                } while (v0 == SENT || v1 == SENT || v2 == SENT || v3 == SENT);
                uint4v v; v.x = v0; v.y = v1; v.z = v2; v.w = v3;
                *(uint4v*)&hS2[(tid >> 4) * 136 + (tid & 15) * 8] = v;
            }
            __syncthreads();
            WLA(DOTC)
        }
        part[tid] = (a0 + a1) + (a2 + a3);
        __syncthreads();
        if (tid < 64) {
            float gi = xi + part[(0   + tid) * 2] + part[(0   + tid) * 2 + 1];
            float gf = xf + part[(64  + tid) * 2] + part[(64  + tid) * 2 + 1];
            float gg = xg + part[(128 + tid) * 2] + part[(128 + tid) * 2 + 1];
            float go = xo + part[(192 + tid) * 2] + part[(192 + tid) * 2 + 1];
            cst = sigm_(gf) * cst + sigm_(gi) * tanh_(gg);
            float h = sigm_(go) * tanh_(cst);
            float hlo = __shfl(h, tid * 2);
            float hhi = __shfl(h, tid * 2 + 1);
            if (t + 1 < T && tid < 32) {
                half2v hp; hp[0] = (_Float16)hlo; hp[1] = (_Float16)hhi;
                __hip_atomic_store(&hExT[((long)t * 32 + b) * 256 + j * 32 + tid],
                                   *(unsigned*)&hp, __ATOMIC_RELAXED, AGENT);
            }
            asm volatile("" ::: "memory");
            long so = ((long)b * T + t) * 512 + j * 64 + tid;
            seq_out[so] = f2bf(h);
            if (f32_out) f32_out[((long)b * T + t) * f32_ld + j * 64 + tid] = h;
        }
    }
}

// ---------- token build ----------
__global__ __launch_bounds__(256) void tok_k(
    const float* __restrict__ holf, const u16* __restrict__ cemb,
    const int* __restrict__ label, u16* __restrict__ tok)
{
    int idx = blockIdx.x * 256 + threadIdx.x;
    int c = idx & 511;
    int m = idx >> 9;
    int b = m / 27, t = m % 27;
    float v;
    if (t == 0) v = holf[(long)b * 512 + c];
    else v = bf2f(cemb[(long)label[b * 26 + (t - 1)] * 512 + c]);
    tok[idx] = f2bf(v);
}

// ---------- fused score v2 (r9-verified) ----------
__global__ __launch_bounds__(256) void score_k(
    const float* __restrict__ q, const u16* __restrict__ kmap,
    const u16* __restrict__ sW, const u16* __restrict__ sb,
    const float* __restrict__ vr, float* __restrict__ aw)
{
    int blk = blockIdx.x;
    int xcd = blk & 7, rest = blk >> 3;
    int bq = rest & 3, t = rest >> 2;
    int b = xcd * 4 + bq;
    int bt = b * 27 + t;
    int tid = threadIdx.x, wv = tid >> 6, ln = tid & 63;

    __shared__ float sc[240];
    __shared__ float red[256];

    float qr[8], sr[8];
    const float* qp = q + (long)bt * 512 + ln * 8;
    #pragma unroll
    for (int i = 0; i < 8; i++) qr[i] = qp[i];
    #pragma unroll
    for (int i = 0; i < 8; i++) sr[i] = bf2f(sW[ln * 8 + i]);

    const u16* kb_ = kmap + (long)b * 240 * 512;
    for (int r = wv * 60; r < wv * 60 + 60; r++) {
        short8 kv = *(const short8*)(kb_ + (long)r * 512 + ln * 8);
        float acc = 0.f;
        #pragma unroll
        for (int i = 0; i < 8; i++) {
            float x = bf2f((u16)kv[i]) + qr[i];
            acc = fmaf(sr[i], tanh_(x), acc);
        }
        #pragma unroll
        for (int m = 32; m > 0; m >>= 1) acc += __shfl_xor(acc, m);
        if (ln == 0) sc[r] = acc;
    }
    __syncthreads();

    float scv = -INFINITY, ex = 0.f;
    if (tid < 240) {
        float rr = vr[b];
        int vw = (int)ceilf(40.f * rr);
        if (vw > 40) vw = 40;
        int wcol = tid % 40;
        scv = (wcol >= vw) ? -INFINITY : (sc[tid] + bf2f(sb[0]));
    }
    red[tid] = scv;
    __syncthreads();
    for (int s = 128; s > 0; s >>= 1) {
        if (tid < s) red[tid] = fmaxf(red[tid], red[tid + s]);
        __syncthreads();
    }
    float mx = red[0];
    __syncthreads();
    if (tid < 240) ex = (scv == -INFINITY) ? 0.f : __expf(scv - mx);
    red[tid] = ex;
    __syncthreads();
    for (int s = 128; s > 0; s >>= 1) {
        if (tid < s) red[tid] += red[tid + s];
        __syncthreads();
    }
    float inv = __builtin_amdgcn_rcpf(red[0]);
    if (tid < 240) aw[(long)bt * 240 + tid] = ex * inv;
}

// ---------- attn_feat -> concat cols [512,1024) ----------
__global__ __launch_bounds__(256) void attn_k(
    const void* __restrict__ feat, const float* __restrict__ aw,
    float* __restrict__ concat, const int* __restrict__ flag)
{
    const int fl = *flag;
    int b = blockIdx.x >> 3;
    int cc = (blockIdx.x & 7) * 64;
    int tid = threadIdx.x;
    __shared__ float awS[27 * 240];
    __shared__ u16 fS[64 * 240];
    for (int i = tid; i < 27 * 240; i += 256) awS[i] = aw[(long)b * 27 * 240 + i];
    long fbase = ((long)b * 512 + cc) * 240;
    for (int i = tid; i < 64 * 240; i += 256)
        fS[i] = fl ? f2bf(((const float*)feat)[fbase + i]) : ((const u16*)feat)[fbase + i];
    __syncthreads();
    for (int item = tid; item < 64 * 27; item += 256) {
        int c = item / 27, t = item % 27;
        const u16* fp = &fS[c * 240];
        const float* ap = &awS[t * 240];
        float acc = 0.f;
        for (int hw = 0; hw < 240; hw++) acc = fmaf(bf2f(fp[hw]), ap[hw], acc);
        concat[((long)(b * 27 + t)) * 1536 + 512 + cc + c] = acc;
    }
}

// ---------- prediction + slice ----------
__global__ __launch_bounds__(256) void pred_k(
    const float* __restrict__ concat, const float* __restrict__ holf,
    const u16* __restrict__ pW, const u16* __restrict__ pb,
    void* __restrict__ out, const int* __restrict__ flag)
{
    int m0 = blockIdx.x * 4;
    int tid = threadIdx.x;
    const int fl = *flag;
    __shared__ float aS[4][1024];
    __shared__ float hS[4][512];
    for (int i = tid; i < 4 * 1024; i += 256)
        aS[i / 1024][i % 1024] = concat[(long)(m0 + i / 1024) * 1536 + (i % 1024)];
    for (int i = tid; i < 4 * 512; i += 256) {
        int m = m0 + i / 512;
        hS[i / 512][i % 512] = holf[(long)(m / 27) * 512 + (i % 512)];
    }
    __syncthreads();
    int r = tid >> 6;
    int nb = tid & 63;
    int m = m0 + r;
    int b = m / 27, t = m % 27;
    for (int n = nb; n < 97; n += 64) {
        const u16* wp = pW + (long)n * 1536;
        float acc = 0.f;
        for (int k = 0; k < 1024; k++) acc = fmaf(aS[r][k], bf2f(wp[k]), acc);
        for (int k = 0; k < 512; k++) acc = fmaf(hS[r][k], bf2f(wp[1024 + k]), acc);
        acc += bf2f(pb[n]);
        if (t > 0) {
            long o = ((long)(b * 26 + (t - 1))) * 97 + n;
            if (fl) ((float*)out)[o] = acc;
            else    ((u16*)out)[o] = f2bf(acc);
        }
    }
}

// ---------- launch ----------
extern "C" void kernel_launch(void* const* d_in, const int* in_sizes, int n_in,
                              void* d_out, int out_size, void* d_ws, size_t ws_size,
                              hipStream_t stream) {
    (void)in_sizes; (void)n_in; (void)out_size; (void)ws_size;
    const void* feat_r = d_in[0];
    const int*  label  = (const int*)d_in[1];
    const void* vr_r   = d_in[2];

    char* w = (char*)d_ws;
    size_t off = 0;
    auto alloc = [&](size_t bytes) -> void* {
        void* p = w + off;
        off = (off + bytes + 63) & ~(size_t)63;
        return p;
    };
    int*   flag    = (int*)  alloc(4);
    unsigned* hEx  = (unsigned*)alloc((size_t)HEX_WORDS * 4);
    u16*   canon   = (u16*)  alloc((size_t)CANON_TOTAL * 2);
    float* cvr     = (float*)alloc(32ull * 4);
    u16*   featv   = (u16*)  alloc(655360ull * 2);
    float* xpre    = (float*)alloc(2621440ull * 4);   // kmap aliases after LSTMs
    u16*   seq0    = (u16*)  alloc(655360ull * 2);
    u16*   seq1    = (u16*)  alloc(655360ull * 2);
    u16*   tok     = (u16*)  alloc(442368ull * 2);
    u16*   seqd0   = (u16*)  alloc(442368ull * 2);
    u16*   Hid     = (u16*)  alloc(442368ull * 2);
    float* holf    = (float*)alloc(16384ull * 4);
    float* qf      = (float*)alloc(442368ull * 4);
    u16*   featP   = (u16*)  alloc(5505024ull * 2);
    u16*   W2      = (u16*)  alloc(2359296ull * 2);
    float* aw      = (float*)alloc(207360ull * 4);
    float* concat  = (float*)alloc(1327104ull * 4);
    _Float16* Wq[4];
    for (int i = 0; i < 4; i++) Wq[i] = (_Float16*)alloc(1048576ull * 2);
    u16*   kmap    = (u16*)xpre;

    unsigned* hEx0 = hEx;
    unsigned* hEx1 = hEx + 40ull * 8192;
    unsigned* hEx2 = hEx + 80ull * 8192;
    unsigned* hEx3 = hEx + 107ull * 8192;

    u16* cW0    = canon + OFF_W0;
    u16* cW1    = canon + OFF_W1;
    u16* cW2    = canon + OFF_W2;
    u16* cW3    = canon + OFF_W3;
    u16* cb0    = canon + OFF_B;
    u16* cencW  = canon + OFF_ENCW;
    u16* cqW    = canon + OFF_QW;
    u16* cpredW = canon + OFF_PREDW;
    u16* cemb   = canon + OFF_EMB;
    u16* cencb  = canon + OFF_ENCB;
    u16* cqb    = canon + OFF_QB;
    u16* ckb    = canon + OFF_KB;
    u16* csW    = canon + OFF_SW;
    u16* csb    = canon + OFF_SB;
    u16* cpredb = canon + OFF_PREDB;

    // ---- fused prep: 7 kernels -> 1 dispatch ----
    PrepArgs P;
    P.S.e0Wih = d_in[3];  P.S.e1Wih = d_in[7];  P.S.d0Wih = d_in[20]; P.S.d1Wih = d_in[24];
    P.S.b0 = d_in[5];  P.S.b1 = d_in[6];  P.S.b2 = d_in[9];  P.S.b3 = d_in[10];
    P.S.b4 = d_in[22]; P.S.b5 = d_in[23]; P.S.b6 = d_in[26]; P.S.b7 = d_in[27];
    P.S.encW = d_in[11]; P.S.qW = d_in[13]; P.S.predW = d_in[28]; P.S.emb = d_in[19];
    P.S.encb = d_in[12]; P.S.qb = d_in[14]; P.S.kb = d_in[16]; P.S.sW = d_in[17];
    P.S.sb = d_in[18]; P.S.predb = d_in[29];
    P.feat_raw = feat_r; P.vr_src = vr_r; P.kW_src = d_in[15];
    P.wq_s0 = d_in[4]; P.wq_s1 = d_in[8]; P.wq_s2 = d_in[21]; P.wq_s3 = d_in[25];
    P.flag = flag; P.hEx = hEx; P.canon = canon; P.cvr = cvr;
    P.featv = featv; P.featP = featP; P.W2 = W2;
    P.wq_d0 = Wq[0]; P.wq_d1 = Wq[1]; P.wq_d2 = Wq[2]; P.wq_d3 = Wq[3];
    prep_all<<<dim3(PB_TOTAL), 256, 0, stream>>>(P);

    // ---- encoder ----
    gemm_nt_128<<<dim3(16, 10), 512, 0, stream>>>(featv, cW0, cb0 + 0 * 2048, cb0 + 1 * 2048, xpre, 1280, 2048);
    lstm_sync<<<dim3(256), 512, 0, stream>>>(xpre, Wq[0], seq0, nullptr, hEx0, 40, 0);
    gemm_nt_128<<<dim3(16, 10), 512, 0, stream>>>(seq0, cW1, cb0 + 2 * 2048, cb0 + 3 * 2048, xpre, 1280, 2048);
    lstm_sync<<<dim3(256), 512, 0, stream>>>(xpre, Wq[1], seq1, nullptr, hEx1, 40, 0);
    gemm_nt_f32<<<dim3(8, 1), 256, 0, stream>>>(seq1 + 39 * 512, 40 * 512, cencW, cencb, nullptr, holf, 32, 512, 512, 512);

    // ---- decoder ----
    tok_k<<<dim3(1728), 256, 0, stream>>>(holf, cemb, label, tok);
    gemm_nt_128<<<dim3(16, 7), 512, 0, stream>>>(tok, cW2, cb0 + 4 * 2048, cb0 + 5 * 2048, xpre, 864, 2048);
    lstm_sync<<<dim3(256), 512, 0, stream>>>(xpre, Wq[2], seqd0, nullptr, hEx2, 27, 0);
    gemm_nt_128<<<dim3(16, 7), 512, 0, stream>>>(seqd0, cW3, cb0 + 6 * 2048, cb0 + 7 * 2048, xpre, 864, 2048);
    lstm_sync<<<dim3(256), 512, 0, stream>>>(xpre, Wq[3], Hid, concat, hEx3, 27, 1536);

    // ---- attention (xpre dead; kmap aliases it) ----
    gemm_nt_128<<<dim3(4, 7), 512, 0, stream>>>(Hid, cqW, cqb, nullptr, qf, 864, 512);
    conv_gemm<<<dim3(8, 32), 512, 0, stream>>>(featP, W2, ckb, kmap);
    score_k<<<dim3(864), 256, 0, stream>>>(qf, kmap, csW, csb, cvr, aw);
    attn_k<<<dim3(256), 256, 0, stream>>>(feat_r, aw, concat, flag);

    // ---- prediction ----
    pred_k<<<dim3(216), 256, 0, stream>>>(concat, holf, cpredW, cpredb, d_out, flag);
}

// Round 11
// 799.816 us; speedup vs baseline: 1.1019x; 1.0041x over previous
//
#include <hip/hip_runtime.h>

typedef unsigned short u16;
typedef __attribute__((ext_vector_type(8))) short short8;
typedef __attribute__((ext_vector_type(4))) float floatx4;
typedef _Float16 half8 __attribute__((ext_vector_type(8)));
typedef _Float16 half2v __attribute__((ext_vector_type(2)));
typedef unsigned uint4v __attribute__((ext_vector_type(4)));

#define AGENT __HIP_MEMORY_SCOPE_AGENT
#define SENT 0x7FFF7FFFu   // f16 NaN pair — unreachable: h = sigm*tanh in (-1,1)

// ---------- helpers ----------
__device__ __forceinline__ float bf2f(u16 v) { return __uint_as_float(((unsigned)v) << 16); }
__device__ __forceinline__ u16 f2bf(float f) {
    unsigned u = __float_as_uint(f);
    unsigned r = (u + 0x7FFFu + ((u >> 16) & 1u)) >> 16;
    return (u16)r;
}
// fast transcendentals: native v_exp + raw v_rcp (no precise-div sequence)
__device__ __forceinline__ float sigm_(float x) {
    return __builtin_amdgcn_rcpf(1.f + __expf(-x));
}
__device__ __forceinline__ float tanh_(float x) {
    x = fminf(fmaxf(x, -15.f), 15.f);
    float e = __expf(2.f * x);
    return (e - 1.f) * __builtin_amdgcn_rcpf(e + 1.f);
}

// async global->LDS, 16B per lane; LDS dest is wave-uniform base + lane*16
typedef __attribute__((address_space(1))) void gvoid_t;
typedef __attribute__((address_space(3))) void lvoid_t;
__device__ __forceinline__ void gl_lds16(const void* g, void* l) {
    __builtin_amdgcn_global_load_lds((gvoid_t*)g, (lvoid_t*)l, 16, 0, 0);
}

// B=32, C=512, H=6, W=40, NC=97, L=26, T=27
#define HEX_WORDS (134 * 32 * 256)

// ---------- offsets ----------
struct SrcPtrs {
    const void* e0Wih; const void* e1Wih; const void* d0Wih; const void* d1Wih;
    const void* b0; const void* b1; const void* b2; const void* b3;
    const void* b4; const void* b5; const void* b6; const void* b7;
    const void* encW; const void* qW; const void* predW; const void* emb;
    const void* encb; const void* qb; const void* kb; const void* sW;
    const void* sb; const void* predb;
};
#define OFF_W0      0
#define OFF_W1      1048576
#define OFF_W2      2097152
#define OFF_W3      3145728
#define OFF_B       4194304
#define OFF_ENCW    4210688
#define OFF_QW      4472832
#define OFF_PREDW   4734976
#define OFF_EMB     4883968
#define OFF_ENCB    4933632
#define OFF_QB      4934144
#define OFF_KB      4934656
#define OFF_SW      4935168
#define OFF_SB      4935680
#define OFF_PREDB   4935681
#define CANON_TOTAL 4935778

// ---------- dtype sniff (32 loads of ONE 64B line; L2-broadcast ~free) ----------
__device__ __forceinline__ int sniff_(const void* feat_raw) {
    const u16* p = (const u16*)feat_raw;
    int insane = 0;
    #pragma unroll
    for (int i = 0; i < 32; i += 2) {
        float x = bf2f(p[i]);
        float a = fabsf(x);
        if (!(a <= 1000.f)) insane = 1;
        if (x != 0.f && a < 1e-8f) insane = 1;
    }
    return insane;
}

// ---------- v13: fused prep (5 branches) — feat transposes moved to featp_k ----------
// v12 post-mortem: prep_all = 117 µs with FETCH 185 MB vs ~40 MB of real input.
// The over-fetch is featv/padfeat: lanes mapped to consecutive c read feat[b][c][h][w]
// at 480 B/lane stride -> each 64B line fetched for 2 bytes, rest belongs to other
// blocks (refetched after eviction). canon/w2/hEx are coalesced. Fix: featv/padfeat
// become featp_k (LDS-tiled transpose, coalesced both sides); prep_all keeps the rest.
struct PrepArgs {
    SrcPtrs S;
    const void* feat_raw;
    const void* vr_src;
    const void* kW_src;
    const void* wq_s0; const void* wq_s1; const void* wq_s2; const void* wq_s3;
    int* flag;
    unsigned* hEx;
    u16* canon;
    float* cvr;
    u16* W2;
    _Float16* wq_d0; _Float16* wq_d1; _Float16* wq_d2; _Float16* wq_d3;
};

// block ranges
#define PB_INIT    0        // 4288 blocks  : hEx sentinel fill (+flag from idx 0)
#define PB_CANON   4288     // 19281 blocks : canon_all
#define PB_CANONF  23569    // 1 block      : cvr (32 floats)
#define PB_W2      23570    // 9216 blocks  : conv weight reshuffle
#define PB_WQ3     32786    // 2048 blocks  : 4x Whh -> f16 dot layout
#define PB_TOTAL   34834

__global__ __launch_bounds__(256) void prep_all(PrepArgs P)
{
    const int blk = blockIdx.x;
    const int tid = threadIdx.x;

    if (blk < PB_CANON) {                       // ---- init: sentinel fill ----
        int idx = blk * 256 + tid;
        P.hEx[idx] = SENT;
        if (idx == 0) *P.flag = sniff_(P.feat_raw);
        return;
    }
    const int fl = sniff_(P.feat_raw);          // per-block local dtype flag

    if (blk < PB_CANONF) {                      // ---- canon_all ----
        int idx = (blk - PB_CANON) * 256 + tid;
        if (idx >= CANON_TOTAL) return;
        const SrcPtrs& S = P.S;
        const void* s; int loc;
        if (idx < OFF_B) {
            int k = idx >> 20; loc = idx & 1048575;
            s = (k == 0) ? S.e0Wih : (k == 1) ? S.e1Wih : (k == 2) ? S.d0Wih : S.d1Wih;
        } else if (idx < OFF_ENCW) {
            int r = idx - OFF_B; int k = r >> 11; loc = r & 2047;
            s = (k == 0) ? S.b0 : (k == 1) ? S.b1 : (k == 2) ? S.b2 : (k == 3) ? S.b3
              : (k == 4) ? S.b4 : (k == 5) ? S.b5 : (k == 6) ? S.b6 : S.b7;
        } else if (idx < OFF_QW)    { s = S.encW;  loc = idx - OFF_ENCW; }
        else if (idx < OFF_PREDW)   { s = S.qW;    loc = idx - OFF_QW; }
        else if (idx < OFF_EMB)     { s = S.predW; loc = idx - OFF_PREDW; }
        else if (idx < OFF_ENCB)    { s = S.emb;   loc = idx - OFF_EMB; }
        else if (idx < OFF_QB)      { s = S.encb;  loc = idx - OFF_ENCB; }
        else if (idx < OFF_KB)      { s = S.qb;    loc = idx - OFF_QB; }
        else if (idx < OFF_SW)      { s = S.kb;    loc = idx - OFF_KB; }
        else if (idx < OFF_SB)      { s = S.sW;    loc = idx - OFF_SW; }
        else if (idx < OFF_PREDB)   { s = S.sb;    loc = idx - OFF_SB; }
        else                        { s = S.predb; loc = idx - OFF_PREDB; }
        P.canon[idx] = fl ? f2bf(((const float*)s)[loc]) : ((const u16*)s)[loc];
    } else if (blk == PB_CANONF) {              // ---- canonf (valid_ratios) ----
        if (tid < 32)
            P.cvr[tid] = fl ? ((const float*)P.vr_src)[tid] : bf2f(((const u16*)P.vr_src)[tid]);
    } else if (blk < PB_WQ3) {                  // ---- w2 ----
        int idx = (blk - PB_W2) * 256 + tid;
        int co = idx / 4608;
        int r = idx % 4608;
        int kh = r / 1536;
        int r2 = r % 1536;
        int kw = r2 / 512;
        int ci = r2 & 511;
        long si = ((long)(co * 512 + ci) * 3 + kh) * 3 + kw;
        P.W2[idx] = fl ? f2bf(((const float*)P.kW_src)[si]) : ((const u16*)P.kW_src)[si];
    } else {                                    // ---- wq3_all ----
        int gb = blk - PB_WQ3;
        int id = gb >> 9;
        const void* W = (id == 0) ? P.wq_s0 : (id == 1) ? P.wq_s1 : (id == 2) ? P.wq_s2 : P.wq_s3;
        _Float16* D = (id == 0) ? P.wq_d0 : (id == 1) ? P.wq_d1 : (id == 2) ? P.wq_d2 : P.wq_d3;
        int o = (gb & 511) * 256 + tid;
        int t = o & 511;
        int c = (o >> 9) & 31;
        int j = o >> 14;
        int rid = t >> 1, hf = t & 1;
        int n = (rid >> 6) * 512 + j * 64 + (rid & 63);
        int k = hf * 256 + c * 8;
        _Float16* dst = D + (long)o * 8;
        #pragma unroll
        for (int jj = 0; jj < 8; jj++) {
            long si = (long)n * 512 + k + jj;
            float v = fl ? ((const float*)W)[si] : bf2f(((const u16*)W)[si]);
            dst[jj] = (_Float16)v;
        }
    }
}

// ---------- v13: featv + padfeat via LDS-tiled transpose (coalesced both sides) ----------
// 256 blocks = 32 b x 8 c-tiles of 64. Each block's [64c x 240hw] slab is CONTIGUOUS
// in global memory (feat[b][c][h][w], c-range contiguous) -> coalesced read into LDS
// [64][242] (pad: lane stride 121 dwords, gcd(121,32)=1 -> conflict-free col reads).
// featv = max over h (f2bf before max is safe: bf16 rounding is monotone); featP
// interior + zero ring written with lanes over c -> coalesced stores.
__global__ __launch_bounds__(256) void featp_k(
    const void* __restrict__ feat, u16* __restrict__ featv, u16* __restrict__ featP)
{
    const int tid = threadIdx.x;
    const int b = blockIdx.x >> 3;
    const int c0 = (blockIdx.x & 7) * 64;
    const int fl = sniff_(feat);

    __shared__ u16 S[64][242];

    long gbase = ((long)b * 512 + c0) * 240;
    for (int i = tid; i < 64 * 240; i += 256) {
        float x = fl ? ((const float*)feat)[gbase + i] : bf2f(((const u16*)feat)[gbase + i]);
        S[i / 240][i % 240] = f2bf(x);
    }
    __syncthreads();

    // featv: 40w x 64c, lanes over c (coalesced store; LDS col read conflict-free)
    for (int i = tid; i < 40 * 64; i += 256) {
        int w = i >> 6, c = i & 63;
        float mx = bf2f(S[c][w]);
        #pragma unroll
        for (int h = 1; h < 6; h++) mx = fmaxf(mx, bf2f(S[c][h * 40 + w]));
        featv[((long)(b * 40 + w)) * 512 + c0 + c] = f2bf(mx);
    }
    // featP interior: hp 1..6, wp 1..40
    for (int i = tid; i < 6 * 40 * 64; i += 256) {
        int c = i & 63; int r = i >> 6;
        int wp1 = r % 40, hp1 = r / 40;
        featP[((long)(b * 8 + hp1 + 1) * 42 + (wp1 + 1)) * 512 + c0 + c] = S[c][hp1 * 40 + wp1];
    }
    // featP zero ring: hp in {0,7} all 42 wp; hp 1..6 wp in {0,41} -> 96 rows
    for (int i = tid; i < 96 * 64; i += 256) {
        int c = i & 63; int r = i >> 6;
        int hp, wp;
        if (r < 42)      { hp = 0; wp = r; }
        else if (r < 84) { hp = 7; wp = r - 42; }
        else             { int q = r - 84; hp = 1 + (q >> 1); wp = (q & 1) * 41; }
        featP[((long)(b * 8 + hp) * 42 + wp) * 512 + c0 + c] = 0;
    }
}

// ---------- NT GEMM (64-tile; kept for tiny M=32 encW GEMM) ----------
__global__ __launch_bounds__(256) void gemm_nt_f32(
    const u16* __restrict__ A, int lda,
    const u16* __restrict__ Bw,
    const u16* __restrict__ bias0, const u16* __restrict__ bias1,
    float* __restrict__ C, int M, int N, int K, int ldc)
{
    __shared__ __align__(16) u16 As[64][40];
    __shared__ __align__(16) u16 Bs[64][40];
    const int tid = threadIdx.x;
    const int bn = blockIdx.x, bm = blockIdx.y;
    const int l = tid & 63, wid = tid >> 6;
    const int wm = wid >> 1, wn = wid & 1;
    const int lr = tid >> 2, lc = (tid & 3) * 8;
    const int l15 = l & 15, lq = l >> 4;

    floatx4 acc00 = (floatx4)(0.f), acc01 = (floatx4)(0.f), acc10 = (floatx4)(0.f), acc11 = (floatx4)(0.f);

    int am = bm * 64 + lr; if (am > M - 1) am = M - 1;
    const u16* Ap = A + (long)am * lda + lc;
    const u16* Bp = Bw + (long)(bn * 64 + lr) * K + lc;

    for (int k0 = 0; k0 < K; k0 += 32) {
        *(short8*)&As[lr][lc] = *(const short8*)(Ap + k0);
        *(short8*)&Bs[lr][lc] = *(const short8*)(Bp + k0);
        __syncthreads();
        short8 af0 = *(const short8*)&As[wm * 32 + l15][lq * 8];
        short8 af1 = *(const short8*)&As[wm * 32 + 16 + l15][lq * 8];
        short8 bf0 = *(const short8*)&Bs[wn * 32 + l15][lq * 8];
        short8 bf1 = *(const short8*)&Bs[wn * 32 + 16 + l15][lq * 8];
        acc00 = __builtin_amdgcn_mfma_f32_16x16x32_bf16(af0, bf0, acc00, 0, 0, 0);
        acc01 = __builtin_amdgcn_mfma_f32_16x16x32_bf16(af0, bf1, acc01, 0, 0, 0);
        acc10 = __builtin_amdgcn_mfma_f32_16x16x32_bf16(af1, bf0, acc10, 0, 0, 0);
        acc11 = __builtin_amdgcn_mfma_f32_16x16x32_bf16(af1, bf1, acc11, 0, 0, 0);
        __syncthreads();
    }
    floatx4 accs[2][2] = {{acc00, acc01}, {acc10, acc11}};
    #pragma unroll
    for (int i = 0; i < 2; i++)
        #pragma unroll
        for (int j = 0; j < 2; j++)
            #pragma unroll
            for (int r = 0; r < 4; r++) {
                int gm = bm * 64 + wm * 32 + i * 16 + lq * 4 + r;
                int gn = bn * 64 + wn * 32 + j * 16 + l15;
                if (gm < M) {
                    float v = accs[i][j][r];
                    if (bias0) v += bf2f(bias0[gn]);
                    if (bias1) v += bf2f(bias1[gn]);
                    C[(long)gm * ldc + gn] = v;
                }
            }
}

// ---------- v11: 128x128 NT GEMM with the conv-v4 proven structure ----------
__global__ __launch_bounds__(512) void gemm_nt_128(
    const u16* __restrict__ A, const u16* __restrict__ Bw,
    const u16* __restrict__ bias0, const u16* __restrict__ bias1,
    float* __restrict__ C, int M, int ldc)
{
    __shared__ __align__(16) u16 As[4][128][32];
    __shared__ __align__(16) u16 Bs[4][128][32];
    const int tid = threadIdx.x;
    const int bn = blockIdx.x, bm = blockIdx.y;
    const int wv = tid >> 6, l = tid & 63;
    const int wm = wv >> 2, wn = wv & 3;     // 2 (M) x 4 (N) wave grid
    const int l15 = l & 15, lq = l >> 4;
    const int ch = ((l & 3) ^ ((l >> 3) & 3)) * 8;

    int ar = bm * 128 + wv * 16 + (l >> 2);
    if (ar > M - 1) ar = M - 1;
    const u16* ga = A + (long)ar * 512 + ch;
    const u16* gb = Bw + (long)(bn * 128 + wv * 16 + (l >> 2)) * 512 + ch;

    floatx4 acc[4][2];
    #pragma unroll
    for (int i = 0; i < 4; i++)
        #pragma unroll
        for (int j = 0; j < 2; j++) acc[i][j] = (floatx4)(0.f);

    auto stage = [&](int k0, int pb) {
        gl_lds16(ga + k0, &As[pb][wv * 16][0]);
        gl_lds16(gb + k0, &Bs[pb][wv * 16][0]);
    };

    const int rs = (lq ^ ((l15 >> 1) & 3)) * 8;

    auto compute = [&](int cur) {
        short8 af[4], bf[2];
        #pragma unroll
        for (int i = 0; i < 4; i++) af[i] = *(const short8*)&As[cur][wm * 64 + i * 16 + l15][rs];
        #pragma unroll
        for (int j = 0; j < 2; j++) bf[j] = *(const short8*)&Bs[cur][wn * 32 + j * 16 + l15][rs];
        #pragma unroll
        for (int i = 0; i < 4; i++)
            #pragma unroll
            for (int j = 0; j < 2; j++)
                acc[i][j] = __builtin_amdgcn_mfma_f32_16x16x32_bf16(af[i], bf[j], acc[i][j], 0, 0, 0);
    };

    stage(0, 0); stage(32, 1); stage(64, 2);
    for (int k = 0; k < 14; k++) {
        asm volatile("s_waitcnt vmcnt(4)" ::: "memory");
        __builtin_amdgcn_s_barrier();
        asm volatile("" ::: "memory");
        if (k < 13) stage((k + 3) * 32, (k + 3) & 3);
        compute(k & 3);
    }
    asm volatile("s_waitcnt vmcnt(2)" ::: "memory");
    __builtin_amdgcn_s_barrier();
    asm volatile("" ::: "memory");
    compute(2);
    asm volatile("s_waitcnt vmcnt(0)" ::: "memory");
    __builtin_amdgcn_s_barrier();
    asm volatile("" ::: "memory");
    compute(3);

    #pragma unroll
    for (int i = 0; i < 4; i++)
        #pragma unroll
        for (int j = 0; j < 2; j++)
            #pragma unroll
            for (int r = 0; r < 4; r++) {
                int gm = bm * 128 + wm * 64 + i * 16 + lq * 4 + r;
                int gn = bn * 128 + wn * 32 + j * 16 + l15;
                if (gm < M) {
                    float v = acc[i][j][r];
                    if (bias0) v += bf2f(bias0[gn]);
                    if (bias1) v += bf2f(bias1[gn]);
                    C[(long)gm * ldc + gn] = v;
                }
            }
}

// ---------- conv3x3 v4 (proven): 8-wave (512thr) 128x128 tile, depth-3 counted-vmcnt, chunk-XOR swizzle ----------
__global__ __launch_bounds__(512) void conv_gemm(
    const u16* __restrict__ featP, const u16* __restrict__ W2,
    const u16* __restrict__ kb, u16* __restrict__ kmap)
{
    __shared__ __align__(16) u16 As[4][128][32];
    __shared__ __align__(16) u16 Bs[4][128][32];
    const int tid = threadIdx.x;
    int bm = blockIdx.x * 8 + (blockIdx.y & 7);
    int bn = blockIdx.y >> 3;
    if (bm >= 60) return;
    const int wv = tid >> 6, l = tid & 63;
    const int wm = wv >> 2, wn = wv & 3;     // 2 (M) x 4 (N) wave grid
    const int l15 = l & 15, lq = l >> 4;
    const int ch = ((l & 3) ^ ((l >> 3) & 3)) * 8;

    int ar = bm * 128 + wv * 16 + (l >> 2);
    int ab = ar / 240, ahw = ar % 240;
    const u16* ga = featP + ((long)(ab * 8 + ahw / 40) * 42 + (ahw % 40)) * 512 + ch;
    const u16* gb = W2 + (long)(bn * 128 + wv * 16 + (l >> 2)) * 4608 + ch;

    floatx4 acc[4][2];
    #pragma unroll
    for (int i = 0; i < 4; i++)
        #pragma unroll
        for (int j = 0; j < 2; j++) acc[i][j] = (floatx4)(0.f);

    auto stage = [&](int k0, int pb) {
        int kh = k0 / 1536;
        int rem = k0 - kh * 1536;
        int aoff = (kh * 42 + (rem >> 9)) * 512 + (rem & 511);
        gl_lds16(ga + aoff, &As[pb][wv * 16][0]);
        gl_lds16(gb + k0, &Bs[pb][wv * 16][0]);
    };

    const int rs = (lq ^ ((l15 >> 1) & 3)) * 8;

    auto compute = [&](int cur) {
        short8 af[4], bf[2];
        #pragma unroll
        for (int i = 0; i < 4; i++) af[i] = *(const short8*)&As[cur][wm * 64 + i * 16 + l15][rs];
        #pragma unroll
        for (int j = 0; j < 2; j++) bf[j] = *(const short8*)&Bs[cur][wn * 32 + j * 16 + l15][rs];
        #pragma unroll
        for (int i = 0; i < 4; i++)
            #pragma unroll
            for (int j = 0; j < 2; j++)
                acc[i][j] = __builtin_amdgcn_mfma_f32_16x16x32_bf16(af[i], bf[j], acc[i][j], 0, 0, 0);
    };

    stage(0, 0); stage(32, 1); stage(64, 2);
    for (int k = 0; k < 142; k++) {
        asm volatile("s_waitcnt vmcnt(4)" ::: "memory");
        __builtin_amdgcn_s_barrier();
        asm volatile("" ::: "memory");
        if (k < 141) stage((k + 3) * 32, (k + 3) & 3);
        compute(k & 3);
    }
    asm volatile("s_waitcnt vmcnt(2)" ::: "memory");
    __builtin_amdgcn_s_barrier();
    asm volatile("" ::: "memory");
    compute(2);
    asm volatile("s_waitcnt vmcnt(0)" ::: "memory");
    __builtin_amdgcn_s_barrier();
    asm volatile("" ::: "memory");
    compute(3);

    #pragma unroll
    for (int i = 0; i < 4; i++)
        #pragma unroll
        for (int j = 0; j < 2; j++)
            #pragma unroll
            for (int r = 0; r < 4; r++) {
                int row = bm * 128 + wm * 64 + i * 16 + lq * 4 + r;
                int col = bn * 128 + wn * 32 + j * 16 + l15;
                kmap[(long)row * 512 + col] = f2bf(acc[i][j][r] + bf2f(kb[col]));
            }
}

// ---------- LSTM recurrence v4 (proven): sentinel self-announcing exchange. DO NOT TOUCH. ----------
#define WL(F) F(0) F(1) F(2) F(3) F(4) F(5) F(6) F(7) F(8) F(9) F(10) F(11) F(12) F(13) F(14) F(15) \
              F(16) F(17) F(18) F(19) F(20) F(21) F(22) F(23) F(24) F(25) F(26) F(27) F(28) F(29) F(30) F(31)
#define WLA(F) F(0,0) F(1,1) F(2,2) F(3,3) F(4,0) F(5,1) F(6,2) F(7,3) \
               F(8,0) F(9,1) F(10,2) F(11,3) F(12,0) F(13,1) F(14,2) F(15,3) \
               F(16,0) F(17,1) F(18,2) F(19,3) F(20,0) F(21,1) F(22,2) F(23,3) \
               F(24,0) F(25,1) F(26,2) F(27,3) F(28,0) F(29,1) F(30,2) F(31,3)
#define WDECL(i) half8 w##i = wp8[(long)(j * 32 + i) * 512 + tid];
#define WPIN(i)  asm volatile("" : "+v"(w##i));
#define DOTC(i,k) { \
    half8 hv = *(const half8*)&hS2[(hf * 2 + (i / 16)) * 136 + (i % 16) * 8]; \
    a##k = __builtin_amdgcn_fdot2(__builtin_shufflevector(hv, hv, 0, 1), __builtin_shufflevector(w##i, w##i, 0, 1), a##k, false); \
    a##k = __builtin_amdgcn_fdot2(__builtin_shufflevector(hv, hv, 2, 3), __builtin_shufflevector(w##i, w##i, 2, 3), a##k, false); \
    a##k = __builtin_amdgcn_fdot2(__builtin_shufflevector(hv, hv, 4, 5), __builtin_shufflevector(w##i, w##i, 4, 5), a##k, false); \
    a##k = __builtin_amdgcn_fdot2(__builtin_shufflevector(hv, hv, 6, 7), __builtin_shufflevector(w##i, w##i, 6, 7), a##k, false); }

__global__ __launch_bounds__(512) __attribute__((amdgpu_waves_per_eu(2, 2))) void lstm_sync(
    const float* __restrict__ xpre, const _Float16* __restrict__ Wq3,
    u16* __restrict__ seq_out, float* __restrict__ f32_out,
    unsigned* __restrict__ hExT, int T, int f32_ld)
{
    const int i_ = blockIdx.x;
    const int slot = i_ >> 3;
    const int b = (i_ & 7) * 4 + (slot & 3);
    const int j = slot >> 2;
    const int tid = threadIdx.x;
    const int hf = tid & 1;

    __shared__ __align__(16) _Float16 hS2[4 * 136];
    __shared__ float part[512];

    const half8* wp8 = (const half8*)Wq3;
    WL(WDECL)
    WL(WPIN)
    float cst = 0.f;

    for (int t = 0; t < T; t++) {
        float xi = 0.f, xf = 0.f, xg = 0.f, xo = 0.f;
        if (tid < 64) {
            const float* xp = xpre + ((long)b * T + t) * 2048 + j * 64 + tid;
            xi = xp[0]; xf = xp[512]; xg = xp[1024]; xo = xp[1536];
        }
        float a0 = 0.f, a1 = 0.f, a2 = 0.f, a3 = 0.f;
        if (t > 0) {
            if (tid < 64) {
                const unsigned* src = &hExT[((long)(t - 1) * 32 + b) * 256 + tid * 4];
                unsigned v0, v1, v2, v3;
                do {
                    v0 = __hip_atomic_load(src + 0, __ATOMIC_RELAXED, AGENT);
                    v1 = __hip_atomic_load(src + 1, __ATOMIC_RELAXED, AGENT);
                    v2 = __hip_atomic_load(src + 2, __ATOMIC_RELAXED, AGENT);
                    v3 = __hip_atomic_load(src + 3, __ATOMIC_RELAXED, AGENT);
                } while (v0 == SENT || v1 == SENT || v2 == SENT || v3 == SENT);
                uint4v v; v.x = v0; v.y = v1; v.z = v2; v.w = v3;
                *(uint4v*)&hS2[(tid >> 4) * 136 + (tid & 15) * 8] = v;
            }
            __syncthreads();
            WLA(DOTC)
        }
        part[tid] = (a0 + a1) + (a2 + a3);
        __syncthreads();
        if (tid < 64) {
            float gi = xi + part[(0   + tid) * 2] + part[(0   + tid) * 2 + 1];
            float gf = xf + part[(64  + tid) * 2] + part[(64  + tid) * 2 + 1];
            float gg = xg + part[(128 + tid) * 2] + part[(128 + tid) * 2 + 1];
            float go = xo + part[(192 + tid) * 2] + part[(192 + tid) * 2 + 1];
            cst = sigm_(gf) * cst + sigm_(gi) * tanh_(gg);
            float h = sigm_(go) * tanh_(cst);
            float hlo = __shfl(h, tid * 2);
            float hhi = __shfl(h, tid * 2 + 1);
            if (t + 1 < T && tid < 32) {
                half2v hp; hp[0] = (_Float16)hlo; hp[1] = (_Float16)hhi;
                __hip_atomic_store(&hExT[((long)t * 32 + b) * 256 + j * 32 + tid],
                                   *(unsigned*)&hp, __ATOMIC_RELAXED, AGENT);
            }
            asm volatile("" ::: "memory");
            long so = ((long)b * T + t) * 512 + j * 64 + tid;
            seq_out[so] = f2bf(h);
            if (f32_out) f32_out[((long)b * T + t) * f32_ld + j * 64 + tid] = h;
        }
    }
}

// ---------- token build ----------
__global__ __launch_bounds__(256) void tok_k(
    const float* __restrict__ holf, const u16* __restrict__ cemb,
    const int* __restrict__ label, u16* __restrict__ tok)
{
    int idx = blockIdx.x * 256 + threadIdx.x;
    int c = idx & 511;
    int m = idx >> 9;
    int b = m / 27, t = m % 27;
    float v;
    if (t == 0) v = holf[(long)b * 512 + c];
    else v = bf2f(cemb[(long)label[b * 26 + (t - 1)] * 512 + c]);
    tok[idx] = f2bf(v);
}

// ---------- fused score v2 (r9-verified) ----------
__global__ __launch_bounds__(256) void score_k(
    const float* __restrict__ q, const u16* __restrict__ kmap,
    const u16* __restrict__ sW, const u16* __restrict__ sb,
    const float* __restrict__ vr, float* __restrict__ aw)
{
    int blk = blockIdx.x;
    int xcd = blk & 7, rest = blk >> 3;
    int bq = rest & 3, t = rest >> 2;
    int b = xcd * 4 + bq;
    int bt = b * 27 + t;
    int tid = threadIdx.x, wv = tid >> 6, ln = tid & 63;

    __shared__ float sc[240];
    __shared__ float red[256];

    float qr[8], sr[8];
    const float* qp = q + (long)bt * 512 + ln * 8;
    #pragma unroll
    for (int i = 0; i < 8; i++) qr[i] = qp[i];
    #pragma unroll
    for (int i = 0; i < 8; i++) sr[i] = bf2f(sW[ln * 8 + i]);

    const u16* kb_ = kmap + (long)b * 240 * 512;
    for (int r = wv * 60; r < wv * 60 + 60; r++) {
        short8 kv = *(const short8*)(kb_ + (long)r * 512 + ln * 8);
        float acc = 0.f;
        #pragma unroll
        for (int i = 0; i < 8; i++) {
            float x = bf2f((u16)kv[i]) + qr[i];
            acc = fmaf(sr[i], tanh_(x), acc);
        }
        #pragma unroll
        for (int m = 32; m > 0; m >>= 1) acc += __shfl_xor(acc, m);
        if (ln == 0) sc[r] = acc;
    }
    __syncthreads();

    float scv = -INFINITY, ex = 0.f;
    if (tid < 240) {
        float rr = vr[b];
        int vw = (int)ceilf(40.f * rr);
        if (vw > 40) vw = 40;
        int wcol = tid % 40;
        scv = (wcol >= vw) ? -INFINITY : (sc[tid] + bf2f(sb[0]));
    }
    red[tid] = scv;
    __syncthreads();
    for (int s = 128; s > 0; s >>= 1) {
        if (tid < s) red[tid] = fmaxf(red[tid], red[tid + s]);
        __syncthreads();
    }
    float mx = red[0];
    __syncthreads();
    if (tid < 240) ex = (scv == -INFINITY) ? 0.f : __expf(scv - mx);
    red[tid] = ex;
    __syncthreads();
    for (int s = 128; s > 0; s >>= 1) {
        if (tid < s) red[tid] += red[tid + s];
        __syncthreads();
    }
    float inv = __builtin_amdgcn_rcpf(red[0]);
    if (tid < 240) aw[(long)bt * 240 + tid] = ex * inv;
}

// ---------- attn_feat -> concat cols [512,1024) ----------
__global__ __launch_bounds__(256) void attn_k(
    const void* __restrict__ feat, const float* __restrict__ aw,
    float* __restrict__ concat, const int* __restrict__ flag)
{
    const int fl = *flag;
    int b = blockIdx.x >> 3;
    int cc = (blockIdx.x & 7) * 64;
    int tid = threadIdx.x;
    __shared__ float awS[27 * 240];
    __shared__ u16 fS[64 * 240];
    for (int i = tid; i < 27 * 240; i += 256) awS[i] = aw[(long)b * 27 * 240 + i];
    long fbase = ((long)b * 512 + cc) * 240;
    for (int i = tid; i < 64 * 240; i += 256)
        fS[i] = fl ? f2bf(((const float*)feat)[fbase + i]) : ((const u16*)feat)[fbase + i];
    __syncthreads();
    for (int item = tid; item < 64 * 27; item += 256) {
        int c = item / 27, t = item % 27;
        const u16* fp = &fS[c * 240];
        const float* ap = &awS[t * 240];
        float acc = 0.f;
        for (int hw = 0; hw < 240; hw++) acc = fmaf(bf2f(fp[hw]), ap[hw], acc);
        concat[((long)(b * 27 + t)) * 1536 + 512 + cc + c] = acc;
    }
}

// ---------- prediction + slice ----------
__global__ __launch_bounds__(256) void pred_k(
    const float* __restrict__ concat, const float* __restrict__ holf,
    const u16* __restrict__ pW, const u16* __restrict__ pb,
    void* __restrict__ out, const int* __restrict__ flag)
{
    int m0 = blockIdx.x * 4;
    int tid = threadIdx.x;
    const int fl = *flag;
    __shared__ float aS[4][1024];
    __shared__ float hS[4][512];
    for (int i = tid; i < 4 * 1024; i += 256)
        aS[i / 1024][i % 1024] = concat[(long)(m0 + i / 1024) * 1536 + (i % 1024)];
    for (int i = tid; i < 4 * 512; i += 256) {
        int m = m0 + i / 512;
        hS[i / 512][i % 512] = holf[(long)(m / 27) * 512 + (i % 512)];
    }
    __syncthreads();
    int r = tid >> 6;
    int nb = tid & 63;
    int m = m0 + r;
    int b = m / 27, t = m % 27;
    for (int n = nb; n < 97; n += 64) {
        const u16* wp = pW + (long)n * 1536;
        float acc = 0.f;
        for (int k = 0; k < 1024; k++) acc = fmaf(aS[r][k], bf2f(wp[k]), acc);
        for (int k = 0; k < 512; k++) acc = fmaf(hS[r][k], bf2f(wp[1024 + k]), acc);
        acc += bf2f(pb[n]);
        if (t > 0) {
            long o = ((long)(b * 26 + (t - 1))) * 97 + n;
            if (fl) ((float*)out)[o] = acc;
            else    ((u16*)out)[o] = f2bf(acc);
        }
    }
}

// ---------- launch ----------
extern "C" void kernel_launch(void* const* d_in, const int* in_sizes, int n_in,
                              void* d_out, int out_size, void* d_ws, size_t ws_size,
                              hipStream_t stream) {
    (void)in_sizes; (void)n_in; (void)out_size; (void)ws_size;
    const void* feat_r = d_in[0];
    const int*  label  = (const int*)d_in[1];
    const void* vr_r   = d_in[2];

    char* w = (char*)d_ws;
    size_t off = 0;
    auto alloc = [&](size_t bytes) -> void* {
        void* p = w + off;
        off = (off + bytes + 63) & ~(size_t)63;
        return p;
    };
    int*   flag    = (int*)  alloc(4);
    unsigned* hEx  = (unsigned*)alloc((size_t)HEX_WORDS * 4);
    u16*   canon   = (u16*)  alloc((size_t)CANON_TOTAL * 2);
    float* cvr     = (float*)alloc(32ull * 4);
    u16*   featv   = (u16*)  alloc(655360ull * 2);
    float* xpre    = (float*)alloc(2621440ull * 4);   // kmap aliases after LSTMs
    u16*   seq0    = (u16*)  alloc(655360ull * 2);
    u16*   seq1    = (u16*)  alloc(655360ull * 2);
    u16*   tok     = (u16*)  alloc(442368ull * 2);
    u16*   seqd0   = (u16*)  alloc(442368ull * 2);
    u16*   Hid     = (u16*)  alloc(442368ull * 2);
    float* holf    = (float*)alloc(16384ull * 4);
    float* qf      = (float*)alloc(442368ull * 4);
    u16*   featP   = (u16*)  alloc(5505024ull * 2);
    u16*   W2      = (u16*)  alloc(2359296ull * 2);
    float* aw      = (float*)alloc(207360ull * 4);
    float* concat  = (float*)alloc(1327104ull * 4);
    _Float16* Wq[4];
    for (int i = 0; i < 4; i++) Wq[i] = (_Float16*)alloc(1048576ull * 2);
    u16*   kmap    = (u16*)xpre;

    unsigned* hEx0 = hEx;
    unsigned* hEx1 = hEx + 40ull * 8192;
    unsigned* hEx2 = hEx + 80ull * 8192;
    unsigned* hEx3 = hEx + 107ull * 8192;

    u16* cW0    = canon + OFF_W0;
    u16* cW1    = canon + OFF_W1;
    u16* cW2    = canon + OFF_W2;
    u16* cW3    = canon + OFF_W3;
    u16* cb0    = canon + OFF_B;
    u16* cencW  = canon + OFF_ENCW;
    u16* cqW    = canon + OFF_QW;
    u16* cpredW = canon + OFF_PREDW;
    u16* cemb   = canon + OFF_EMB;
    u16* cencb  = canon + OFF_ENCB;
    u16* cqb    = canon + OFF_QB;
    u16* ckb    = canon + OFF_KB;
    u16* csW    = canon + OFF_SW;
    u16* csb    = canon + OFF_SB;
    u16* cpredb = canon + OFF_PREDB;

    // ---- fused prep (5 branches) + coalesced feat transpose ----
    PrepArgs P;
    P.S.e0Wih = d_in[3];  P.S.e1Wih = d_in[7];  P.S.d0Wih = d_in[20]; P.S.d1Wih = d_in[24];
    P.S.b0 = d_in[5];  P.S.b1 = d_in[6];  P.S.b2 = d_in[9];  P.S.b3 = d_in[10];
    P.S.b4 = d_in[22]; P.S.b5 = d_in[23]; P.S.b6 = d_in[26]; P.S.b7 = d_in[27];
    P.S.encW = d_in[11]; P.S.qW = d_in[13]; P.S.predW = d_in[28]; P.S.emb = d_in[19];
    P.S.encb = d_in[12]; P.S.qb = d_in[14]; P.S.kb = d_in[16]; P.S.sW = d_in[17];
    P.S.sb = d_in[18]; P.S.predb = d_in[29];
    P.feat_raw = feat_r; P.vr_src = vr_r; P.kW_src = d_in[15];
    P.wq_s0 = d_in[4]; P.wq_s1 = d_in[8]; P.wq_s2 = d_in[21]; P.wq_s3 = d_in[25];
    P.flag = flag; P.hEx = hEx; P.canon = canon; P.cvr = cvr;
    P.W2 = W2;
    P.wq_d0 = Wq[0]; P.wq_d1 = Wq[1]; P.wq_d2 = Wq[2]; P.wq_d3 = Wq[3];
    prep_all<<<dim3(PB_TOTAL), 256, 0, stream>>>(P);
    featp_k<<<dim3(256), 256, 0, stream>>>(feat_r, featv, featP);

    // ---- encoder ----
    gemm_nt_128<<<dim3(16, 10), 512, 0, stream>>>(featv, cW0, cb0 + 0 * 2048, cb0 + 1 * 2048, xpre, 1280, 2048);
    lstm_sync<<<dim3(256), 512, 0, stream>>>(xpre, Wq[0], seq0, nullptr, hEx0, 40, 0);
    gemm_nt_128<<<dim3(16, 10), 512, 0, stream>>>(seq0, cW1, cb0 + 2 * 2048, cb0 + 3 * 2048, xpre, 1280, 2048);
    lstm_sync<<<dim3(256), 512, 0, stream>>>(xpre, Wq[1], seq1, nullptr, hEx1, 40, 0);
    gemm_nt_f32<<<dim3(8, 1), 256, 0, stream>>>(seq1 + 39 * 512, 40 * 512, cencW, cencb, nullptr, holf, 32, 512, 512, 512);

    // ---- decoder ----
    tok_k<<<dim3(1728), 256, 0, stream>>>(holf, cemb, label, tok);
    gemm_nt_128<<<dim3(16, 7), 512, 0, stream>>>(tok, cW2, cb0 + 4 * 2048, cb0 + 5 * 2048, xpre, 864, 2048);
    lstm_sync<<<dim3(256), 512, 0, stream>>>(xpre, Wq[2], seqd0, nullptr, hEx2, 27, 0);
    gemm_nt_128<<<dim3(16, 7), 512, 0, stream>>>(seqd0, cW3, cb0 + 6 * 2048, cb0 + 7 * 2048, xpre, 864, 2048);
    lstm_sync<<<dim3(256), 512, 0, stream>>>(xpre, Wq[3], Hid, concat, hEx3, 27, 1536);

    // ---- attention (xpre dead; kmap aliases it) ----
    gemm_nt_128<<<dim3(4, 7), 512, 0, stream>>>(Hid, cqW, cqb, nullptr, qf, 864, 512);
    conv_gemm<<<dim3(8, 32), 512, 0, stream>>>(featP, W2, ckb, kmap);
    score_k<<<dim3(864), 256, 0, stream>>>(qf, kmap, csW, csb, cvr, aw);
    attn_k<<<dim3(256), 256, 0, stream>>>(feat_r, aw, concat, flag);

    // ---- prediction ----
    pred_k<<<dim3(216), 256, 0, stream>>>(concat, holf, cpredW, cpredb, d_out, flag);
}

// Round 12
// 743.084 us; speedup vs baseline: 1.1860x; 1.0763x over previous
//
#include <hip/hip_runtime.h>

typedef unsigned short u16;
typedef __attribute__((ext_vector_type(8))) short short8;
typedef __attribute__((ext_vector_type(4))) float floatx4;
typedef _Float16 half8 __attribute__((ext_vector_type(8)));
typedef _Float16 half2v __attribute__((ext_vector_type(2)));
typedef unsigned uint4v __attribute__((ext_vector_type(4)));

#define AGENT __HIP_MEMORY_SCOPE_AGENT
#define SENT 0x7FFF7FFFu   // f16 NaN pair — unreachable: h = sigm*tanh in (-1,1)

// ---------- helpers ----------
__device__ __forceinline__ float bf2f(u16 v) { return __uint_as_float(((unsigned)v) << 16); }
__device__ __forceinline__ u16 f2bf(float f) {
    unsigned u = __float_as_uint(f);
    unsigned r = (u + 0x7FFFu + ((u >> 16) & 1u)) >> 16;
    return (u16)r;
}
// fast transcendentals: native v_exp + raw v_rcp (no precise-div sequence)
__device__ __forceinline__ float sigm_(float x) {
    return __builtin_amdgcn_rcpf(1.f + __expf(-x));
}
__device__ __forceinline__ float tanh_(float x) {
    x = fminf(fmaxf(x, -15.f), 15.f);
    float e = __expf(2.f * x);
    return (e - 1.f) * __builtin_amdgcn_rcpf(e + 1.f);
}

// async global->LDS, 16B per lane; LDS dest is wave-uniform base + lane*16
typedef __attribute__((address_space(1))) void gvoid_t;
typedef __attribute__((address_space(3))) void lvoid_t;
__device__ __forceinline__ void gl_lds16(const void* g, void* l) {
    __builtin_amdgcn_global_load_lds((gvoid_t*)g, (lvoid_t*)l, 16, 0, 0);
}

// B=32, C=512, H=6, W=40, NC=97, L=26, T=27
#define HEX_WORDS (134 * 32 * 256)

// ---------- offsets ----------
struct SrcPtrs {
    const void* e0Wih; const void* e1Wih; const void* d0Wih; const void* d1Wih;
    const void* b0; const void* b1; const void* b2; const void* b3;
    const void* b4; const void* b5; const void* b6; const void* b7;
    const void* encW; const void* qW; const void* predW; const void* emb;
    const void* encb; const void* qb; const void* kb; const void* sW;
    const void* sb; const void* predb;
};
#define OFF_W0      0
#define OFF_W1      1048576
#define OFF_W2      2097152
#define OFF_W3      3145728
#define OFF_B       4194304
#define OFF_ENCW    4210688
#define OFF_QW      4472832
#define OFF_PREDW   4734976
#define OFF_EMB     4883968
#define OFF_ENCB    4933632
#define OFF_QB      4934144
#define OFF_KB      4934656
#define OFF_SW      4935168
#define OFF_SB      4935680
#define OFF_PREDB   4935681
#define CANON_TOTAL 4935778

// ---------- dtype sniff (32 loads of ONE 64B line; L2-broadcast ~free) ----------
__device__ __forceinline__ int sniff_(const void* feat_raw) {
    const u16* p = (const u16*)feat_raw;
    int insane = 0;
    #pragma unroll
    for (int i = 0; i < 32; i += 2) {
        float x = bf2f(p[i]);
        float a = fabsf(x);
        if (!(a <= 1000.f)) insane = 1;
        if (x != 0.f && a < 1e-8f) insane = 1;
    }
    return insane;
}

// ---------- v14: fused prep — now includes the featp transpose (6 branches, 1 dispatch) ----------
struct PrepArgs {
    SrcPtrs S;
    const void* feat_raw;
    const void* vr_src;
    const void* kW_src;
    const void* wq_s0; const void* wq_s1; const void* wq_s2; const void* wq_s3;
    int* flag;
    unsigned* hEx;
    u16* canon;
    float* cvr;
    u16* W2;
    _Float16* wq_d0; _Float16* wq_d1; _Float16* wq_d2; _Float16* wq_d3;
    u16* featv;
    u16* featP;
};

// block ranges
#define PB_INIT    0        // 4288 blocks  : hEx sentinel fill (+flag from idx 0)
#define PB_CANON   4288     // 19281 blocks : canon_all
#define PB_CANONF  23569    // 1 block      : cvr (32 floats)
#define PB_W2      23570    // 9216 blocks  : conv weight reshuffle
#define PB_WQ3     32786    // 2048 blocks  : 4x Whh -> f16 dot layout
#define PB_FEATP   34834    // 256 blocks   : LDS-tiled feat transpose (featv + featP)
#define PB_TOTAL   35090

__global__ __launch_bounds__(256) void prep_all(PrepArgs P)
{
    const int blk = blockIdx.x;
    const int tid = threadIdx.x;

    if (blk < PB_CANON) {                       // ---- init: sentinel fill ----
        int idx = blk * 256 + tid;
        P.hEx[idx] = SENT;
        if (idx == 0) *P.flag = sniff_(P.feat_raw);
        return;
    }
    const int fl = sniff_(P.feat_raw);          // per-block local dtype flag

    if (blk < PB_CANONF) {                      // ---- canon_all ----
        int idx = (blk - PB_CANON) * 256 + tid;
        if (idx >= CANON_TOTAL) return;
        const SrcPtrs& S = P.S;
        const void* s; int loc;
        if (idx < OFF_B) {
            int k = idx >> 20; loc = idx & 1048575;
            s = (k == 0) ? S.e0Wih : (k == 1) ? S.e1Wih : (k == 2) ? S.d0Wih : S.d1Wih;
        } else if (idx < OFF_ENCW) {
            int r = idx - OFF_B; int k = r >> 11; loc = r & 2047;
            s = (k == 0) ? S.b0 : (k == 1) ? S.b1 : (k == 2) ? S.b2 : (k == 3) ? S.b3
              : (k == 4) ? S.b4 : (k == 5) ? S.b5 : (k == 6) ? S.b6 : S.b7;
        } else if (idx < OFF_QW)    { s = S.encW;  loc = idx - OFF_ENCW; }
        else if (idx < OFF_PREDW)   { s = S.qW;    loc = idx - OFF_QW; }
        else if (idx < OFF_EMB)     { s = S.predW; loc = idx - OFF_PREDW; }
        else if (idx < OFF_ENCB)    { s = S.emb;   loc = idx - OFF_EMB; }
        else if (idx < OFF_QB)      { s = S.encb;  loc = idx - OFF_ENCB; }
        else if (idx < OFF_KB)      { s = S.qb;    loc = idx - OFF_QB; }
        else if (idx < OFF_SW)      { s = S.kb;    loc = idx - OFF_KB; }
        else if (idx < OFF_SB)      { s = S.sW;    loc = idx - OFF_SW; }
        else if (idx < OFF_PREDB)   { s = S.sb;    loc = idx - OFF_SB; }
        else                        { s = S.predb; loc = idx - OFF_PREDB; }
        P.canon[idx] = fl ? f2bf(((const float*)s)[loc]) : ((const u16*)s)[loc];
    } else if (blk == PB_CANONF) {              // ---- canonf (valid_ratios) ----
        if (tid < 32)
            P.cvr[tid] = fl ? ((const float*)P.vr_src)[tid] : bf2f(((const u16*)P.vr_src)[tid]);
    } else if (blk < PB_WQ3) {                  // ---- w2 ----
        int idx = (blk - PB_W2) * 256 + tid;
        int co = idx / 4608;
        int r = idx % 4608;
        int kh = r / 1536;
        int r2 = r % 1536;
        int kw = r2 / 512;
        int ci = r2 & 511;
        long si = ((long)(co * 512 + ci) * 3 + kh) * 3 + kw;
        P.W2[idx] = fl ? f2bf(((const float*)P.kW_src)[si]) : ((const u16*)P.kW_src)[si];
    } else if (blk < PB_FEATP) {                // ---- wq3_all ----
        int gb = blk - PB_WQ3;
        int id = gb >> 9;
        const void* W = (id == 0) ? P.wq_s0 : (id == 1) ? P.wq_s1 : (id == 2) ? P.wq_s2 : P.wq_s3;
        _Float16* D = (id == 0) ? P.wq_d0 : (id == 1) ? P.wq_d1 : (id == 2) ? P.wq_d2 : P.wq_d3;
        int o = (gb & 511) * 256 + tid;
        int t = o & 511;
        int c = (o >> 9) & 31;
        int j = o >> 14;
        int rid = t >> 1, hf = t & 1;
        int n = (rid >> 6) * 512 + j * 64 + (rid & 63);
        int k = hf * 256 + c * 8;
        _Float16* dst = D + (long)o * 8;
        #pragma unroll
        for (int jj = 0; jj < 8; jj++) {
            long si = (long)n * 512 + k + jj;
            float v = fl ? ((const float*)W)[si] : bf2f(((const u16*)W)[si]);
            dst[jj] = (_Float16)v;
        }
    } else {                                    // ---- featp: LDS-tiled transpose ----
        __shared__ u16 S[64][242];
        int q = blk - PB_FEATP;
        int b = q >> 3;
        int c0 = (q & 7) * 64;
        long gbase = ((long)b * 512 + c0) * 240;
        for (int i = tid; i < 64 * 240; i += 256) {
            float x = fl ? ((const float*)P.feat_raw)[gbase + i] : bf2f(((const u16*)P.feat_raw)[gbase + i]);
            S[i / 240][i % 240] = f2bf(x);
        }
        __syncthreads();
        for (int i = tid; i < 40 * 64; i += 256) {
            int w = i >> 6, c = i & 63;
            float mx = bf2f(S[c][w]);
            #pragma unroll
            for (int h = 1; h < 6; h++) mx = fmaxf(mx, bf2f(S[c][h * 40 + w]));
            P.featv[((long)(b * 40 + w)) * 512 + c0 + c] = f2bf(mx);
        }
        for (int i = tid; i < 6 * 40 * 64; i += 256) {
            int c = i & 63; int r = i >> 6;
            int wp1 = r % 40, hp1 = r / 40;
            P.featP[((long)(b * 8 + hp1 + 1) * 42 + (wp1 + 1)) * 512 + c0 + c] = S[c][hp1 * 40 + wp1];
        }
        for (int i = tid; i < 96 * 64; i += 256) {
            int c = i & 63; int r = i >> 6;
            int hp, wp;
            if (r < 42)      { hp = 0; wp = r; }
            else if (r < 84) { hp = 7; wp = r - 42; }
            else             { int q2 = r - 84; hp = 1 + (q2 >> 1); wp = (q2 & 1) * 41; }
            P.featP[((long)(b * 8 + hp) * 42 + wp) * 512 + c0 + c] = 0;
        }
    }
}

// ---------- NT GEMM (64-tile; kept for tiny M=32 encW GEMM) ----------
__global__ __launch_bounds__(256) void gemm_nt_f32(
    const u16* __restrict__ A, int lda,
    const u16* __restrict__ Bw,
    const u16* __restrict__ bias0, const u16* __restrict__ bias1,
    float* __restrict__ C, int M, int N, int K, int ldc)
{
    __shared__ __align__(16) u16 As[64][40];
    __shared__ __align__(16) u16 Bs[64][40];
    const int tid = threadIdx.x;
    const int bn = blockIdx.x, bm = blockIdx.y;
    const int l = tid & 63, wid = tid >> 6;
    const int wm = wid >> 1, wn = wid & 1;
    const int lr = tid >> 2, lc = (tid & 3) * 8;
    const int l15 = l & 15, lq = l >> 4;

    floatx4 acc00 = (floatx4)(0.f), acc01 = (floatx4)(0.f), acc10 = (floatx4)(0.f), acc11 = (floatx4)(0.f);

    int am = bm * 64 + lr; if (am > M - 1) am = M - 1;
    const u16* Ap = A + (long)am * lda + lc;
    const u16* Bp = Bw + (long)(bn * 64 + lr) * K + lc;

    for (int k0 = 0; k0 < K; k0 += 32) {
        *(short8*)&As[lr][lc] = *(const short8*)(Ap + k0);
        *(short8*)&Bs[lr][lc] = *(const short8*)(Bp + k0);
        __syncthreads();
        short8 af0 = *(const short8*)&As[wm * 32 + l15][lq * 8];
        short8 af1 = *(const short8*)&As[wm * 32 + 16 + l15][lq * 8];
        short8 bf0 = *(const short8*)&Bs[wn * 32 + l15][lq * 8];
        short8 bf1 = *(const short8*)&Bs[wn * 32 + 16 + l15][lq * 8];
        acc00 = __builtin_amdgcn_mfma_f32_16x16x32_bf16(af0, bf0, acc00, 0, 0, 0);
        acc01 = __builtin_amdgcn_mfma_f32_16x16x32_bf16(af0, bf1, acc01, 0, 0, 0);
        acc10 = __builtin_amdgcn_mfma_f32_16x16x32_bf16(af1, bf0, acc10, 0, 0, 0);
        acc11 = __builtin_amdgcn_mfma_f32_16x16x32_bf16(af1, bf1, acc11, 0, 0, 0);
        __syncthreads();
    }
    floatx4 accs[2][2] = {{acc00, acc01}, {acc10, acc11}};
    #pragma unroll
    for (int i = 0; i < 2; i++)
        #pragma unroll
        for (int j = 0; j < 2; j++)
            #pragma unroll
            for (int r = 0; r < 4; r++) {
                int gm = bm * 64 + wm * 32 + i * 16 + lq * 4 + r;
                int gn = bn * 64 + wn * 32 + j * 16 + l15;
                if (gm < M) {
                    float v = accs[i][j][r];
                    if (bias0) v += bf2f(bias0[gn]);
                    if (bias1) v += bf2f(bias1[gn]);
                    C[(long)gm * ldc + gn] = v;
                }
            }
}

// ---------- 128x128 tile bodies (dynamic LDS so qf GEMM + conv can share one kernel) ----------
// Layout: As = lds[0 .. 4*128*32), Bs = lds[4*128*32 .. 8*128*32)  (64 KB total)
__device__ __forceinline__ void gemm128_body(
    u16* lds, const u16* __restrict__ A, const u16* __restrict__ Bw,
    const u16* __restrict__ bias0, const u16* __restrict__ bias1,
    float* __restrict__ C, int M, int ldc, int bn, int bm)
{
    u16 (*As)[128][32] = (u16(*)[128][32])lds;
    u16 (*Bs)[128][32] = (u16(*)[128][32])(lds + 4 * 128 * 32);
    const int tid = threadIdx.x;
    const int wv = tid >> 6, l = tid & 63;
    const int wm = wv >> 2, wn = wv & 3;
    const int l15 = l & 15, lq = l >> 4;
    const int ch = ((l & 3) ^ ((l >> 3) & 3)) * 8;

    int ar = bm * 128 + wv * 16 + (l >> 2);
    if (ar > M - 1) ar = M - 1;
    const u16* ga = A + (long)ar * 512 + ch;
    const u16* gb = Bw + (long)(bn * 128 + wv * 16 + (l >> 2)) * 512 + ch;

    floatx4 acc[4][2];
    #pragma unroll
    for (int i = 0; i < 4; i++)
        #pragma unroll
        for (int j = 0; j < 2; j++) acc[i][j] = (floatx4)(0.f);

    auto stage = [&](int k0, int pb) {
        gl_lds16(ga + k0, &As[pb][wv * 16][0]);
        gl_lds16(gb + k0, &Bs[pb][wv * 16][0]);
    };
    const int rs = (lq ^ ((l15 >> 1) & 3)) * 8;
    auto compute = [&](int cur) {
        short8 af[4], bf[2];
        #pragma unroll
        for (int i = 0; i < 4; i++) af[i] = *(const short8*)&As[cur][wm * 64 + i * 16 + l15][rs];
        #pragma unroll
        for (int j = 0; j < 2; j++) bf[j] = *(const short8*)&Bs[cur][wn * 32 + j * 16 + l15][rs];
        #pragma unroll
        for (int i = 0; i < 4; i++)
            #pragma unroll
            for (int j = 0; j < 2; j++)
                acc[i][j] = __builtin_amdgcn_mfma_f32_16x16x32_bf16(af[i], bf[j], acc[i][j], 0, 0, 0);
    };

    stage(0, 0); stage(32, 1); stage(64, 2);
    for (int k = 0; k < 14; k++) {
        asm volatile("s_waitcnt vmcnt(4)" ::: "memory");
        __builtin_amdgcn_s_barrier();
        asm volatile("" ::: "memory");
        if (k < 13) stage((k + 3) * 32, (k + 3) & 3);
        compute(k & 3);
    }
    asm volatile("s_waitcnt vmcnt(2)" ::: "memory");
    __builtin_amdgcn_s_barrier();
    asm volatile("" ::: "memory");
    compute(2);
    asm volatile("s_waitcnt vmcnt(0)" ::: "memory");
    __builtin_amdgcn_s_barrier();
    asm volatile("" ::: "memory");
    compute(3);

    #pragma unroll
    for (int i = 0; i < 4; i++)
        #pragma unroll
        for (int j = 0; j < 2; j++)
            #pragma unroll
            for (int r = 0; r < 4; r++) {
                int gm = bm * 128 + wm * 64 + i * 16 + lq * 4 + r;
                int gn = bn * 128 + wn * 32 + j * 16 + l15;
                if (gm < M) {
                    float v = acc[i][j][r];
                    if (bias0) v += bf2f(bias0[gn]);
                    if (bias1) v += bf2f(bias1[gn]);
                    C[(long)gm * ldc + gn] = v;
                }
            }
}

__device__ __forceinline__ void conv_body(
    u16* lds, const u16* __restrict__ featP, const u16* __restrict__ W2,
    const u16* __restrict__ kb, u16* __restrict__ kmap, int bx, int by)
{
    u16 (*As)[128][32] = (u16(*)[128][32])lds;
    u16 (*Bs)[128][32] = (u16(*)[128][32])(lds + 4 * 128 * 32);
    const int tid = threadIdx.x;
    int bm = bx * 8 + (by & 7);
    int bn = by >> 3;
    if (bm >= 60) return;
    const int wv = tid >> 6, l = tid & 63;
    const int wm = wv >> 2, wn = wv & 3;
    const int l15 = l & 15, lq = l >> 4;
    const int ch = ((l & 3) ^ ((l >> 3) & 3)) * 8;

    int ar = bm * 128 + wv * 16 + (l >> 2);
    int ab = ar / 240, ahw = ar % 240;
    const u16* ga = featP + ((long)(ab * 8 + ahw / 40) * 42 + (ahw % 40)) * 512 + ch;
    const u16* gb = W2 + (long)(bn * 128 + wv * 16 + (l >> 2)) * 4608 + ch;

    floatx4 acc[4][2];
    #pragma unroll
    for (int i = 0; i < 4; i++)
        #pragma unroll
        for (int j = 0; j < 2; j++) acc[i][j] = (floatx4)(0.f);

    auto stage = [&](int k0, int pb) {
        int kh = k0 / 1536;
        int rem = k0 - kh * 1536;
        int aoff = (kh * 42 + (rem >> 9)) * 512 + (rem & 511);
        gl_lds16(ga + aoff, &As[pb][wv * 16][0]);
        gl_lds16(gb + k0, &Bs[pb][wv * 16][0]);
    };
    const int rs = (lq ^ ((l15 >> 1) & 3)) * 8;
    auto compute = [&](int cur) {
        short8 af[4], bf[2];
        #pragma unroll
        for (int i = 0; i < 4; i++) af[i] = *(const short8*)&As[cur][wm * 64 + i * 16 + l15][rs];
        #pragma unroll
        for (int j = 0; j < 2; j++) bf[j] = *(const short8*)&Bs[cur][wn * 32 + j * 16 + l15][rs];
        #pragma unroll
        for (int i = 0; i < 4; i++)
            #pragma unroll
            for (int j = 0; j < 2; j++)
                acc[i][j] = __builtin_amdgcn_mfma_f32_16x16x32_bf16(af[i], bf[j], acc[i][j], 0, 0, 0);
    };

    stage(0, 0); stage(32, 1); stage(64, 2);
    for (int k = 0; k < 142; k++) {
        asm volatile("s_waitcnt vmcnt(4)" ::: "memory");
        __builtin_amdgcn_s_barrier();
        asm volatile("" ::: "memory");
        if (k < 141) stage((k + 3) * 32, (k + 3) & 3);
        compute(k & 3);
    }
    asm volatile("s_waitcnt vmcnt(2)" ::: "memory");
    __builtin_amdgcn_s_barrier();
    asm volatile("" ::: "memory");
    compute(2);
    asm volatile("s_waitcnt vmcnt(0)" ::: "memory");
    __builtin_amdgcn_s_barrier();
    asm volatile("" ::: "memory");
    compute(3);

    #pragma unroll
    for (int i = 0; i < 4; i++)
        #pragma unroll
        for (int j = 0; j < 2; j++)
            #pragma unroll
            for (int r = 0; r < 4; r++) {
                int row = bm * 128 + wm * 64 + i * 16 + lq * 4 + r;
                int col = bn * 128 + wn * 32 + j * 16 + l15;
                kmap[(long)row * 512 + col] = f2bf(acc[i][j][r] + bf2f(kb[col]));
            }
}

__global__ __launch_bounds__(512) void gemm_nt_128(
    const u16* __restrict__ A, const u16* __restrict__ Bw,
    const u16* __restrict__ bias0, const u16* __restrict__ bias1,
    float* __restrict__ C, int M, int ldc)
{
    extern __shared__ u16 ldsb[];
    gemm128_body(ldsb, A, Bw, bias0, bias1, C, M, ldc, blockIdx.x, blockIdx.y);
}

// ---------- v14: qf GEMM co-dispatched with conv (no polling, no pinned regs -> safe fusion) ----------
// Blocks 0..27: qf = Hid @ qW^T + qb (M=864, N=512). Blocks 28..283: conv 240 tiles.
// 284 blocks ~ 256 CUs: the 28 qf blocks ride inside conv's execution shadow.
__global__ __launch_bounds__(512) void qf_conv(
    const u16* __restrict__ Hid, const u16* __restrict__ qW,
    const u16* __restrict__ qb, float* __restrict__ qf,
    const u16* __restrict__ featP, const u16* __restrict__ W2,
    const u16* __restrict__ kb, u16* __restrict__ kmap)
{
    extern __shared__ u16 ldsb[];
    int q = blockIdx.x;
    if (q < 28) {
        gemm128_body(ldsb, Hid, qW, qb, nullptr, qf, 864, 512, q & 3, q >> 2);
    } else {
        int c = q - 28;
        conv_body(ldsb, featP, W2, kb, kmap, c & 7, c >> 3);
    }
}

// ---------- LSTM recurrence v4 (proven): sentinel self-announcing exchange. DO NOT TOUCH. ----------
#define WL(F) F(0) F(1) F(2) F(3) F(4) F(5) F(6) F(7) F(8) F(9) F(10) F(11) F(12) F(13) F(14) F(15) \
              F(16) F(17) F(18) F(19) F(20) F(21) F(22) F(23) F(24) F(25) F(26) F(27) F(28) F(29) F(30) F(31)
#define WLA(F) F(0,0) F(1,1) F(2,2) F(3,3) F(4,0) F(5,1) F(6,2) F(7,3) \
               F(8,0) F(9,1) F(10,2) F(11,3) F(12,0) F(13,1) F(14,2) F(15,3) \
               F(16,0) F(17,1) F(18,2) F(19,3) F(20,0) F(21,1) F(22,2) F(23,3) \
               F(24,0) F(25,1) F(26,2) F(27,3) F(28,0) F(29,1) F(30,2) F(31,3)
#define WDECL(i) half8 w##i = wp8[(long)(j * 32 + i) * 512 + tid];
#define WPIN(i)  asm volatile("" : "+v"(w##i));
#define DOTC(i,k) { \
    half8 hv = *(const half8*)&hS2[(hf * 2 + (i / 16)) * 136 + (i % 16) * 8]; \
    a##k = __builtin_amdgcn_fdot2(__builtin_shufflevector(hv, hv, 0, 1), __builtin_shufflevector(w##i, w##i, 0, 1), a##k, false); \
    a##k = __builtin_amdgcn_fdot2(__builtin_shufflevector(hv, hv, 2, 3), __builtin_shufflevector(w##i, w##i, 2, 3), a##k, false); \
    a##k = __builtin_amdgcn_fdot2(__builtin_shufflevector(hv, hv, 4, 5), __builtin_shufflevector(w##i, w##i, 4, 5), a##k, false); \
    a##k = __builtin_amdgcn_fdot2(__builtin_shufflevector(hv, hv, 6, 7), __builtin_shufflevector(w##i, w##i, 6, 7), a##k, false); }

__global__ __launch_bounds__(512) __attribute__((amdgpu_waves_per_eu(2, 2))) void lstm_sync(
    const float* __restrict__ xpre, const _Float16* __restrict__ Wq3,
    u16* __restrict__ seq_out, float* __restrict__ f32_out,
    unsigned* __restrict__ hExT, int T, int f32_ld)
{
    const int i_ = blockIdx.x;
    const int slot = i_ >> 3;
    const int b = (i_ & 7) * 4 + (slot & 3);
    const int j = slot >> 2;
    const int tid = threadIdx.x;
    const int hf = tid & 1;

    __shared__ __align__(16) _Float16 hS2[4 * 136];
    __shared__ float part[512];

    const half8* wp8 = (const half8*)Wq3;
    WL(WDECL)
    WL(WPIN)
    float cst = 0.f;

    for (int t = 0; t < T; t++) {
        float xi = 0.f, xf = 0.f, xg = 0.f, xo = 0.f;
        if (tid < 64) {
            const float* xp = xpre + ((long)b * T + t) * 2048 + j * 64 + tid;
            xi = xp[0]; xf = xp[512]; xg = xp[1024]; xo = xp[1536];
        }
        float a0 = 0.f, a1 = 0.f, a2 = 0.f, a3 = 0.f;
        if (t > 0) {
            if (tid < 64) {
                const unsigned* src = &hExT[((long)(t - 1) * 32 + b) * 256 + tid * 4];
                unsigned v0, v1, v2, v3;
                do {
                    v0 = __hip_atomic_load(src + 0, __ATOMIC_RELAXED, AGENT);
                    v1 = __hip_atomic_load(src + 1, __ATOMIC_RELAXED, AGENT);
                    v2 = __hip_atomic_load(src + 2, __ATOMIC_RELAXED, AGENT);
                    v3 = __hip_atomic_load(src + 3, __ATOMIC_RELAXED, AGENT);
                } while (v0 == SENT || v1 == SENT || v2 == SENT || v3 == SENT);
                uint4v v; v.x = v0; v.y = v1; v.z = v2; v.w = v3;
                *(uint4v*)&hS2[(tid >> 4) * 136 + (tid & 15) * 8] = v;
            }
            __syncthreads();
            WLA(DOTC)
        }
        part[tid] = (a0 + a1) + (a2 + a3);
        __syncthreads();
        if (tid < 64) {
            float gi = xi + part[(0   + tid) * 2] + part[(0   + tid) * 2 + 1];
            float gf = xf + part[(64  + tid) * 2] + part[(64  + tid) * 2 + 1];
            float gg = xg + part[(128 + tid) * 2] + part[(128 + tid) * 2 + 1];
            float go = xo + part[(192 + tid) * 2] + part[(192 + tid) * 2 + 1];
            cst = sigm_(gf) * cst + sigm_(gi) * tanh_(gg);
            float h = sigm_(go) * tanh_(cst);
            float hlo = __shfl(h, tid * 2);
            float hhi = __shfl(h, tid * 2 + 1);
            if (t + 1 < T && tid < 32) {
                half2v hp; hp[0] = (_Float16)hlo; hp[1] = (_Float16)hhi;
                __hip_atomic_store(&hExT[((long)t * 32 + b) * 256 + j * 32 + tid],
                                   *(unsigned*)&hp, __ATOMIC_RELAXED, AGENT);
            }
            asm volatile("" ::: "memory");
            long so = ((long)b * T + t) * 512 + j * 64 + tid;
            seq_out[so] = f2bf(h);
            if (f32_out) f32_out[((long)b * T + t) * f32_ld + j * 64 + tid] = h;
        }
    }
}

// ---------- token build ----------
__global__ __launch_bounds__(256) void tok_k(
    const float* __restrict__ holf, const u16* __restrict__ cemb,
    const int* __restrict__ label, u16* __restrict__ tok)
{
    int idx = blockIdx.x * 256 + threadIdx.x;
    int c = idx & 511;
    int m = idx >> 9;
    int b = m / 27, t = m % 27;
    float v;
    if (t == 0) v = holf[(long)b * 512 + c];
    else v = bf2f(cemb[(long)label[b * 26 + (t - 1)] * 512 + c]);
    tok[idx] = f2bf(v);
}

// ---------- fused score v2 (r9-verified) ----------
__global__ __launch_bounds__(256) void score_k(
    const float* __restrict__ q, const u16* __restrict__ kmap,
    const u16* __restrict__ sW, const u16* __restrict__ sb,
    const float* __restrict__ vr, float* __restrict__ aw)
{
    int blk = blockIdx.x;
    int xcd = blk & 7, rest = blk >> 3;
    int bq = rest & 3, t = rest >> 2;
    int b = xcd * 4 + bq;
    int bt = b * 27 + t;
    int tid = threadIdx.x, wv = tid >> 6, ln = tid & 63;

    __shared__ float sc[240];
    __shared__ float red[256];

    float qr[8], sr[8];
    const float* qp = q + (long)bt * 512 + ln * 8;
    #pragma unroll
    for (int i = 0; i < 8; i++) qr[i] = qp[i];
    #pragma unroll
    for (int i = 0; i < 8; i++) sr[i] = bf2f(sW[ln * 8 + i]);

    const u16* kb_ = kmap + (long)b * 240 * 512;
    for (int r = wv * 60; r < wv * 60 + 60; r++) {
        short8 kv = *(const short8*)(kb_ + (long)r * 512 + ln * 8);
        float acc = 0.f;
        #pragma unroll
        for (int i = 0; i < 8; i++) {
            float x = bf2f((u16)kv[i]) + qr[i];
            acc = fmaf(sr[i], tanh_(x), acc);
        }
        #pragma unroll
        for (int m = 32; m > 0; m >>= 1) acc += __shfl_xor(acc, m);
        if (ln == 0) sc[r] = acc;
    }
    __syncthreads();

    float scv = -INFINITY, ex = 0.f;
    if (tid < 240) {
        float rr = vr[b];
        int vw = (int)ceilf(40.f * rr);
        if (vw > 40) vw = 40;
        int wcol = tid % 40;
        scv = (wcol >= vw) ? -INFINITY : (sc[tid] + bf2f(sb[0]));
    }
    red[tid] = scv;
    __syncthreads();
    for (int s = 128; s > 0; s >>= 1) {
        if (tid < s) red[tid] = fmaxf(red[tid], red[tid + s]);
        __syncthreads();
    }
    float mx = red[0];
    __syncthreads();
    if (tid < 240) ex = (scv == -INFINITY) ? 0.f : __expf(scv - mx);
    red[tid] = ex;
    __syncthreads();
    for (int s = 128; s > 0; s >>= 1) {
        if (tid < s) red[tid] += red[tid + s];
        __syncthreads();
    }
    float inv = __builtin_amdgcn_rcpf(red[0]);
    if (tid < 240) aw[(long)bt * 240 + tid] = ex * inv;
}

// ---------- attn_feat -> concat cols [512,1024) ----------
__global__ __launch_bounds__(256) void attn_k(
    const void* __restrict__ feat, const float* __restrict__ aw,
    float* __restrict__ concat, const int* __restrict__ flag)
{
    const int fl = *flag;
    int b = blockIdx.x >> 3;
    int cc = (blockIdx.x & 7) * 64;
    int tid = threadIdx.x;
    __shared__ float awS[27 * 240];
    __shared__ u16 fS[64 * 240];
    for (int i = tid; i < 27 * 240; i += 256) awS[i] = aw[(long)b * 27 * 240 + i];
    long fbase = ((long)b * 512 + cc) * 240;
    for (int i = tid; i < 64 * 240; i += 256)
        fS[i] = fl ? f2bf(((const float*)feat)[fbase + i]) : ((const u16*)feat)[fbase + i];
    __syncthreads();
    for (int item = tid; item < 64 * 27; item += 256) {
        int c = item / 27, t = item % 27;
        const u16* fp = &fS[c * 240];
        const float* ap = &awS[t * 240];
        float acc = 0.f;
        for (int hw = 0; hw < 240; hw++) acc = fmaf(bf2f(fp[hw]), ap[hw], acc);
        concat[((long)(b * 27 + t)) * 1536 + 512 + cc + c] = acc;
    }
}

// ---------- prediction + slice (v14: short8 weight stream — was 1536 scalar u16 loads/lane) ----------
__global__ __launch_bounds__(256) void pred_k(
    const float* __restrict__ concat, const float* __restrict__ holf,
    const u16* __restrict__ pW, const u16* __restrict__ pb,
    void* __restrict__ out, const int* __restrict__ flag)
{
    int m0 = blockIdx.x * 4;
    int tid = threadIdx.x;
    const int fl = *flag;
    __shared__ float aS[4][1024];
    __shared__ float hS[4][512];
    for (int i = tid; i < 4 * 1024; i += 256)
        aS[i / 1024][i % 1024] = concat[(long)(m0 + i / 1024) * 1536 + (i % 1024)];
    for (int i = tid; i < 4 * 512; i += 256) {
        int m = m0 + i / 512;
        hS[i / 512][i % 512] = holf[(long)(m / 27) * 512 + (i % 512)];
    }
    __syncthreads();
    int r = tid >> 6;
    int nb = tid & 63;
    int m = m0 + r;
    int b = m / 27, t = m % 27;
    for (int n = nb; n < 97; n += 64) {
        const u16* wp = pW + (long)n * 1536;     // 16B-aligned (OFF_PREDW*2 and 3072B rows)
        float acc = 0.f;
        for (int k0 = 0; k0 < 1024; k0 += 8) {
            short8 wv8 = *(const short8*)(wp + k0);
            #pragma unroll
            for (int q = 0; q < 8; q++) acc = fmaf(aS[r][k0 + q], bf2f((u16)wv8[q]), acc);
        }
        for (int k0 = 0; k0 < 512; k0 += 8) {
            short8 wv8 = *(const short8*)(wp + 1024 + k0);
            #pragma unroll
            for (int q = 0; q < 8; q++) acc = fmaf(hS[r][k0 + q], bf2f((u16)wv8[q]), acc);
        }
        acc += bf2f(pb[n]);
        if (t > 0) {
            long o = ((long)(b * 26 + (t - 1))) * 97 + n;
            if (fl) ((float*)out)[o] = acc;
            else    ((u16*)out)[o] = f2bf(acc);
        }
    }
}

// ---------- launch ----------
extern "C" void kernel_launch(void* const* d_in, const int* in_sizes, int n_in,
                              void* d_out, int out_size, void* d_ws, size_t ws_size,
                              hipStream_t stream) {
    (void)in_sizes; (void)n_in; (void)out_size; (void)ws_size;
    const void* feat_r = d_in[0];
    const int*  label  = (const int*)d_in[1];
    const void* vr_r   = d_in[2];

    char* w = (char*)d_ws;
    size_t off = 0;
    auto alloc = [&](size_t bytes) -> void* {
        void* p = w + off;
        off = (off + bytes + 63) & ~(size_t)63;
        return p;
    };
    int*   flag    = (int*)  alloc(4);
    unsigned* hEx  = (unsigned*)alloc((size_t)HEX_WORDS * 4);
    u16*   canon   = (u16*)  alloc((size_t)CANON_TOTAL * 2);
    float* cvr     = (float*)alloc(32ull * 4);
    u16*   featv   = (u16*)  alloc(655360ull * 2);
    float* xpre    = (float*)alloc(2621440ull * 4);   // kmap aliases after LSTMs
    u16*   seq0    = (u16*)  alloc(655360ull * 2);
    u16*   seq1    = (u16*)  alloc(655360ull * 2);
    u16*   tok     = (u16*)  alloc(442368ull * 2);
    u16*   seqd0   = (u16*)  alloc(442368ull * 2);
    u16*   Hid     = (u16*)  alloc(442368ull * 2);
    float* holf    = (float*)alloc(16384ull * 4);
    float* qf      = (float*)alloc(442368ull * 4);
    u16*   featP   = (u16*)  alloc(5505024ull * 2);
    u16*   W2      = (u16*)  alloc(2359296ull * 2);
    float* aw      = (float*)alloc(207360ull * 4);
    float* concat  = (float*)alloc(1327104ull * 4);
    _Float16* Wq[4];
    for (int i = 0; i < 4; i++) Wq[i] = (_Float16*)alloc(1048576ull * 2);
    u16*   kmap    = (u16*)xpre;

    unsigned* hEx0 = hEx;
    unsigned* hEx1 = hEx + 40ull * 8192;
    unsigned* hEx2 = hEx + 80ull * 8192;
    unsigned* hEx3 = hEx + 107ull * 8192;

    u16* cW0    = canon + OFF_W0;
    u16* cW1    = canon + OFF_W1;
    u16* cW2    = canon + OFF_W2;
    u16* cW3    = canon + OFF_W3;
    u16* cb0    = canon + OFF_B;
    u16* cencW  = canon + OFF_ENCW;
    u16* cqW    = canon + OFF_QW;
    u16* cpredW = canon + OFF_PREDW;
    u16* cemb   = canon + OFF_EMB;
    u16* cencb  = canon + OFF_ENCB;
    u16* cqb    = canon + OFF_QB;
    u16* ckb    = canon + OFF_KB;
    u16* csW    = canon + OFF_SW;
    u16* csb    = canon + OFF_SB;
    u16* cpredb = canon + OFF_PREDB;

    // ---- fused prep (6 branches, incl. feat transpose) ----
    PrepArgs P;
    P.S.e0Wih = d_in[3];  P.S.e1Wih = d_in[7];  P.S.d0Wih = d_in[20]; P.S.d1Wih = d_in[24];
    P.S.b0 = d_in[5];  P.S.b1 = d_in[6];  P.S.b2 = d_in[9];  P.S.b3 = d_in[10];
    P.S.b4 = d_in[22]; P.S.b5 = d_in[23]; P.S.b6 = d_in[26]; P.S.b7 = d_in[27];
    P.S.encW = d_in[11]; P.S.qW = d_in[13]; P.S.predW = d_in[28]; P.S.emb = d_in[19];
    P.S.encb = d_in[12]; P.S.qb = d_in[14]; P.S.kb = d_in[16]; P.S.sW = d_in[17];
    P.S.sb = d_in[18]; P.S.predb = d_in[29];
    P.feat_raw = feat_r; P.vr_src = vr_r; P.kW_src = d_in[15];
    P.wq_s0 = d_in[4]; P.wq_s1 = d_in[8]; P.wq_s2 = d_in[21]; P.wq_s3 = d_in[25];
    P.flag = flag; P.hEx = hEx; P.canon = canon; P.cvr = cvr;
    P.W2 = W2;
    P.wq_d0 = Wq[0]; P.wq_d1 = Wq[1]; P.wq_d2 = Wq[2]; P.wq_d3 = Wq[3];
    P.featv = featv; P.featP = featP;
    prep_all<<<dim3(PB_TOTAL), 256, 0, stream>>>(P);

    // ---- encoder ----
    gemm_nt_128<<<dim3(16, 10), 512, 65536, stream>>>(featv, cW0, cb0 + 0 * 2048, cb0 + 1 * 2048, xpre, 1280, 2048);
    lstm_sync<<<dim3(256), 512, 0, stream>>>(xpre, Wq[0], seq0, nullptr, hEx0, 40, 0);
    gemm_nt_128<<<dim3(16, 10), 512, 65536, stream>>>(seq0, cW1, cb0 + 2 * 2048, cb0 + 3 * 2048, xpre, 1280, 2048);
    lstm_sync<<<dim3(256), 512, 0, stream>>>(xpre, Wq[1], seq1, nullptr, hEx1, 40, 0);
    gemm_nt_f32<<<dim3(8, 1), 256, 0, stream>>>(seq1 + 39 * 512, 40 * 512, cencW, cencb, nullptr, holf, 32, 512, 512, 512);

    // ---- decoder ----
    tok_k<<<dim3(1728), 256, 0, stream>>>(holf, cemb, label, tok);
    gemm_nt_128<<<dim3(16, 7), 512, 65536, stream>>>(tok, cW2, cb0 + 4 * 2048, cb0 + 5 * 2048, xpre, 864, 2048);
    lstm_sync<<<dim3(256), 512, 0, stream>>>(xpre, Wq[2], seqd0, nullptr, hEx2, 27, 0);
    gemm_nt_128<<<dim3(16, 7), 512, 65536, stream>>>(seqd0, cW3, cb0 + 6 * 2048, cb0 + 7 * 2048, xpre, 864, 2048);
    lstm_sync<<<dim3(256), 512, 0, stream>>>(xpre, Wq[3], Hid, concat, hEx3, 27, 1536);

    // ---- attention: qf GEMM co-dispatched with conv (xpre dead; kmap aliases it) ----
    qf_conv<<<dim3(284), 512, 65536, stream>>>(Hid, cqW, cqb, qf, featP, W2, ckb, kmap);
    score_k<<<dim3(864), 256, 0, stream>>>(qf, kmap, csW, csb, cvr, aw);
    attn_k<<<dim3(256), 256, 0, stream>>>(feat_r, aw, concat, flag);

    // ---- prediction ----
    pred_k<<<dim3(216), 256, 0, stream>>>(concat, holf, cpredW, cpredb, d_out, flag);
}

// Round 13
// 733.016 us; speedup vs baseline: 1.2023x; 1.0137x over previous
//
#include <hip/hip_runtime.h>

typedef unsigned short u16;
typedef __attribute__((ext_vector_type(8))) short short8;
typedef __attribute__((ext_vector_type(4))) float floatx4;
typedef _Float16 half8 __attribute__((ext_vector_type(8)));
typedef _Float16 half2v __attribute__((ext_vector_type(2)));
typedef unsigned uint4v __attribute__((ext_vector_type(4)));

#define AGENT __HIP_MEMORY_SCOPE_AGENT
#define SENT 0x7FFF7FFFu   // f16 NaN pair — unreachable: h = sigm*tanh in (-1,1)

// ---------- helpers ----------
__device__ __forceinline__ float bf2f(u16 v) { return __uint_as_float(((unsigned)v) << 16); }
__device__ __forceinline__ u16 f2bf(float f) {
    unsigned u = __float_as_uint(f);
    unsigned r = (u + 0x7FFFu + ((u >> 16) & 1u)) >> 16;
    return (u16)r;
}
// fast transcendentals: native v_exp + raw v_rcp (no precise-div sequence)
__device__ __forceinline__ float sigm_(float x) {
    return __builtin_amdgcn_rcpf(1.f + __expf(-x));
}
__device__ __forceinline__ float tanh_(float x) {
    x = fminf(fmaxf(x, -15.f), 15.f);
    float e = __expf(2.f * x);
    return (e - 1.f) * __builtin_amdgcn_rcpf(e + 1.f);
}

// async global->LDS, 16B per lane; LDS dest is wave-uniform base + lane*16
typedef __attribute__((address_space(1))) void gvoid_t;
typedef __attribute__((address_space(3))) void lvoid_t;
__device__ __forceinline__ void gl_lds16(const void* g, void* l) {
    __builtin_amdgcn_global_load_lds((gvoid_t*)g, (lvoid_t*)l, 16, 0, 0);
}

// B=32, C=512, H=6, W=40, NC=97, L=26, T=27
#define HEX_WORDS (134 * 32 * 256)

// ---------- offsets ----------
struct SrcPtrs {
    const void* e0Wih; const void* e1Wih; const void* d0Wih; const void* d1Wih;
    const void* b0; const void* b1; const void* b2; const void* b3;
    const void* b4; const void* b5; const void* b6; const void* b7;
    const void* encW; const void* qW; const void* predW; const void* emb;
    const void* encb; const void* qb; const void* kb; const void* sW;
    const void* sb; const void* predb;
};
#define OFF_W0      0
#define OFF_W1      1048576
#define OFF_W2      2097152
#define OFF_W3      3145728
#define OFF_B       4194304
#define OFF_ENCW    4210688
#define OFF_QW      4472832
#define OFF_PREDW   4734976
#define OFF_EMB     4883968
#define OFF_ENCB    4933632
#define OFF_QB      4934144
#define OFF_KB      4934656
#define OFF_SW      4935168
#define OFF_SB      4935680
#define OFF_PREDB   4935681
#define CANON_TOTAL 4935778

// ---------- dtype sniff (32 loads of ONE 64B line; L2-broadcast ~free) ----------
__device__ __forceinline__ int sniff_(const void* feat_raw) {
    const u16* p = (const u16*)feat_raw;
    int insane = 0;
    #pragma unroll
    for (int i = 0; i < 32; i += 2) {
        float x = bf2f(p[i]);
        float a = fabsf(x);
        if (!(a <= 1000.f)) insane = 1;
        if (x != 0.f && a < 1e-8f) insane = 1;
    }
    return insane;
}

// ---------- v15: fused prep — featp tile halved to 32 channels ----------
// v14 post-mortem: merging featp with a static S[64][242] (31 KB) charged 31 KB LDS to
// ALL 35K prep blocks -> 5 blocks/CU, Occupancy 33%, hbm 1.5 TB/s, 120 µs (v12 ran 63%
// / 2.3 TB/s). v15: featp processes 32 channels/block (512 blocks), S[32][242] = 15.5 KB
// -> 8 blocks/CU (full 32 waves). Transpose slab still contiguous; LDS col reads still
// conflict-free (stride 121 dwords, gcd(121,32)=1); stores still coalesced.
struct PrepArgs {
    SrcPtrs S;
    const void* feat_raw;
    const void* vr_src;
    const void* kW_src;
    const void* wq_s0; const void* wq_s1; const void* wq_s2; const void* wq_s3;
    int* flag;
    unsigned* hEx;
    u16* canon;
    float* cvr;
    u16* W2;
    _Float16* wq_d0; _Float16* wq_d1; _Float16* wq_d2; _Float16* wq_d3;
    u16* featv;
    u16* featP;
};

// block ranges
#define PB_INIT    0        // 4288 blocks  : hEx sentinel fill (+flag from idx 0)
#define PB_CANON   4288     // 19281 blocks : canon_all
#define PB_CANONF  23569    // 1 block      : cvr (32 floats)
#define PB_W2      23570    // 9216 blocks  : conv weight reshuffle
#define PB_WQ3     32786    // 2048 blocks  : 4x Whh -> f16 dot layout
#define PB_FEATP   34834    // 512 blocks   : LDS-tiled feat transpose, 32 ch/block
#define PB_TOTAL   35346

__global__ __launch_bounds__(256) void prep_all(PrepArgs P)
{
    const int blk = blockIdx.x;
    const int tid = threadIdx.x;

    if (blk < PB_CANON) {                       // ---- init: sentinel fill ----
        int idx = blk * 256 + tid;
        P.hEx[idx] = SENT;
        if (idx == 0) *P.flag = sniff_(P.feat_raw);
        return;
    }
    const int fl = sniff_(P.feat_raw);          // per-block local dtype flag

    if (blk < PB_CANONF) {                      // ---- canon_all ----
        int idx = (blk - PB_CANON) * 256 + tid;
        if (idx >= CANON_TOTAL) return;
        const SrcPtrs& S = P.S;
        const void* s; int loc;
        if (idx < OFF_B) {
            int k = idx >> 20; loc = idx & 1048575;
            s = (k == 0) ? S.e0Wih : (k == 1) ? S.e1Wih : (k == 2) ? S.d0Wih : S.d1Wih;
        } else if (idx < OFF_ENCW) {
            int r = idx - OFF_B; int k = r >> 11; loc = r & 2047;
            s = (k == 0) ? S.b0 : (k == 1) ? S.b1 : (k == 2) ? S.b2 : (k == 3) ? S.b3
              : (k == 4) ? S.b4 : (k == 5) ? S.b5 : (k == 6) ? S.b6 : S.b7;
        } else if (idx < OFF_QW)    { s = S.encW;  loc = idx - OFF_ENCW; }
        else if (idx < OFF_PREDW)   { s = S.qW;    loc = idx - OFF_QW; }
        else if (idx < OFF_EMB)     { s = S.predW; loc = idx - OFF_PREDW; }
        else if (idx < OFF_ENCB)    { s = S.emb;   loc = idx - OFF_EMB; }
        else if (idx < OFF_QB)      { s = S.encb;  loc = idx - OFF_ENCB; }
        else if (idx < OFF_KB)      { s = S.qb;    loc = idx - OFF_QB; }
        else if (idx < OFF_SW)      { s = S.kb;    loc = idx - OFF_KB; }
        else if (idx < OFF_SB)      { s = S.sW;    loc = idx - OFF_SW; }
        else if (idx < OFF_PREDB)   { s = S.sb;    loc = idx - OFF_SB; }
        else                        { s = S.predb; loc = idx - OFF_PREDB; }
        P.canon[idx] = fl ? f2bf(((const float*)s)[loc]) : ((const u16*)s)[loc];
    } else if (blk == PB_CANONF) {              // ---- canonf (valid_ratios) ----
        if (tid < 32)
            P.cvr[tid] = fl ? ((const float*)P.vr_src)[tid] : bf2f(((const u16*)P.vr_src)[tid]);
    } else if (blk < PB_WQ3) {                  // ---- w2 ----
        int idx = (blk - PB_W2) * 256 + tid;
        int co = idx / 4608;
        int r = idx % 4608;
        int kh = r / 1536;
        int r2 = r % 1536;
        int kw = r2 / 512;
        int ci = r2 & 511;
        long si = ((long)(co * 512 + ci) * 3 + kh) * 3 + kw;
        P.W2[idx] = fl ? f2bf(((const float*)P.kW_src)[si]) : ((const u16*)P.kW_src)[si];
    } else if (blk < PB_FEATP) {                // ---- wq3_all ----
        int gb = blk - PB_WQ3;
        int id = gb >> 9;
        const void* W = (id == 0) ? P.wq_s0 : (id == 1) ? P.wq_s1 : (id == 2) ? P.wq_s2 : P.wq_s3;
        _Float16* D = (id == 0) ? P.wq_d0 : (id == 1) ? P.wq_d1 : (id == 2) ? P.wq_d2 : P.wq_d3;
        int o = (gb & 511) * 256 + tid;
        int t = o & 511;
        int c = (o >> 9) & 31;
        int j = o >> 14;
        int rid = t >> 1, hf = t & 1;
        int n = (rid >> 6) * 512 + j * 64 + (rid & 63);
        int k = hf * 256 + c * 8;
        _Float16* dst = D + (long)o * 8;
        #pragma unroll
        for (int jj = 0; jj < 8; jj++) {
            long si = (long)n * 512 + k + jj;
            float v = fl ? ((const float*)W)[si] : bf2f(((const u16*)W)[si]);
            dst[jj] = (_Float16)v;
        }
    } else {                                    // ---- featp: LDS-tiled transpose (32 ch) ----
        __shared__ u16 S[32][242];
        int q = blk - PB_FEATP;
        int b = q >> 4;
        int c0 = (q & 15) * 32;
        long gbase = ((long)b * 512 + c0) * 240;
        for (int i = tid; i < 32 * 240; i += 256) {
            float x = fl ? ((const float*)P.feat_raw)[gbase + i] : bf2f(((const u16*)P.feat_raw)[gbase + i]);
            S[i / 240][i % 240] = f2bf(x);
        }
        __syncthreads();
        for (int i = tid; i < 40 * 32; i += 256) {
            int w = i >> 5, c = i & 31;
            float mx = bf2f(S[c][w]);
            #pragma unroll
            for (int h = 1; h < 6; h++) mx = fmaxf(mx, bf2f(S[c][h * 40 + w]));
            P.featv[((long)(b * 40 + w)) * 512 + c0 + c] = f2bf(mx);
        }
        for (int i = tid; i < 6 * 40 * 32; i += 256) {
            int c = i & 31; int r = i >> 5;
            int wp1 = r % 40, hp1 = r / 40;
            P.featP[((long)(b * 8 + hp1 + 1) * 42 + (wp1 + 1)) * 512 + c0 + c] = S[c][hp1 * 40 + wp1];
        }
        for (int i = tid; i < 96 * 32; i += 256) {
            int c = i & 31; int r = i >> 5;
            int hp, wp;
            if (r < 42)      { hp = 0; wp = r; }
            else if (r < 84) { hp = 7; wp = r - 42; }
            else             { int q2 = r - 84; hp = 1 + (q2 >> 1); wp = (q2 & 1) * 41; }
            P.featP[((long)(b * 8 + hp) * 42 + wp) * 512 + c0 + c] = 0;
        }
    }
}

// ---------- NT GEMM (64-tile; kept for tiny M=32 encW GEMM) ----------
__global__ __launch_bounds__(256) void gemm_nt_f32(
    const u16* __restrict__ A, int lda,
    const u16* __restrict__ Bw,
    const u16* __restrict__ bias0, const u16* __restrict__ bias1,
    float* __restrict__ C, int M, int N, int K, int ldc)
{
    __shared__ __align__(16) u16 As[64][40];
    __shared__ __align__(16) u16 Bs[64][40];
    const int tid = threadIdx.x;
    const int bn = blockIdx.x, bm = blockIdx.y;
    const int l = tid & 63, wid = tid >> 6;
    const int wm = wid >> 1, wn = wid & 1;
    const int lr = tid >> 2, lc = (tid & 3) * 8;
    const int l15 = l & 15, lq = l >> 4;

    floatx4 acc00 = (floatx4)(0.f), acc01 = (floatx4)(0.f), acc10 = (floatx4)(0.f), acc11 = (floatx4)(0.f);

    int am = bm * 64 + lr; if (am > M - 1) am = M - 1;
    const u16* Ap = A + (long)am * lda + lc;
    const u16* Bp = Bw + (long)(bn * 64 + lr) * K + lc;

    for (int k0 = 0; k0 < K; k0 += 32) {
        *(short8*)&As[lr][lc] = *(const short8*)(Ap + k0);
        *(short8*)&Bs[lr][lc] = *(const short8*)(Bp + k0);
        __syncthreads();
        short8 af0 = *(const short8*)&As[wm * 32 + l15][lq * 8];
        short8 af1 = *(const short8*)&As[wm * 32 + 16 + l15][lq * 8];
        short8 bf0 = *(const short8*)&Bs[wn * 32 + l15][lq * 8];
        short8 bf1 = *(const short8*)&Bs[wn * 32 + 16 + l15][lq * 8];
        acc00 = __builtin_amdgcn_mfma_f32_16x16x32_bf16(af0, bf0, acc00, 0, 0, 0);
        acc01 = __builtin_amdgcn_mfma_f32_16x16x32_bf16(af0, bf1, acc01, 0, 0, 0);
        acc10 = __builtin_amdgcn_mfma_f32_16x16x32_bf16(af1, bf0, acc10, 0, 0, 0);
        acc11 = __builtin_amdgcn_mfma_f32_16x16x32_bf16(af1, bf1, acc11, 0, 0, 0);
        __syncthreads();
    }
    floatx4 accs[2][2] = {{acc00, acc01}, {acc10, acc11}};
    #pragma unroll
    for (int i = 0; i < 2; i++)
        #pragma unroll
        for (int j = 0; j < 2; j++)
            #pragma unroll
            for (int r = 0; r < 4; r++) {
                int gm = bm * 64 + wm * 32 + i * 16 + lq * 4 + r;
                int gn = bn * 64 + wn * 32 + j * 16 + l15;
                if (gm < M) {
                    float v = accs[i][j][r];
                    if (bias0) v += bf2f(bias0[gn]);
                    if (bias1) v += bf2f(bias1[gn]);
                    C[(long)gm * ldc + gn] = v;
                }
            }
}

// ---------- 128x128 tile bodies (dynamic LDS so qf GEMM + conv can share one kernel) ----------
// Layout: As = lds[0 .. 4*128*32), Bs = lds[4*128*32 .. 8*128*32)  (64 KB total)
__device__ __forceinline__ void gemm128_body(
    u16* lds, const u16* __restrict__ A, const u16* __restrict__ Bw,
    const u16* __restrict__ bias0, const u16* __restrict__ bias1,
    float* __restrict__ C, int M, int ldc, int bn, int bm)
{
    u16 (*As)[128][32] = (u16(*)[128][32])lds;
    u16 (*Bs)[128][32] = (u16(*)[128][32])(lds + 4 * 128 * 32);
    const int tid = threadIdx.x;
    const int wv = tid >> 6, l = tid & 63;
    const int wm = wv >> 2, wn = wv & 3;
    const int l15 = l & 15, lq = l >> 4;
    const int ch = ((l & 3) ^ ((l >> 3) & 3)) * 8;

    int ar = bm * 128 + wv * 16 + (l >> 2);
    if (ar > M - 1) ar = M - 1;
    const u16* ga = A + (long)ar * 512 + ch;
    const u16* gb = Bw + (long)(bn * 128 + wv * 16 + (l >> 2)) * 512 + ch;

    floatx4 acc[4][2];
    #pragma unroll
    for (int i = 0; i < 4; i++)
        #pragma unroll
        for (int j = 0; j < 2; j++) acc[i][j] = (floatx4)(0.f);

    auto stage = [&](int k0, int pb) {
        gl_lds16(ga + k0, &As[pb][wv * 16][0]);
        gl_lds16(gb + k0, &Bs[pb][wv * 16][0]);
    };
    const int rs = (lq ^ ((l15 >> 1) & 3)) * 8;
    auto compute = [&](int cur) {
        short8 af[4], bf[2];
        #pragma unroll
        for (int i = 0; i < 4; i++) af[i] = *(const short8*)&As[cur][wm * 64 + i * 16 + l15][rs];
        #pragma unroll
        for (int j = 0; j < 2; j++) bf[j] = *(const short8*)&Bs[cur][wn * 32 + j * 16 + l15][rs];
        #pragma unroll
        for (int i = 0; i < 4; i++)
            #pragma unroll
            for (int j = 0; j < 2; j++)
                acc[i][j] = __builtin_amdgcn_mfma_f32_16x16x32_bf16(af[i], bf[j], acc[i][j], 0, 0, 0);
    };

    stage(0, 0); stage(32, 1); stage(64, 2);
    for (int k = 0; k < 14; k++) {
        asm volatile("s_waitcnt vmcnt(4)" ::: "memory");
        __builtin_amdgcn_s_barrier();
        asm volatile("" ::: "memory");
        if (k < 13) stage((k + 3) * 32, (k + 3) & 3);
        compute(k & 3);
    }
    asm volatile("s_waitcnt vmcnt(2)" ::: "memory");
    __builtin_amdgcn_s_barrier();
    asm volatile("" ::: "memory");
    compute(2);
    asm volatile("s_waitcnt vmcnt(0)" ::: "memory");
    __builtin_amdgcn_s_barrier();
    asm volatile("" ::: "memory");
    compute(3);

    #pragma unroll
    for (int i = 0; i < 4; i++)
        #pragma unroll
        for (int j = 0; j < 2; j++)
            #pragma unroll
            for (int r = 0; r < 4; r++) {
                int gm = bm * 128 + wm * 64 + i * 16 + lq * 4 + r;
                int gn = bn * 128 + wn * 32 + j * 16 + l15;
                if (gm < M) {
                    float v = acc[i][j][r];
                    if (bias0) v += bf2f(bias0[gn]);
                    if (bias1) v += bf2f(bias1[gn]);
                    C[(long)gm * ldc + gn] = v;
                }
            }
}

__device__ __forceinline__ void conv_body(
    u16* lds, const u16* __restrict__ featP, const u16* __restrict__ W2,
    const u16* __restrict__ kb, u16* __restrict__ kmap, int bx, int by)
{
    u16 (*As)[128][32] = (u16(*)[128][32])lds;
    u16 (*Bs)[128][32] = (u16(*)[128][32])(lds + 4 * 128 * 32);
    const int tid = threadIdx.x;
    int bm = bx * 8 + (by & 7);
    int bn = by >> 3;
    if (bm >= 60) return;
    const int wv = tid >> 6, l = tid & 63;
    const int wm = wv >> 2, wn = wv & 3;
    const int l15 = l & 15, lq = l >> 4;
    const int ch = ((l & 3) ^ ((l >> 3) & 3)) * 8;

    int ar = bm * 128 + wv * 16 + (l >> 2);
    int ab = ar / 240, ahw = ar % 240;
    const u16* ga = featP + ((long)(ab * 8 + ahw / 40) * 42 + (ahw % 40)) * 512 + ch;
    const u16* gb = W2 + (long)(bn * 128 + wv * 16 + (l >> 2)) * 4608 + ch;

    floatx4 acc[4][2];
    #pragma unroll
    for (int i = 0; i < 4; i++)
        #pragma unroll
        for (int j = 0; j < 2; j++) acc[i][j] = (floatx4)(0.f);

    auto stage = [&](int k0, int pb) {
        int kh = k0 / 1536;
        int rem = k0 - kh * 1536;
        int aoff = (kh * 42 + (rem >> 9)) * 512 + (rem & 511);
        gl_lds16(ga + aoff, &As[pb][wv * 16][0]);
        gl_lds16(gb + k0, &Bs[pb][wv * 16][0]);
    };
    const int rs = (lq ^ ((l15 >> 1) & 3)) * 8;
    auto compute = [&](int cur) {
        short8 af[4], bf[2];
        #pragma unroll
        for (int i = 0; i < 4; i++) af[i] = *(const short8*)&As[cur][wm * 64 + i * 16 + l15][rs];
        #pragma unroll
        for (int j = 0; j < 2; j++) bf[j] = *(const short8*)&Bs[cur][wn * 32 + j * 16 + l15][rs];
        #pragma unroll
        for (int i = 0; i < 4; i++)
            #pragma unroll
            for (int j = 0; j < 2; j++)
                acc[i][j] = __builtin_amdgcn_mfma_f32_16x16x32_bf16(af[i], bf[j], acc[i][j], 0, 0, 0);
    };

    stage(0, 0); stage(32, 1); stage(64, 2);
    for (int k = 0; k < 142; k++) {
        asm volatile("s_waitcnt vmcnt(4)" ::: "memory");
        __builtin_amdgcn_s_barrier();
        asm volatile("" ::: "memory");
        if (k < 141) stage((k + 3) * 32, (k + 3) & 3);
        compute(k & 3);
    }
    asm volatile("s_waitcnt vmcnt(2)" ::: "memory");
    __builtin_amdgcn_s_barrier();
    asm volatile("" ::: "memory");
    compute(2);
    asm volatile("s_waitcnt vmcnt(0)" ::: "memory");
    __builtin_amdgcn_s_barrier();
    asm volatile("" ::: "memory");
    compute(3);

    #pragma unroll
    for (int i = 0; i < 4; i++)
        #pragma unroll
        for (int j = 0; j < 2; j++)
            #pragma unroll
            for (int r = 0; r < 4; r++) {
                int row = bm * 128 + wm * 64 + i * 16 + lq * 4 + r;
                int col = bn * 128 + wn * 32 + j * 16 + l15;
                kmap[(long)row * 512 + col] = f2bf(acc[i][j][r] + bf2f(kb[col]));
            }
}

__global__ __launch_bounds__(512) void gemm_nt_128(
    const u16* __restrict__ A, const u16* __restrict__ Bw,
    const u16* __restrict__ bias0, const u16* __restrict__ bias1,
    float* __restrict__ C, int M, int ldc)
{
    extern __shared__ u16 ldsb[];
    gemm128_body(ldsb, A, Bw, bias0, bias1, C, M, ldc, blockIdx.x, blockIdx.y);
}

// ---------- qf GEMM co-dispatched with conv (proven v14) ----------
__global__ __launch_bounds__(512) void qf_conv(
    const u16* __restrict__ Hid, const u16* __restrict__ qW,
    const u16* __restrict__ qb, float* __restrict__ qf,
    const u16* __restrict__ featP, const u16* __restrict__ W2,
    const u16* __restrict__ kb, u16* __restrict__ kmap)
{
    extern __shared__ u16 ldsb[];
    int q = blockIdx.x;
    if (q < 28) {
        gemm128_body(ldsb, Hid, qW, qb, nullptr, qf, 864, 512, q & 3, q >> 2);
    } else {
        int c = q - 28;
        conv_body(ldsb, featP, W2, kb, kmap, c & 7, c >> 3);
    }
}

// ---------- LSTM recurrence v4 (proven): sentinel self-announcing exchange. DO NOT TOUCH. ----------
#define WL(F) F(0) F(1) F(2) F(3) F(4) F(5) F(6) F(7) F(8) F(9) F(10) F(11) F(12) F(13) F(14) F(15) \
              F(16) F(17) F(18) F(19) F(20) F(21) F(22) F(23) F(24) F(25) F(26) F(27) F(28) F(29) F(30) F(31)
#define WLA(F) F(0,0) F(1,1) F(2,2) F(3,3) F(4,0) F(5,1) F(6,2) F(7,3) \
               F(8,0) F(9,1) F(10,2) F(11,3) F(12,0) F(13,1) F(14,2) F(15,3) \
               F(16,0) F(17,1) F(18,2) F(19,3) F(20,0) F(21,1) F(22,2) F(23,3) \
               F(24,0) F(25,1) F(26,2) F(27,3) F(28,0) F(29,1) F(30,2) F(31,3)
#define WDECL(i) half8 w##i = wp8[(long)(j * 32 + i) * 512 + tid];
#define WPIN(i)  asm volatile("" : "+v"(w##i));
#define DOTC(i,k) { \
    half8 hv = *(const half8*)&hS2[(hf * 2 + (i / 16)) * 136 + (i % 16) * 8]; \
    a##k = __builtin_amdgcn_fdot2(__builtin_shufflevector(hv, hv, 0, 1), __builtin_shufflevector(w##i, w##i, 0, 1), a##k, false); \
    a##k = __builtin_amdgcn_fdot2(__builtin_shufflevector(hv, hv, 2, 3), __builtin_shufflevector(w##i, w##i, 2, 3), a##k, false); \
    a##k = __builtin_amdgcn_fdot2(__builtin_shufflevector(hv, hv, 4, 5), __builtin_shufflevector(w##i, w##i, 4, 5), a##k, false); \
    a##k = __builtin_amdgcn_fdot2(__builtin_shufflevector(hv, hv, 6, 7), __builtin_shufflevector(w##i, w##i, 6, 7), a##k, false); }

__global__ __launch_bounds__(512) __attribute__((amdgpu_waves_per_eu(2, 2))) void lstm_sync(
    const float* __restrict__ xpre, const _Float16* __restrict__ Wq3,
    u16* __restrict__ seq_out, float* __restrict__ f32_out,
    unsigned* __restrict__ hExT, int T, int f32_ld)
{
    const int i_ = blockIdx.x;
    const int slot = i_ >> 3;
    const int b = (i_ & 7) * 4 + (slot & 3);
    const int j = slot >> 2;
    const int tid = threadIdx.x;
    const int hf = tid & 1;

    __shared__ __align__(16) _Float16 hS2[4 * 136];
    __shared__ float part[512];

    const half8* wp8 = (const half8*)Wq3;
    WL(WDECL)
    WL(WPIN)
    float cst = 0.f;

    for (int t = 0; t < T; t++) {
        float xi = 0.f, xf = 0.f, xg = 0.f, xo = 0.f;
        if (tid < 64) {
            const float* xp = xpre + ((long)b * T + t) * 2048 + j * 64 + tid;
            xi = xp[0]; xf = xp[512]; xg = xp[1024]; xo = xp[1536];
        }
        float a0 = 0.f, a1 = 0.f, a2 = 0.f, a3 = 0.f;
        if (t > 0) {
            if (tid < 64) {
                const unsigned* src = &hExT[((long)(t - 1) * 32 + b) * 256 + tid * 4];
                unsigned v0, v1, v2, v3;
                do {
                    v0 = __hip_atomic_load(src + 0, __ATOMIC_RELAXED, AGENT);
                    v1 = __hip_atomic_load(src + 1, __ATOMIC_RELAXED, AGENT);
                    v2 = __hip_atomic_load(src + 2, __ATOMIC_RELAXED, AGENT);
                    v3 = __hip_atomic_load(src + 3, __ATOMIC_RELAXED, AGENT);
                } while (v0 == SENT || v1 == SENT || v2 == SENT || v3 == SENT);
                uint4v v; v.x = v0; v.y = v1; v.z = v2; v.w = v3;
                *(uint4v*)&hS2[(tid >> 4) * 136 + (tid & 15) * 8] = v;
            }
            __syncthreads();
            WLA(DOTC)
        }
        part[tid] = (a0 + a1) + (a2 + a3);
        __syncthreads();
        if (tid < 64) {
            float gi = xi + part[(0   + tid) * 2] + part[(0   + tid) * 2 + 1];
            float gf = xf + part[(64  + tid) * 2] + part[(64  + tid) * 2 + 1];
            float gg = xg + part[(128 + tid) * 2] + part[(128 + tid) * 2 + 1];
            float go = xo + part[(192 + tid) * 2] + part[(192 + tid) * 2 + 1];
            cst = sigm_(gf) * cst + sigm_(gi) * tanh_(gg);
            float h = sigm_(go) * tanh_(cst);
            float hlo = __shfl(h, tid * 2);
            float hhi = __shfl(h, tid * 2 + 1);
            if (t + 1 < T && tid < 32) {
                half2v hp; hp[0] = (_Float16)hlo; hp[1] = (_Float16)hhi;
                __hip_atomic_store(&hExT[((long)t * 32 + b) * 256 + j * 32 + tid],
                                   *(unsigned*)&hp, __ATOMIC_RELAXED, AGENT);
            }
            asm volatile("" ::: "memory");
            long so = ((long)b * T + t) * 512 + j * 64 + tid;
            seq_out[so] = f2bf(h);
            if (f32_out) f32_out[((long)b * T + t) * f32_ld + j * 64 + tid] = h;
        }
    }
}

// ---------- token build ----------
__global__ __launch_bounds__(256) void tok_k(
    const float* __restrict__ holf, const u16* __restrict__ cemb,
    const int* __restrict__ label, u16* __restrict__ tok)
{
    int idx = blockIdx.x * 256 + threadIdx.x;
    int c = idx & 511;
    int m = idx >> 9;
    int b = m / 27, t = m % 27;
    float v;
    if (t == 0) v = holf[(long)b * 512 + c];
    else v = bf2f(cemb[(long)label[b * 26 + (t - 1)] * 512 + c]);
    tok[idx] = f2bf(v);
}

// ---------- fused score v2 (r9-verified) ----------
__global__ __launch_bounds__(256) void score_k(
    const float* __restrict__ q, const u16* __restrict__ kmap,
    const u16* __restrict__ sW, const u16* __restrict__ sb,
    const float* __restrict__ vr, float* __restrict__ aw)
{
    int blk = blockIdx.x;
    int xcd = blk & 7, rest = blk >> 3;
    int bq = rest & 3, t = rest >> 2;
    int b = xcd * 4 + bq;
    int bt = b * 27 + t;
    int tid = threadIdx.x, wv = tid >> 6, ln = tid & 63;

    __shared__ float sc[240];
    __shared__ float red[256];

    float qr[8], sr[8];
    const float* qp = q + (long)bt * 512 + ln * 8;
    #pragma unroll
    for (int i = 0; i < 8; i++) qr[i] = qp[i];
    #pragma unroll
    for (int i = 0; i < 8; i++) sr[i] = bf2f(sW[ln * 8 + i]);

    const u16* kb_ = kmap + (long)b * 240 * 512;
    for (int r = wv * 60; r < wv * 60 + 60; r++) {
        short8 kv = *(const short8*)(kb_ + (long)r * 512 + ln * 8);
        float acc = 0.f;
        #pragma unroll
        for (int i = 0; i < 8; i++) {
            float x = bf2f((u16)kv[i]) + qr[i];
            acc = fmaf(sr[i], tanh_(x), acc);
        }
        #pragma unroll
        for (int m = 32; m > 0; m >>= 1) acc += __shfl_xor(acc, m);
        if (ln == 0) sc[r] = acc;
    }
    __syncthreads();

    float scv = -INFINITY, ex = 0.f;
    if (tid < 240) {
        float rr = vr[b];
        int vw = (int)ceilf(40.f * rr);
        if (vw > 40) vw = 40;
        int wcol = tid % 40;
        scv = (wcol >= vw) ? -INFINITY : (sc[tid] + bf2f(sb[0]));
    }
    red[tid] = scv;
    __syncthreads();
    for (int s = 128; s > 0; s >>= 1) {
        if (tid < s) red[tid] = fmaxf(red[tid], red[tid + s]);
        __syncthreads();
    }
    float mx = red[0];
    __syncthreads();
    if (tid < 240) ex = (scv == -INFINITY) ? 0.f : __expf(scv - mx);
    red[tid] = ex;
    __syncthreads();
    for (int s = 128; s > 0; s >>= 1) {
        if (tid < s) red[tid] += red[tid + s];
        __syncthreads();
    }
    float inv = __builtin_amdgcn_rcpf(red[0]);
    if (tid < 240) aw[(long)bt * 240 + tid] = ex * inv;
}

// ---------- attn_feat -> concat cols [512,1024) ----------
__global__ __launch_bounds__(256) void attn_k(
    const void* __restrict__ feat, const float* __restrict__ aw,
    float* __restrict__ concat, const int* __restrict__ flag)
{
    const int fl = *flag;
    int b = blockIdx.x >> 3;
    int cc = (blockIdx.x & 7) * 64;
    int tid = threadIdx.x;
    __shared__ float awS[27 * 240];
    __shared__ u16 fS[64 * 240];
    for (int i = tid; i < 27 * 240; i += 256) awS[i] = aw[(long)b * 27 * 240 + i];
    long fbase = ((long)b * 512 + cc) * 240;
    for (int i = tid; i < 64 * 240; i += 256)
        fS[i] = fl ? f2bf(((const float*)feat)[fbase + i]) : ((const u16*)feat)[fbase + i];
    __syncthreads();
    for (int item = tid; item < 64 * 27; item += 256) {
        int c = item / 27, t = item % 27;
        const u16* fp = &fS[c * 240];
        const float* ap = &awS[t * 240];
        float acc = 0.f;
        for (int hw = 0; hw < 240; hw++) acc = fmaf(bf2f(fp[hw]), ap[hw], acc);
        concat[((long)(b * 27 + t)) * 1536 + 512 + cc + c] = acc;
    }
}

// ---------- prediction + slice (short8 weight stream) ----------
__global__ __launch_bounds__(256) void pred_k(
    const float* __restrict__ concat, const float* __restrict__ holf,
    const u16* __restrict__ pW, const u16* __restrict__ pb,
    void* __restrict__ out, const int* __restrict__ flag)
{
    int m0 = blockIdx.x * 4;
    int tid = threadIdx.x;
    const int fl = *flag;
    __shared__ float aS[4][1024];
    __shared__ float hS[4][512];
    for (int i = tid; i < 4 * 1024; i += 256)
        aS[i / 1024][i % 1024] = concat[(long)(m0 + i / 1024) * 1536 + (i % 1024)];
    for (int i = tid; i < 4 * 512; i += 256) {
        int m = m0 + i / 512;
        hS[i / 512][i % 512] = holf[(long)(m / 27) * 512 + (i % 512)];
    }
    __syncthreads();
    int r = tid >> 6;
    int nb = tid & 63;
    int m = m0 + r;
    int b = m / 27, t = m % 27;
    for (int n = nb; n < 97; n += 64) {
        const u16* wp = pW + (long)n * 1536;     // 16B-aligned (OFF_PREDW*2 and 3072B rows)
        float acc = 0.f;
        for (int k0 = 0; k0 < 1024; k0 += 8) {
            short8 wv8 = *(const short8*)(wp + k0);
            #pragma unroll
            for (int q = 0; q < 8; q++) acc = fmaf(aS[r][k0 + q], bf2f((u16)wv8[q]), acc);
        }
        for (int k0 = 0; k0 < 512; k0 += 8) {
            short8 wv8 = *(const short8*)(wp + 1024 + k0);
            #pragma unroll
            for (int q = 0; q < 8; q++) acc = fmaf(hS[r][k0 + q], bf2f((u16)wv8[q]), acc);
        }
        acc += bf2f(pb[n]);
        if (t > 0) {
            long o = ((long)(b * 26 + (t - 1))) * 97 + n;
            if (fl) ((float*)out)[o] = acc;
            else    ((u16*)out)[o] = f2bf(acc);
        }
    }
}

// ---------- launch ----------
extern "C" void kernel_launch(void* const* d_in, const int* in_sizes, int n_in,
                              void* d_out, int out_size, void* d_ws, size_t ws_size,
                              hipStream_t stream) {
    (void)in_sizes; (void)n_in; (void)out_size; (void)ws_size;
    const void* feat_r = d_in[0];
    const int*  label  = (const int*)d_in[1];
    const void* vr_r   = d_in[2];

    char* w = (char*)d_ws;
    size_t off = 0;
    auto alloc = [&](size_t bytes) -> void* {
        void* p = w + off;
        off = (off + bytes + 63) & ~(size_t)63;
        return p;
    };
    int*   flag    = (int*)  alloc(4);
    unsigned* hEx  = (unsigned*)alloc((size_t)HEX_WORDS * 4);
    u16*   canon   = (u16*)  alloc((size_t)CANON_TOTAL * 2);
    float* cvr     = (float*)alloc(32ull * 4);
    u16*   featv   = (u16*)  alloc(655360ull * 2);
    float* xpre    = (float*)alloc(2621440ull * 4);   // kmap aliases after LSTMs
    u16*   seq0    = (u16*)  alloc(655360ull * 2);
    u16*   seq1    = (u16*)  alloc(655360ull * 2);
    u16*   tok     = (u16*)  alloc(442368ull * 2);
    u16*   seqd0   = (u16*)  alloc(442368ull * 2);
    u16*   Hid     = (u16*)  alloc(442368ull * 2);
    float* holf    = (float*)alloc(16384ull * 4);
    float* qf      = (float*)alloc(442368ull * 4);
    u16*   featP   = (u16*)  alloc(5505024ull * 2);
    u16*   W2      = (u16*)  alloc(2359296ull * 2);
    float* aw      = (float*)alloc(207360ull * 4);
    float* concat  = (float*)alloc(1327104ull * 4);
    _Float16* Wq[4];
    for (int i = 0; i < 4; i++) Wq[i] = (_Float16*)alloc(1048576ull * 2);
    u16*   kmap    = (u16*)xpre;

    unsigned* hEx0 = hEx;
    unsigned* hEx1 = hEx + 40ull * 8192;
    unsigned* hEx2 = hEx + 80ull * 8192;
    unsigned* hEx3 = hEx + 107ull * 8192;

    u16* cW0    = canon + OFF_W0;
    u16* cW1    = canon + OFF_W1;
    u16* cW2    = canon + OFF_W2;
    u16* cW3    = canon + OFF_W3;
    u16* cb0    = canon + OFF_B;
    u16* cencW  = canon + OFF_ENCW;
    u16* cqW    = canon + OFF_QW;
    u16* cpredW = canon + OFF_PREDW;
    u16* cemb   = canon + OFF_EMB;
    u16* cencb  = canon + OFF_ENCB;
    u16* cqb    = canon + OFF_QB;
    u16* ckb    = canon + OFF_KB;
    u16* csW    = canon + OFF_SW;
    u16* csb    = canon + OFF_SB;
    u16* cpredb = canon + OFF_PREDB;

    // ---- fused prep (6 branches, incl. 32-ch feat transpose) ----
    PrepArgs P;
    P.S.e0Wih = d_in[3];  P.S.e1Wih = d_in[7];  P.S.d0Wih = d_in[20]; P.S.d1Wih = d_in[24];
    P.S.b0 = d_in[5];  P.S.b1 = d_in[6];  P.S.b2 = d_in[9];  P.S.b3 = d_in[10];
    P.S.b4 = d_in[22]; P.S.b5 = d_in[23]; P.S.b6 = d_in[26]; P.S.b7 = d_in[27];
    P.S.encW = d_in[11]; P.S.qW = d_in[13]; P.S.predW = d_in[28]; P.S.emb = d_in[19];
    P.S.encb = d_in[12]; P.S.qb = d_in[14]; P.S.kb = d_in[16]; P.S.sW = d_in[17];
    P.S.sb = d_in[18]; P.S.predb = d_in[29];
    P.feat_raw = feat_r; P.vr_src = vr_r; P.kW_src = d_in[15];
    P.wq_s0 = d_in[4]; P.wq_s1 = d_in[8]; P.wq_s2 = d_in[21]; P.wq_s3 = d_in[25];
    P.flag = flag; P.hEx = hEx; P.canon = canon; P.cvr = cvr;
    P.W2 = W2;
    P.wq_d0 = Wq[0]; P.wq_d1 = Wq[1]; P.wq_d2 = Wq[2]; P.wq_d3 = Wq[3];
    P.featv = featv; P.featP = featP;
    prep_all<<<dim3(PB_TOTAL), 256, 0, stream>>>(P);

    // ---- encoder ----
    gemm_nt_128<<<dim3(16, 10), 512, 65536, stream>>>(featv, cW0, cb0 + 0 * 2048, cb0 + 1 * 2048, xpre, 1280, 2048);
    lstm_sync<<<dim3(256), 512, 0, stream>>>(xpre, Wq[0], seq0, nullptr, hEx0, 40, 0);
    gemm_nt_128<<<dim3(16, 10), 512, 65536, stream>>>(seq0, cW1, cb0 + 2 * 2048, cb0 + 3 * 2048, xpre, 1280, 2048);
    lstm_sync<<<dim3(256), 512, 0, stream>>>(xpre, Wq[1], seq1, nullptr, hEx1, 40, 0);
    gemm_nt_f32<<<dim3(8, 1), 256, 0, stream>>>(seq1 + 39 * 512, 40 * 512, cencW, cencb, nullptr, holf, 32, 512, 512, 512);

    // ---- decoder ----
    tok_k<<<dim3(1728), 256, 0, stream>>>(holf, cemb, label, tok);
    gemm_nt_128<<<dim3(16, 7), 512, 65536, stream>>>(tok, cW2, cb0 + 4 * 2048, cb0 + 5 * 2048, xpre, 864, 2048);
    lstm_sync<<<dim3(256), 512, 0, stream>>>(xpre, Wq[2], seqd0, nullptr, hEx2, 27, 0);
    gemm_nt_128<<<dim3(16, 7), 512, 65536, stream>>>(seqd0, cW3, cb0 + 6 * 2048, cb0 + 7 * 2048, xpre, 864, 2048);
    lstm_sync<<<dim3(256), 512, 0, stream>>>(xpre, Wq[3], Hid, concat, hEx3, 27, 1536);

    // ---- attention: qf GEMM co-dispatched with conv (xpre dead; kmap aliases it) ----
    qf_conv<<<dim3(284), 512, 65536, stream>>>(Hid, cqW, cqb, qf, featP, W2, ckb, kmap);
    score_k<<<dim3(864), 256, 0, stream>>>(qf, kmap, csW, csb, cvr, aw);
    attn_k<<<dim3(256), 256, 0, stream>>>(feat_r, aw, concat, flag);

    // ---- prediction ----
    pred_k<<<dim3(216), 256, 0, stream>>>(concat, holf, cpredW, cpredb, d_out, flag);
}

// Round 14
// 724.744 us; speedup vs baseline: 1.2161x; 1.0114x over previous
//
#include <hip/hip_runtime.h>

typedef unsigned short u16;
typedef __attribute__((ext_vector_type(8))) short short8;
typedef __attribute__((ext_vector_type(4))) float floatx4;
typedef _Float16 half8 __attribute__((ext_vector_type(8)));
typedef _Float16 half2v __attribute__((ext_vector_type(2)));
typedef unsigned uint4v __attribute__((ext_vector_type(4)));

#define AGENT __HIP_MEMORY_SCOPE_AGENT
#define SENT 0x7FFF7FFFu   // f16 NaN pair — unreachable: h = sigm*tanh in (-1,1)

// ---------- helpers ----------
__device__ __forceinline__ float bf2f(u16 v) { return __uint_as_float(((unsigned)v) << 16); }
__device__ __forceinline__ u16 f2bf(float f) {
    unsigned u = __float_as_uint(f);
    unsigned r = (u + 0x7FFFu + ((u >> 16) & 1u)) >> 16;
    return (u16)r;
}
// fast transcendentals: native v_exp + raw v_rcp (no precise-div sequence)
__device__ __forceinline__ float sigm_(float x) {
    return __builtin_amdgcn_rcpf(1.f + __expf(-x));
}
__device__ __forceinline__ float tanh_(float x) {
    x = fminf(fmaxf(x, -15.f), 15.f);
    float e = __expf(2.f * x);
    return (e - 1.f) * __builtin_amdgcn_rcpf(e + 1.f);
}

// async global->LDS, 16B per lane; LDS dest is wave-uniform base + lane*16
typedef __attribute__((address_space(1))) void gvoid_t;
typedef __attribute__((address_space(3))) void lvoid_t;
__device__ __forceinline__ void gl_lds16(const void* g, void* l) {
    __builtin_amdgcn_global_load_lds((gvoid_t*)g, (lvoid_t*)l, 16, 0, 0);
}

// B=32, C=512, H=6, W=40, NC=97, L=26, T=27
#define HEX_WORDS (134 * 32 * 256)

// ---------- offsets ----------
struct SrcPtrs {
    const void* e0Wih; const void* e1Wih; const void* d0Wih; const void* d1Wih;
    const void* b0; const void* b1; const void* b2; const void* b3;
    const void* b4; const void* b5; const void* b6; const void* b7;
    const void* encW; const void* qW; const void* predW; const void* emb;
    const void* encb; const void* qb; const void* kb; const void* sW;
    const void* sb; const void* predb;
};
#define OFF_W0      0
#define OFF_W1      1048576
#define OFF_W2      2097152
#define OFF_W3      3145728
#define OFF_B       4194304
#define OFF_ENCW    4210688
#define OFF_QW      4472832
#define OFF_PREDW   4734976
#define OFF_EMB     4883968
#define OFF_ENCB    4933632
#define OFF_QB      4934144
#define OFF_KB      4934656
#define OFF_SW      4935168
#define OFF_SB      4935680
#define OFF_PREDB   4935681
#define CANON_TOTAL 4935778

// ---------- dtype sniff (32 loads of ONE 64B line; L2-broadcast ~free) ----------
__device__ __forceinline__ int sniff_(const void* feat_raw) {
    const u16* p = (const u16*)feat_raw;
    int insane = 0;
    #pragma unroll
    for (int i = 0; i < 32; i += 2) {
        float x = bf2f(p[i]);
        float a = fabsf(x);
        if (!(a <= 1000.f)) insane = 1;
        if (x != 0.f && a < 1e-8f) insane = 1;
    }
    return insane;
}

// ---------- v16: fused prep ----------
// v15 post-mortem: prep 95 µs, FETCH still 107-126 MB vs ~45 MB unique input. The
// canon section below OFF_PREDW (Wih x4 + encW + qW, 9.5 MB) is a PURE COPY — when
// the input is already bf16 (fl==0) the consumers can read raw pointers directly.
// v16: canon early-outs that range when fl==0; the consumer GEMMs take
// (canonPtr, rawPtr, flag) and select at runtime (uniform scalar branch).
// Biases/emb/sW/kb/predW (>= OFF_PREDW) are still always canonized.
struct PrepArgs {
    SrcPtrs S;
    const void* feat_raw;
    const void* vr_src;
    const void* kW_src;
    const void* wq_s0; const void* wq_s1; const void* wq_s2; const void* wq_s3;
    int* flag;
    unsigned* hEx;
    u16* canon;
    float* cvr;
    u16* W2;
    _Float16* wq_d0; _Float16* wq_d1; _Float16* wq_d2; _Float16* wq_d3;
    u16* featv;
    u16* featP;
};

// block ranges
#define PB_INIT    0        // 4288 blocks  : hEx sentinel fill (+flag from idx 0)
#define PB_CANON   4288     // 19281 blocks : canon_all
#define PB_CANONF  23569    // 1 block      : cvr (32 floats)
#define PB_W2      23570    // 9216 blocks  : conv weight reshuffle
#define PB_WQ3     32786    // 2048 blocks  : 4x Whh -> f16 dot layout
#define PB_FEATP   34834    // 512 blocks   : LDS-tiled feat transpose, 32 ch/block
#define PB_TOTAL   35346

__global__ __launch_bounds__(256) void prep_all(PrepArgs P)
{
    const int blk = blockIdx.x;
    const int tid = threadIdx.x;

    if (blk < PB_CANON) {                       // ---- init: sentinel fill ----
        int idx = blk * 256 + tid;
        P.hEx[idx] = SENT;
        if (idx == 0) *P.flag = sniff_(P.feat_raw);
        return;
    }
    const int fl = sniff_(P.feat_raw);          // per-block local dtype flag

    if (blk < PB_CANONF) {                      // ---- canon_all ----
        int idx = (blk - PB_CANON) * 256 + tid;
        if (idx >= CANON_TOTAL) return;
        if (!fl && idx < OFF_PREDW) return;     // bf16 input: big-weight copies skipped
        const SrcPtrs& S = P.S;
        const void* s; int loc;
        if (idx < OFF_B) {
            int k = idx >> 20; loc = idx & 1048575;
            s = (k == 0) ? S.e0Wih : (k == 1) ? S.e1Wih : (k == 2) ? S.d0Wih : S.d1Wih;
        } else if (idx < OFF_ENCW) {
            int r = idx - OFF_B; int k = r >> 11; loc = r & 2047;
            s = (k == 0) ? S.b0 : (k == 1) ? S.b1 : (k == 2) ? S.b2 : (k == 3) ? S.b3
              : (k == 4) ? S.b4 : (k == 5) ? S.b5 : (k == 6) ? S.b6 : S.b7;
        } else if (idx < OFF_QW)    { s = S.encW;  loc = idx - OFF_ENCW; }
        else if (idx < OFF_PREDW)   { s = S.qW;    loc = idx - OFF_QW; }
        else if (idx < OFF_EMB)     { s = S.predW; loc = idx - OFF_PREDW; }
        else if (idx < OFF_ENCB)    { s = S.emb;   loc = idx - OFF_EMB; }
        else if (idx < OFF_QB)      { s = S.encb;  loc = idx - OFF_ENCB; }
        else if (idx < OFF_KB)      { s = S.qb;    loc = idx - OFF_QB; }
        else if (idx < OFF_SW)      { s = S.kb;    loc = idx - OFF_KB; }
        else if (idx < OFF_SB)      { s = S.sW;    loc = idx - OFF_SW; }
        else if (idx < OFF_PREDB)   { s = S.sb;    loc = idx - OFF_SB; }
        else                        { s = S.predb; loc = idx - OFF_PREDB; }
        P.canon[idx] = fl ? f2bf(((const float*)s)[loc]) : ((const u16*)s)[loc];
    } else if (blk == PB_CANONF) {              // ---- canonf (valid_ratios) ----
        if (tid < 32)
            P.cvr[tid] = fl ? ((const float*)P.vr_src)[tid] : bf2f(((const u16*)P.vr_src)[tid]);
    } else if (blk < PB_WQ3) {                  // ---- w2 ----
        int idx = (blk - PB_W2) * 256 + tid;
        int co = idx / 4608;
        int r = idx % 4608;
        int kh = r / 1536;
        int r2 = r % 1536;
        int kw = r2 / 512;
        int ci = r2 & 511;
        long si = ((long)(co * 512 + ci) * 3 + kh) * 3 + kw;
        P.W2[idx] = fl ? f2bf(((const float*)P.kW_src)[si]) : ((const u16*)P.kW_src)[si];
    } else if (blk < PB_FEATP) {                // ---- wq3_all ----
        int gb = blk - PB_WQ3;
        int id = gb >> 9;
        const void* W = (id == 0) ? P.wq_s0 : (id == 1) ? P.wq_s1 : (id == 2) ? P.wq_s2 : P.wq_s3;
        _Float16* D = (id == 0) ? P.wq_d0 : (id == 1) ? P.wq_d1 : (id == 2) ? P.wq_d2 : P.wq_d3;
        int o = (gb & 511) * 256 + tid;
        int t = o & 511;
        int c = (o >> 9) & 31;
        int j = o >> 14;
        int rid = t >> 1, hf = t & 1;
        int n = (rid >> 6) * 512 + j * 64 + (rid & 63);
        int k = hf * 256 + c * 8;
        _Float16* dst = D + (long)o * 8;
        #pragma unroll
        for (int jj = 0; jj < 8; jj++) {
            long si = (long)n * 512 + k + jj;
            float v = fl ? ((const float*)W)[si] : bf2f(((const u16*)W)[si]);
            dst[jj] = (_Float16)v;
        }
    } else {                                    // ---- featp: LDS-tiled transpose (32 ch) ----
        __shared__ u16 S[32][242];
        int q = blk - PB_FEATP;
        int b = q >> 4;
        int c0 = (q & 15) * 32;
        long gbase = ((long)b * 512 + c0) * 240;
        for (int i = tid; i < 32 * 240; i += 256) {
            float x = fl ? ((const float*)P.feat_raw)[gbase + i] : bf2f(((const u16*)P.feat_raw)[gbase + i]);
            S[i / 240][i % 240] = f2bf(x);
        }
        __syncthreads();
        for (int i = tid; i < 40 * 32; i += 256) {
            int w = i >> 5, c = i & 31;
            float mx = bf2f(S[c][w]);
            #pragma unroll
            for (int h = 1; h < 6; h++) mx = fmaxf(mx, bf2f(S[c][h * 40 + w]));
            P.featv[((long)(b * 40 + w)) * 512 + c0 + c] = f2bf(mx);
        }
        for (int i = tid; i < 6 * 40 * 32; i += 256) {
            int c = i & 31; int r = i >> 5;
            int wp1 = r % 40, hp1 = r / 40;
            P.featP[((long)(b * 8 + hp1 + 1) * 42 + (wp1 + 1)) * 512 + c0 + c] = S[c][hp1 * 40 + wp1];
        }
        for (int i = tid; i < 96 * 32; i += 256) {
            int c = i & 31; int r = i >> 5;
            int hp, wp;
            if (r < 42)      { hp = 0; wp = r; }
            else if (r < 84) { hp = 7; wp = r - 42; }
            else             { int q2 = r - 84; hp = 1 + (q2 >> 1); wp = (q2 & 1) * 41; }
            P.featP[((long)(b * 8 + hp) * 42 + wp) * 512 + c0 + c] = 0;
        }
    }
}

// ---------- 128x128 tile bodies (dynamic LDS; dual-pointer B select) ----------
// Layout: As = lds[0 .. 4*128*32), Bs = lds[4*128*32 .. 8*128*32)  (64 KB total)
__device__ __forceinline__ void gemm128_body(
    u16* lds, const u16* __restrict__ A,
    const u16* __restrict__ Bcanon, const u16* __restrict__ Braw, const int* __restrict__ flag,
    const u16* __restrict__ bias0, const u16* __restrict__ bias1,
    float* __restrict__ C, int M, int ldc, int bn, int bm)
{
    const u16* Bw = (*flag) ? Bcanon : Braw;    // fl==0: raw IS bf16 row-major
    u16 (*As)[128][32] = (u16(*)[128][32])lds;
    u16 (*Bs)[128][32] = (u16(*)[128][32])(lds + 4 * 128 * 32);
    const int tid = threadIdx.x;
    const int wv = tid >> 6, l = tid & 63;
    const int wm = wv >> 2, wn = wv & 3;
    const int l15 = l & 15, lq = l >> 4;
    const int ch = ((l & 3) ^ ((l >> 3) & 3)) * 8;

    int ar = bm * 128 + wv * 16 + (l >> 2);
    if (ar > M - 1) ar = M - 1;
    const u16* ga = A + (long)ar * 512 + ch;
    const u16* gb = Bw + (long)(bn * 128 + wv * 16 + (l >> 2)) * 512 + ch;

    floatx4 acc[4][2];
    #pragma unroll
    for (int i = 0; i < 4; i++)
        #pragma unroll
        for (int j = 0; j < 2; j++) acc[i][j] = (floatx4)(0.f);

    auto stage = [&](int k0, int pb) {
        gl_lds16(ga + k0, &As[pb][wv * 16][0]);
        gl_lds16(gb + k0, &Bs[pb][wv * 16][0]);
    };
    const int rs = (lq ^ ((l15 >> 1) & 3)) * 8;
    auto compute = [&](int cur) {
        short8 af[4], bf[2];
        #pragma unroll
        for (int i = 0; i < 4; i++) af[i] = *(const short8*)&As[cur][wm * 64 + i * 16 + l15][rs];
        #pragma unroll
        for (int j = 0; j < 2; j++) bf[j] = *(const short8*)&Bs[cur][wn * 32 + j * 16 + l15][rs];
        #pragma unroll
        for (int i = 0; i < 4; i++)
            #pragma unroll
            for (int j = 0; j < 2; j++)
                acc[i][j] = __builtin_amdgcn_mfma_f32_16x16x32_bf16(af[i], bf[j], acc[i][j], 0, 0, 0);
    };

    stage(0, 0); stage(32, 1); stage(64, 2);
    for (int k = 0; k < 14; k++) {
        asm volatile("s_waitcnt vmcnt(4)" ::: "memory");
        __builtin_amdgcn_s_barrier();
        asm volatile("" ::: "memory");
        if (k < 13) stage((k + 3) * 32, (k + 3) & 3);
        compute(k & 3);
    }
    asm volatile("s_waitcnt vmcnt(2)" ::: "memory");
    __builtin_amdgcn_s_barrier();
    asm volatile("" ::: "memory");
    compute(2);
    asm volatile("s_waitcnt vmcnt(0)" ::: "memory");
    __builtin_amdgcn_s_barrier();
    asm volatile("" ::: "memory");
    compute(3);

    #pragma unroll
    for (int i = 0; i < 4; i++)
        #pragma unroll
        for (int j = 0; j < 2; j++)
            #pragma unroll
            for (int r = 0; r < 4; r++) {
                int gm = bm * 128 + wm * 64 + i * 16 + lq * 4 + r;
                int gn = bn * 128 + wn * 32 + j * 16 + l15;
                if (gm < M) {
                    float v = acc[i][j][r];
                    if (bias0) v += bf2f(bias0[gn]);
                    if (bias1) v += bf2f(bias1[gn]);
                    C[(long)gm * ldc + gn] = v;
                }
            }
}

__device__ __forceinline__ void conv_body(
    u16* lds, const u16* __restrict__ featP, const u16* __restrict__ W2,
    const u16* __restrict__ kb, u16* __restrict__ kmap, int bx, int by)
{
    u16 (*As)[128][32] = (u16(*)[128][32])lds;
    u16 (*Bs)[128][32] = (u16(*)[128][32])(lds + 4 * 128 * 32);
    const int tid = threadIdx.x;
    int bm = bx * 8 + (by & 7);
    int bn = by >> 3;
    if (bm >= 60) return;
    const int wv = tid >> 6, l = tid & 63;
    const int wm = wv >> 2, wn = wv & 3;
    const int l15 = l & 15, lq = l >> 4;
    const int ch = ((l & 3) ^ ((l >> 3) & 3)) * 8;

    int ar = bm * 128 + wv * 16 + (l >> 2);
    int ab = ar / 240, ahw = ar % 240;
    const u16* ga = featP + ((long)(ab * 8 + ahw / 40) * 42 + (ahw % 40)) * 512 + ch;
    const u16* gb = W2 + (long)(bn * 128 + wv * 16 + (l >> 2)) * 4608 + ch;

    floatx4 acc[4][2];
    #pragma unroll
    for (int i = 0; i < 4; i++)
        #pragma unroll
        for (int j = 0; j < 2; j++) acc[i][j] = (floatx4)(0.f);

    auto stage = [&](int k0, int pb) {
        int kh = k0 / 1536;
        int rem = k0 - kh * 1536;
        int aoff = (kh * 42 + (rem >> 9)) * 512 + (rem & 511);
        gl_lds16(ga + aoff, &As[pb][wv * 16][0]);
        gl_lds16(gb + k0, &Bs[pb][wv * 16][0]);
    };
    const int rs = (lq ^ ((l15 >> 1) & 3)) * 8;
    auto compute = [&](int cur) {
        short8 af[4], bf[2];
        #pragma unroll
        for (int i = 0; i < 4; i++) af[i] = *(const short8*)&As[cur][wm * 64 + i * 16 + l15][rs];
        #pragma unroll
        for (int j = 0; j < 2; j++) bf[j] = *(const short8*)&Bs[cur][wn * 32 + j * 16 + l15][rs];
        #pragma unroll
        for (int i = 0; i < 4; i++)
            #pragma unroll
            for (int j = 0; j < 2; j++)
                acc[i][j] = __builtin_amdgcn_mfma_f32_16x16x32_bf16(af[i], bf[j], acc[i][j], 0, 0, 0);
    };

    stage(0, 0); stage(32, 1); stage(64, 2);
    for (int k = 0; k < 142; k++) {
        asm volatile("s_waitcnt vmcnt(4)" ::: "memory");
        __builtin_amdgcn_s_barrier();
        asm volatile("" ::: "memory");
        if (k < 141) stage((k + 3) * 32, (k + 3) & 3);
        compute(k & 3);
    }
    asm volatile("s_waitcnt vmcnt(2)" ::: "memory");
    __builtin_amdgcn_s_barrier();
    asm volatile("" ::: "memory");
    compute(2);
    asm volatile("s_waitcnt vmcnt(0)" ::: "memory");
    __builtin_amdgcn_s_barrier();
    asm volatile("" ::: "memory");
    compute(3);

    #pragma unroll
    for (int i = 0; i < 4; i++)
        #pragma unroll
        for (int j = 0; j < 2; j++)
            #pragma unroll
            for (int r = 0; r < 4; r++) {
                int row = bm * 128 + wm * 64 + i * 16 + lq * 4 + r;
                int col = bn * 128 + wn * 32 + j * 16 + l15;
                kmap[(long)row * 512 + col] = f2bf(acc[i][j][r] + bf2f(kb[col]));
            }
}

__global__ __launch_bounds__(512) void gemm_nt_128(
    const u16* __restrict__ A,
    const u16* __restrict__ Bcanon, const u16* __restrict__ Braw,
    const u16* __restrict__ bias0, const u16* __restrict__ bias1,
    float* __restrict__ C, int M, int ldc, const int* __restrict__ flag)
{
    extern __shared__ u16 ldsb[];
    gemm128_body(ldsb, A, Bcanon, Braw, flag, bias0, bias1, C, M, ldc, blockIdx.x, blockIdx.y);
}

// ---------- qf GEMM co-dispatched with conv (proven v14; dual-pointer qW) ----------
__global__ __launch_bounds__(512) void qf_conv(
    const u16* __restrict__ Hid, const u16* __restrict__ qWc, const u16* __restrict__ qWr,
    const u16* __restrict__ qb, float* __restrict__ qf,
    const u16* __restrict__ featP, const u16* __restrict__ W2,
    const u16* __restrict__ kb, u16* __restrict__ kmap, const int* __restrict__ flag)
{
    extern __shared__ u16 ldsb[];
    int q = blockIdx.x;
    if (q < 28) {
        gemm128_body(ldsb, Hid, qWc, qWr, flag, qb, nullptr, qf, 864, 512, q & 3, q >> 2);
    } else {
        int c = q - 28;
        conv_body(ldsb, featP, W2, kb, kmap, c & 7, c >> 3);
    }
}

// ---------- v16: encW GEMM (8 blocks) fused with token build ----------
// GEMM blocks write holf AND the t=0 token rows (removes holf->tok RAW hazard);
// tok blocks handle t>0 (pure emb gather, no holf dependency). -1 dispatch.
__global__ __launch_bounds__(256) void enc_tok(
    const u16* __restrict__ A, int lda,
    const u16* __restrict__ Bcanon, const u16* __restrict__ Braw,
    const u16* __restrict__ bias0,
    float* __restrict__ holf, u16* __restrict__ tok,
    const u16* __restrict__ cemb, const int* __restrict__ label,
    const int* __restrict__ flag)
{
    if (blockIdx.x < 8) {
        const u16* Bw = (*flag) ? Bcanon : Braw;
        __shared__ __align__(16) u16 As[64][40];
        __shared__ __align__(16) u16 Bs[64][40];
        const int tid = threadIdx.x;
        const int bn = blockIdx.x;
        const int l = tid & 63, wid = tid >> 6;
        const int wm = wid >> 1, wn = wid & 1;
        const int lr = tid >> 2, lc = (tid & 3) * 8;
        const int l15 = l & 15, lq = l >> 4;

        floatx4 acc00 = (floatx4)(0.f), acc01 = (floatx4)(0.f), acc10 = (floatx4)(0.f), acc11 = (floatx4)(0.f);

        int am = lr; if (am > 31) am = 31;    // M = 32
        const u16* Ap = A + (long)am * lda + lc;
        const u16* Bp = Bw + (long)(bn * 64 + lr) * 512 + lc;

        for (int k0 = 0; k0 < 512; k0 += 32) {
            *(short8*)&As[lr][lc] = *(const short8*)(Ap + k0);
            *(short8*)&Bs[lr][lc] = *(const short8*)(Bp + k0);
            __syncthreads();
            short8 af0 = *(const short8*)&As[wm * 32 + l15][lq * 8];
            short8 af1 = *(const short8*)&As[wm * 32 + 16 + l15][lq * 8];
            short8 bf0 = *(const short8*)&Bs[wn * 32 + l15][lq * 8];
            short8 bf1 = *(const short8*)&Bs[wn * 32 + 16 + l15][lq * 8];
            acc00 = __builtin_amdgcn_mfma_f32_16x16x32_bf16(af0, bf0, acc00, 0, 0, 0);
            acc01 = __builtin_amdgcn_mfma_f32_16x16x32_bf16(af0, bf1, acc01, 0, 0, 0);
            acc10 = __builtin_amdgcn_mfma_f32_16x16x32_bf16(af1, bf0, acc10, 0, 0, 0);
            acc11 = __builtin_amdgcn_mfma_f32_16x16x32_bf16(af1, bf1, acc11, 0, 0, 0);
            __syncthreads();
        }
        floatx4 accs[2][2] = {{acc00, acc01}, {acc10, acc11}};
        #pragma unroll
        for (int i = 0; i < 2; i++)
            #pragma unroll
            for (int j = 0; j < 2; j++)
                #pragma unroll
                for (int r = 0; r < 4; r++) {
                    int gm = wm * 32 + i * 16 + lq * 4 + r;
                    int gn = bn * 64 + wn * 32 + j * 16 + l15;
                    if (gm < 32) {
                        float v = accs[i][j][r] + bf2f(bias0[gn]);
                        holf[(long)gm * 512 + gn] = v;
                        tok[(long)gm * 27 * 512 + gn] = f2bf(v);   // t = 0 token row
                    }
                }
    } else {
        int idx = (blockIdx.x - 8) * 256 + threadIdx.x;   // < 32*26*512
        int c = idx & 511;
        int m2 = idx >> 9;
        int b = m2 / 26, t = m2 % 26 + 1;
        tok[((long)(b * 27 + t)) * 512 + c] = cemb[(long)label[b * 26 + (t - 1)] * 512 + c];
    }
}

// ---------- LSTM recurrence v4 (proven): sentinel self-announcing exchange. DO NOT TOUCH. ----------
#define WL(F) F(0) F(1) F(2) F(3) F(4) F(5) F(6) F(7) F(8) F(9) F(10) F(11) F(12) F(13) F(14) F(15) \
              F(16) F(17) F(18) F(19) F(20) F(21) F(22) F(23) F(24) F(25) F(26) F(27) F(28) F(29) F(30) F(31)
#define WLA(F) F(0,0) F(1,1) F(2,2) F(3,3) F(4,0) F(5,1) F(6,2) F(7,3) \
               F(8,0) F(9,1) F(10,2) F(11,3) F(12,0) F(13,1) F(14,2) F(15,3) \
               F(16,0) F(17,1) F(18,2) F(19,3) F(20,0) F(21,1) F(22,2) F(23,3) \
               F(24,0) F(25,1) F(26,2) F(27,3) F(28,0) F(29,1) F(30,2) F(31,3)
#define WDECL(i) half8 w##i = wp8[(long)(j * 32 + i) * 512 + tid];
#define WPIN(i)  asm volatile("" : "+v"(w##i));
#define DOTC(i,k) { \
    half8 hv = *(const half8*)&hS2[(hf * 2 + (i / 16)) * 136 + (i % 16) * 8]; \
    a##k = __builtin_amdgcn_fdot2(__builtin_shufflevector(hv, hv, 0, 1), __builtin_shufflevector(w##i, w##i, 0, 1), a##k, false); \
    a##k = __builtin_amdgcn_fdot2(__builtin_shufflevector(hv, hv, 2, 3), __builtin_shufflevector(w##i, w##i, 2, 3), a##k, false); \
    a##k = __builtin_amdgcn_fdot2(__builtin_shufflevector(hv, hv, 4, 5), __builtin_shufflevector(w##i, w##i, 4, 5), a##k, false); \
    a##k = __builtin_amdgcn_fdot2(__builtin_shufflevector(hv, hv, 6, 7), __builtin_shufflevector(w##i, w##i, 6, 7), a##k, false); }

__global__ __launch_bounds__(512) __attribute__((amdgpu_waves_per_eu(2, 2))) void lstm_sync(
    const float* __restrict__ xpre, const _Float16* __restrict__ Wq3,
    u16* __restrict__ seq_out, float* __restrict__ f32_out,
    unsigned* __restrict__ hExT, int T, int f32_ld)
{
    const int i_ = blockIdx.x;
    const int slot = i_ >> 3;
    const int b = (i_ & 7) * 4 + (slot & 3);
    const int j = slot >> 2;
    const int tid = threadIdx.x;
    const int hf = tid & 1;

    __shared__ __align__(16) _Float16 hS2[4 * 136];
    __shared__ float part[512];

    const half8* wp8 = (const half8*)Wq3;
    WL(WDECL)
    WL(WPIN)
    float cst = 0.f;

    for (int t = 0; t < T; t++) {
        float xi = 0.f, xf = 0.f, xg = 0.f, xo = 0.f;
        if (tid < 64) {
            const float* xp = xpre + ((long)b * T + t) * 2048 + j * 64 + tid;
            xi = xp[0]; xf = xp[512]; xg = xp[1024]; xo = xp[1536];
        }
        float a0 = 0.f, a1 = 0.f, a2 = 0.f, a3 = 0.f;
        if (t > 0) {
            if (tid < 64) {
                const unsigned* src = &hExT[((long)(t - 1) * 32 + b) * 256 + tid * 4];
                unsigned v0, v1, v2, v3;
                do {
                    v0 = __hip_atomic_load(src + 0, __ATOMIC_RELAXED, AGENT);
                    v1 = __hip_atomic_load(src + 1, __ATOMIC_RELAXED, AGENT);
                    v2 = __hip_atomic_load(src + 2, __ATOMIC_RELAXED, AGENT);
                    v3 = __hip_atomic_load(src + 3, __ATOMIC_RELAXED, AGENT);
                } while (v0 == SENT || v1 == SENT || v2 == SENT || v3 == SENT);
                uint4v v; v.x = v0; v.y = v1; v.z = v2; v.w = v3;
                *(uint4v*)&hS2[(tid >> 4) * 136 + (tid & 15) * 8] = v;
            }
            __syncthreads();
            WLA(DOTC)
        }
        part[tid] = (a0 + a1) + (a2 + a3);
        __syncthreads();
        if (tid < 64) {
            float gi = xi + part[(0   + tid) * 2] + part[(0   + tid) * 2 + 1];
            float gf = xf + part[(64  + tid) * 2] + part[(64  + tid) * 2 + 1];
            float gg = xg + part[(128 + tid) * 2] + part[(128 + tid) * 2 + 1];
            float go = xo + part[(192 + tid) * 2] + part[(192 + tid) * 2 + 1];
            cst = sigm_(gf) * cst + sigm_(gi) * tanh_(gg);
            float h = sigm_(go) * tanh_(cst);
            float hlo = __shfl(h, tid * 2);
            float hhi = __shfl(h, tid * 2 + 1);
            if (t + 1 < T && tid < 32) {
                half2v hp; hp[0] = (_Float16)hlo; hp[1] = (_Float16)hhi;
                __hip_atomic_store(&hExT[((long)t * 32 + b) * 256 + j * 32 + tid],
                                   *(unsigned*)&hp, __ATOMIC_RELAXED, AGENT);
            }
            asm volatile("" ::: "memory");
            long so = ((long)b * T + t) * 512 + j * 64 + tid;
            seq_out[so] = f2bf(h);
            if (f32_out) f32_out[((long)b * T + t) * f32_ld + j * 64 + tid] = h;
        }
    }
}

// ---------- fused score v2 (r9-verified) ----------
__global__ __launch_bounds__(256) void score_k(
    const float* __restrict__ q, const u16* __restrict__ kmap,
    const u16* __restrict__ sW, const u16* __restrict__ sb,
    const float* __restrict__ vr, float* __restrict__ aw)
{
    int blk = blockIdx.x;
    int xcd = blk & 7, rest = blk >> 3;
    int bq = rest & 3, t = rest >> 2;
    int b = xcd * 4 + bq;
    int bt = b * 27 + t;
    int tid = threadIdx.x, wv = tid >> 6, ln = tid & 63;

    __shared__ float sc[240];
    __shared__ float red[256];

    float qr[8], sr[8];
    const float* qp = q + (long)bt * 512 + ln * 8;
    #pragma unroll
    for (int i = 0; i < 8; i++) qr[i] = qp[i];
    #pragma unroll
    for (int i = 0; i < 8; i++) sr[i] = bf2f(sW[ln * 8 + i]);

    const u16* kb_ = kmap + (long)b * 240 * 512;
    for (int r = wv * 60; r < wv * 60 + 60; r++) {
        short8 kv = *(const short8*)(kb_ + (long)r * 512 + ln * 8);
        float acc = 0.f;
        #pragma unroll
        for (int i = 0; i < 8; i++) {
            float x = bf2f((u16)kv[i]) + qr[i];
            acc = fmaf(sr[i], tanh_(x), acc);
        }
        #pragma unroll
        for (int m = 32; m > 0; m >>= 1) acc += __shfl_xor(acc, m);
        if (ln == 0) sc[r] = acc;
    }
    __syncthreads();

    float scv = -INFINITY, ex = 0.f;
    if (tid < 240) {
        float rr = vr[b];
        int vw = (int)ceilf(40.f * rr);
        if (vw > 40) vw = 40;
        int wcol = tid % 40;
        scv = (wcol >= vw) ? -INFINITY : (sc[tid] + bf2f(sb[0]));
    }
    red[tid] = scv;
    __syncthreads();
    for (int s = 128; s > 0; s >>= 1) {
        if (tid < s) red[tid] = fmaxf(red[tid], red[tid + s]);
        __syncthreads();
    }
    float mx = red[0];
    __syncthreads();
    if (tid < 240) ex = (scv == -INFINITY) ? 0.f : __expf(scv - mx);
    red[tid] = ex;
    __syncthreads();
    for (int s = 128; s > 0; s >>= 1) {
        if (tid < s) red[tid] += red[tid + s];
        __syncthreads();
    }
    float inv = __builtin_amdgcn_rcpf(red[0]);
    if (tid < 240) aw[(long)bt * 240 + tid] = ex * inv;
}

// ---------- attn_feat -> concat cols [512,1024) ----------
__global__ __launch_bounds__(256) void attn_k(
    const void* __restrict__ feat, const float* __restrict__ aw,
    float* __restrict__ concat, const int* __restrict__ flag)
{
    const int fl = *flag;
    int b = blockIdx.x >> 3;
    int cc = (blockIdx.x & 7) * 64;
    int tid = threadIdx.x;
    __shared__ float awS[27 * 240];
    __shared__ u16 fS[64 * 240];
    for (int i = tid; i < 27 * 240; i += 256) awS[i] = aw[(long)b * 27 * 240 + i];
    long fbase = ((long)b * 512 + cc) * 240;
    for (int i = tid; i < 64 * 240; i += 256)
        fS[i] = fl ? f2bf(((const float*)feat)[fbase + i]) : ((const u16*)feat)[fbase + i];
    __syncthreads();
    for (int item = tid; item < 64 * 27; item += 256) {
        int c = item / 27, t = item % 27;
        const u16* fp = &fS[c * 240];
        const float* ap = &awS[t * 240];
        float acc = 0.f;
        for (int hw = 0; hw < 240; hw++) acc = fmaf(bf2f(fp[hw]), ap[hw], acc);
        concat[((long)(b * 27 + t)) * 1536 + 512 + cc + c] = acc;
    }
}

// ---------- prediction + slice (short8 weight stream) ----------
__global__ __launch_bounds__(256) void pred_k(
    const float* __restrict__ concat, const float* __restrict__ holf,
    const u16* __restrict__ pW, const u16* __restrict__ pb,
    void* __restrict__ out, const int* __restrict__ flag)
{
    int m0 = blockIdx.x * 4;
    int tid = threadIdx.x;
    const int fl = *flag;
    __shared__ float aS[4][1024];
    __shared__ float hS[4][512];
    for (int i = tid; i < 4 * 1024; i += 256)
        aS[i / 1024][i % 1024] = concat[(long)(m0 + i / 1024) * 1536 + (i % 1024)];
    for (int i = tid; i < 4 * 512; i += 256) {
        int m = m0 + i / 512;
        hS[i / 512][i % 512] = holf[(long)(m / 27) * 512 + (i % 512)];
    }
    __syncthreads();
    int r = tid >> 6;
    int nb = tid & 63;
    int m = m0 + r;
    int b = m / 27, t = m % 27;
    for (int n = nb; n < 97; n += 64) {
        const u16* wp = pW + (long)n * 1536;     // 16B-aligned (OFF_PREDW*2 and 3072B rows)
        float acc = 0.f;
        for (int k0 = 0; k0 < 1024; k0 += 8) {
            short8 wv8 = *(const short8*)(wp + k0);
            #pragma unroll
            for (int q = 0; q < 8; q++) acc = fmaf(aS[r][k0 + q], bf2f((u16)wv8[q]), acc);
        }
        for (int k0 = 0; k0 < 512; k0 += 8) {
            short8 wv8 = *(const short8*)(wp + 1024 + k0);
            #pragma unroll
            for (int q = 0; q < 8; q++) acc = fmaf(hS[r][k0 + q], bf2f((u16)wv8[q]), acc);
        }
        acc += bf2f(pb[n]);
        if (t > 0) {
            long o = ((long)(b * 26 + (t - 1))) * 97 + n;
            if (fl) ((float*)out)[o] = acc;
            else    ((u16*)out)[o] = f2bf(acc);
        }
    }
}

// ---------- launch ----------
extern "C" void kernel_launch(void* const* d_in, const int* in_sizes, int n_in,
                              void* d_out, int out_size, void* d_ws, size_t ws_size,
                              hipStream_t stream) {
    (void)in_sizes; (void)n_in; (void)out_size; (void)ws_size;
    const void* feat_r = d_in[0];
    const int*  label  = (const int*)d_in[1];
    const void* vr_r   = d_in[2];

    char* w = (char*)d_ws;
    size_t off = 0;
    auto alloc = [&](size_t bytes) -> void* {
        void* p = w + off;
        off = (off + bytes + 63) & ~(size_t)63;
        return p;
    };
    int*   flag    = (int*)  alloc(4);
    unsigned* hEx  = (unsigned*)alloc((size_t)HEX_WORDS * 4);
    u16*   canon   = (u16*)  alloc((size_t)CANON_TOTAL * 2);
    float* cvr     = (float*)alloc(32ull * 4);
    u16*   featv   = (u16*)  alloc(655360ull * 2);
    float* xpre    = (float*)alloc(2621440ull * 4);   // kmap aliases after LSTMs
    u16*   seq0    = (u16*)  alloc(655360ull * 2);
    u16*   seq1    = (u16*)  alloc(655360ull * 2);
    u16*   tok     = (u16*)  alloc(442368ull * 2);
    u16*   seqd0   = (u16*)  alloc(442368ull * 2);
    u16*   Hid     = (u16*)  alloc(442368ull * 2);
    float* holf    = (float*)alloc(16384ull * 4);
    float* qf      = (float*)alloc(442368ull * 4);
    u16*   featP   = (u16*)  alloc(5505024ull * 2);
    u16*   W2      = (u16*)  alloc(2359296ull * 2);
    float* aw      = (float*)alloc(207360ull * 4);
    float* concat  = (float*)alloc(1327104ull * 4);
    _Float16* Wq[4];
    for (int i = 0; i < 4; i++) Wq[i] = (_Float16*)alloc(1048576ull * 2);
    u16*   kmap    = (u16*)xpre;

    unsigned* hEx0 = hEx;
    unsigned* hEx1 = hEx + 40ull * 8192;
    unsigned* hEx2 = hEx + 80ull * 8192;
    unsigned* hEx3 = hEx + 107ull * 8192;

    u16* cW0    = canon + OFF_W0;
    u16* cW1    = canon + OFF_W1;
    u16* cW2    = canon + OFF_W2;
    u16* cW3    = canon + OFF_W3;
    u16* cb0    = canon + OFF_B;
    u16* cencW  = canon + OFF_ENCW;
    u16* cqW    = canon + OFF_QW;
    u16* cpredW = canon + OFF_PREDW;
    u16* cemb   = canon + OFF_EMB;
    u16* cencb  = canon + OFF_ENCB;
    u16* cqb    = canon + OFF_QB;
    u16* ckb    = canon + OFF_KB;
    u16* csW    = canon + OFF_SW;
    u16* csb    = canon + OFF_SB;
    u16* cpredb = canon + OFF_PREDB;

    // ---- fused prep (6 branches; big-weight canon skipped when input is bf16) ----
    PrepArgs P;
    P.S.e0Wih = d_in[3];  P.S.e1Wih = d_in[7];  P.S.d0Wih = d_in[20]; P.S.d1Wih = d_in[24];
    P.S.b0 = d_in[5];  P.S.b1 = d_in[6];  P.S.b2 = d_in[9];  P.S.b3 = d_in[10];
    P.S.b4 = d_in[22]; P.S.b5 = d_in[23]; P.S.b6 = d_in[26]; P.S.b7 = d_in[27];
    P.S.encW = d_in[11]; P.S.qW = d_in[13]; P.S.predW = d_in[28]; P.S.emb = d_in[19];
    P.S.encb = d_in[12]; P.S.qb = d_in[14]; P.S.kb = d_in[16]; P.S.sW = d_in[17];
    P.S.sb = d_in[18]; P.S.predb = d_in[29];
    P.feat_raw = feat_r; P.vr_src = vr_r; P.kW_src = d_in[15];
    P.wq_s0 = d_in[4]; P.wq_s1 = d_in[8]; P.wq_s2 = d_in[21]; P.wq_s3 = d_in[25];
    P.flag = flag; P.hEx = hEx; P.canon = canon; P.cvr = cvr;
    P.W2 = W2;
    P.wq_d0 = Wq[0]; P.wq_d1 = Wq[1]; P.wq_d2 = Wq[2]; P.wq_d3 = Wq[3];
    P.featv = featv; P.featP = featP;
    prep_all<<<dim3(PB_TOTAL), 256, 0, stream>>>(P);

    // ---- encoder ----
    gemm_nt_128<<<dim3(16, 10), 512, 65536, stream>>>(featv, cW0, (const u16*)d_in[3], cb0 + 0 * 2048, cb0 + 1 * 2048, xpre, 1280, 2048, flag);
    lstm_sync<<<dim3(256), 512, 0, stream>>>(xpre, Wq[0], seq0, nullptr, hEx0, 40, 0);
    gemm_nt_128<<<dim3(16, 10), 512, 65536, stream>>>(seq0, cW1, (const u16*)d_in[7], cb0 + 2 * 2048, cb0 + 3 * 2048, xpre, 1280, 2048, flag);
    lstm_sync<<<dim3(256), 512, 0, stream>>>(xpre, Wq[1], seq1, nullptr, hEx1, 40, 0);

    // ---- decoder (encW GEMM fused with token build) ----
    enc_tok<<<dim3(1672), 256, 0, stream>>>(seq1 + 39 * 512, 40 * 512, cencW, (const u16*)d_in[11],
                                            cencb, holf, tok, cemb, label, flag);
    gemm_nt_128<<<dim3(16, 7), 512, 65536, stream>>>(tok, cW2, (const u16*)d_in[20], cb0 + 4 * 2048, cb0 + 5 * 2048, xpre, 864, 2048, flag);
    lstm_sync<<<dim3(256), 512, 0, stream>>>(xpre, Wq[2], seqd0, nullptr, hEx2, 27, 0);
    gemm_nt_128<<<dim3(16, 7), 512, 65536, stream>>>(seqd0, cW3, (const u16*)d_in[24], cb0 + 6 * 2048, cb0 + 7 * 2048, xpre, 864, 2048, flag);
    lstm_sync<<<dim3(256), 512, 0, stream>>>(xpre, Wq[3], Hid, concat, hEx3, 27, 1536);

    // ---- attention: qf GEMM co-dispatched with conv (xpre dead; kmap aliases it) ----
    qf_conv<<<dim3(284), 512, 65536, stream>>>(Hid, cqW, (const u16*)d_in[13], cqb, qf, featP, W2, ckb, kmap, flag);
    score_k<<<dim3(864), 256, 0, stream>>>(qf, kmap, csW, csb, cvr, aw);
    attn_k<<<dim3(256), 256, 0, stream>>>(feat_r, aw, concat, flag);

    // ---- prediction ----
    pred_k<<<dim3(216), 256, 0, stream>>>(concat, holf, cpredW, cpredb, d_out, flag);
}